// Round 1
// baseline (5552.150 us; speedup 1.0000x reference)
//
#include <hip/hip_runtime.h>
#include <math.h>

#define T_  1024
#define B_  4
#define D_  512
#define H_  8
#define DH_ 64
#define DI_ 2048
#define V_  256
#define L_  8
#define S_  256   // segments

// ---------------------------------------------------------------------------
// Embedding: x[t,b,:] = word_emb[data[t,b],:]
__global__ __launch_bounds__(256) void k_embed(const int* __restrict__ data,
                                               const float* __restrict__ emb,
                                               float* __restrict__ x) {
    int idx = blockIdx.x * 256 + threadIdx.x;         // over T*B*D = 2,097,152
    if (idx >= T_ * B_ * D_) return;
    int d  = idx & (D_ - 1);
    int tb = idx >> 9;
    x[idx] = emb[(size_t)data[tb] * D_ + d];
}

// ---------------------------------------------------------------------------
// Sinusoidal relative position embedding, positions qlen-1 .. 0
__global__ __launch_bounds__(256) void k_posemb(float* __restrict__ r, int qlen) {
    int p = blockIdx.x;
    int k = threadIdx.x;                               // 0..255
    float pos = (float)(qlen - 1 - p);
    float inv = powf(10000.f, -((float)k) / 256.f);
    float ang = pos * inv;
    r[(size_t)p * D_ + k]       = sinf(ang);
    r[(size_t)p * D_ + 256 + k] = cosf(ang);
}

// ---------------------------------------------------------------------------
// Tiled fp32 GEMM: Y(M,N) = X(M,K) @ W(N,K)^T  (+bias, +ReLU if ACT==1)
// 64x64 tile, BK=16, 256 threads, 4x4 per thread.
template<int ACT>
__global__ __launch_bounds__(256) void k_gemm(const float* __restrict__ X,
                                              const float* __restrict__ W,
                                              const float* __restrict__ bias,
                                              float* __restrict__ Y,
                                              int M, int N, int K) {
    __shared__ float As[16][68];   // [k][m]
    __shared__ float Bs[16][68];   // [k][n]
    const int bm = blockIdx.x * 64, bn = blockIdx.y * 64;
    const int tid = threadIdx.x;
    const int tx = tid & 15, ty = tid >> 4;
    const int lm = tid >> 2, lk = (tid & 3) * 4;
    float acc[4][4] = {};
    const int gm_l = bm + lm;
    const bool okA = gm_l < M;
    const float* xp = X + (size_t)gm_l * K + lk;
    const float* wp = W + (size_t)(bn + lm) * K + lk;   // bn+lm < N guaranteed (N % 64 == 0)
    for (int k0 = 0; k0 < K; k0 += 16) {
        __syncthreads();
        float4 xv;
        if (okA) xv = *(const float4*)(xp + k0);
        else     xv = make_float4(0.f, 0.f, 0.f, 0.f);
        float4 wv = *(const float4*)(wp + k0);
        As[lk + 0][lm] = xv.x; As[lk + 1][lm] = xv.y; As[lk + 2][lm] = xv.z; As[lk + 3][lm] = xv.w;
        Bs[lk + 0][lm] = wv.x; Bs[lk + 1][lm] = wv.y; Bs[lk + 2][lm] = wv.z; Bs[lk + 3][lm] = wv.w;
        __syncthreads();
        #pragma unroll
        for (int k = 0; k < 16; ++k) {
            float4 a  = *(const float4*)(&As[k][ty * 4]);
            float4 bv = *(const float4*)(&Bs[k][tx * 4]);
            float a4[4] = {a.x, a.y, a.z, a.w};
            float b4[4] = {bv.x, bv.y, bv.z, bv.w};
            #pragma unroll
            for (int i2 = 0; i2 < 4; ++i2)
                #pragma unroll
                for (int j2 = 0; j2 < 4; ++j2)
                    acc[i2][j2] += a4[i2] * b4[j2];
        }
    }
    #pragma unroll
    for (int i2 = 0; i2 < 4; ++i2) {
        int gm = bm + ty * 4 + i2;
        if (gm >= M) continue;
        float* yp = Y + (size_t)gm * N + bn + tx * 4;
        #pragma unroll
        for (int j2 = 0; j2 < 4; ++j2) {
            float v = acc[i2][j2];
            if (bias) v += bias[bn + tx * 4 + j2];
            if (ACT == 1) v = fmaxf(v, 0.f);
            yp[j2] = v;
        }
    }
}

// ---------------------------------------------------------------------------
// Fused add + LayerNorm over D=512: x = LN(x (+ add)) * g + b, in-place.
__global__ __launch_bounds__(256) void k_ln(float* __restrict__ x,
                                            const float* __restrict__ add,
                                            const float* __restrict__ g,
                                            const float* __restrict__ b) {
    int row = blockIdx.x;
    float* xr = x + (size_t)row * D_;
    int t = threadIdx.x;
    float v0 = xr[t], v1 = xr[t + 256];
    if (add) {
        const float* ar = add + (size_t)row * D_;
        v0 += ar[t]; v1 += ar[t + 256];
    }
    float s  = v0 + v1;
    float sq = v0 * v0 + v1 * v1;
    #pragma unroll
    for (int off = 1; off < 64; off <<= 1) {
        s  += __shfl_xor(s,  off, 64);
        sq += __shfl_xor(sq, off, 64);
    }
    __shared__ float ls[4], lq[4];
    int wid = t >> 6;
    if ((t & 63) == 0) { ls[wid] = s; lq[wid] = sq; }
    __syncthreads();
    s  = ls[0] + ls[1] + ls[2] + ls[3];
    sq = lq[0] + lq[1] + lq[2] + lq[3];
    float mean = s * (1.f / (float)D_);
    float var  = sq * (1.f / (float)D_) - mean * mean;
    float rs   = rsqrtf(var + 1e-5f);
    xr[t]       = (v0 - mean) * rs * g[t]       + b[t];
    xr[t + 256] = (v1 - mean) * rs * g[t + 256] + b[t + 256];
}

// ---------------------------------------------------------------------------
// Downsample: xs[0,b,:] = null; xs[s,b,:] = mean(x[4(s-1)..4s-1, b, :])
__global__ __launch_bounds__(256) void k_down(const float* __restrict__ x,
                                              const float* __restrict__ nullg,
                                              float* __restrict__ xs) {
    int sb = blockIdx.x;            // 0 .. (S+1)*B-1
    int s = sb >> 2, b = sb & 3;
    for (int d = threadIdx.x; d < D_; d += 256) {
        float v;
        if (s == 0) v = nullg[d];
        else {
            int t0 = (s - 1) * 4;
            v = (x[((size_t)(t0 + 0) * B_ + b) * D_ + d] +
                 x[((size_t)(t0 + 1) * B_ + b) * D_ + d] +
                 x[((size_t)(t0 + 2) * B_ + b) * D_ + d] +
                 x[((size_t)(t0 + 3) * B_ + b) * D_ + d]) * 0.25f;
        }
        xs[((size_t)s * B_ + b) * D_ + d] = v;
    }
}

// Upsample + residual: x[t,b,:] += xs[(t+1)/4, b, :]
__global__ __launch_bounds__(256) void k_up(float* __restrict__ x,
                                            const float* __restrict__ xs) {
    int idx = blockIdx.x * 256 + threadIdx.x;        // over T*B*D
    if (idx >= T_ * B_ * D_) return;
    int d  = idx & (D_ - 1);
    int tb = idx >> 9;
    int t = tb >> 2, b = tb & 3;
    int seg = (t + 1) >> 2;
    x[idx] += xs[((size_t)seg * B_ + b) * D_ + d];
}

// ---------------------------------------------------------------------------
// Fused rel-pos flash attention (fp32).
// Block: 256 threads handles 32 query rows for one (b, n). Loops over 32-key
// chunks with online softmax. BD term: score(i,j) += qr_i . rk[Q-1-(i-j)],
// in-tile RK row = 31 - q + jj (window p0 = Q-32-i0+j0 .. +63).
__global__ __launch_bounds__(256) void k_attn(const float* __restrict__ qkv,
                                              const float* __restrict__ rk,
                                              const float* __restrict__ rwb,
                                              const float* __restrict__ rrb,
                                              float* __restrict__ outp, int Q) {
    __shared__ float qw[32][68], qr[32][68], Ks[32][68], Vs[32][68];
    __shared__ float RKs[64][68];
    __shared__ float Ps[32][36];
    const int i0 = blockIdx.x * 32;
    const int b  = blockIdx.y >> 3;
    const int n  = blockIdx.y & 7;
    const int tid = threadIdx.x;
    const int lr = tid >> 3, ld = (tid & 7) * 8;      // loader mapping (32 rows x 64)
    {   // load q tile, fold in biases
        const int i = i0 + lr;
        const float* qp = qkv + ((size_t)(i * B_ + b)) * 1536 + n * 64 + ld;
        #pragma unroll
        for (int u = 0; u < 8; ++u) {
            float qv = (i < Q) ? qp[u] : 0.f;
            qw[lr][ld + u] = qv + rwb[n * 64 + ld + u];
            qr[lr][ld + u] = qv + rrb[n * 64 + ld + u];
        }
    }
    const int q   = tid >> 3;          // this thread's query row (0..31)
    const int jj4 = (tid & 7) * 4;     // its 4-key slice for score compute
    const int d8  = (tid & 7) * 8;     // its 8-dim slice for PV
    const int i   = i0 + q;
    const int rr = tid >> 2, rd = (tid & 3) * 16;     // RK loader mapping (64 rows x 64)
    float mrun = -1e30f, lrun = 0.f;
    float acc[8] = {0, 0, 0, 0, 0, 0, 0, 0};
    const int jmax = min(i0 + 31, Q - 1);
    for (int j0 = 0; j0 <= jmax; j0 += 32) {
        __syncthreads();
        {   // load K, V chunk (rows j0..j0+31)
            const int j = j0 + lr;
            const bool ok = j < Q;
            const float* kp = qkv + ((size_t)(j * B_ + b)) * 1536 + 512 + n * 64 + ld;
            #pragma unroll
            for (int u = 0; u < 8; ++u) {
                Ks[lr][ld + u] = ok ? kp[u] : 0.f;
                Vs[lr][ld + u] = ok ? kp[512 + u] : 0.f;
            }
            // load RK window (64 rows starting at p0 = Q-32-i0+j0)
            const int p = Q - 32 - i0 + j0 + rr;
            const bool pok = (p >= 0) && (p < Q);
            const float* rp = rk + ((size_t)p * H_ + n) * 64 + rd;
            #pragma unroll
            for (int u = 0; u < 16; ++u) RKs[rr][rd + u] = pok ? rp[u] : 0.f;
        }
        __syncthreads();
        // scores for (q, jj4..jj4+3)
        float sv[4] = {0, 0, 0, 0};
        {
            const float* qwp = &qw[q][0];
            const float* qrp = &qr[q][0];
            const float* kp0 = &Ks[jj4][0];
            const float* rp0 = &RKs[31 - q + jj4][0];
            #pragma unroll
            for (int d = 0; d < 64; d += 4) {
                const float4 a = *(const float4*)(qwp + d);
                const float4 c = *(const float4*)(qrp + d);
                #pragma unroll
                for (int v = 0; v < 4; ++v) {
                    const float4 kk = *(const float4*)(kp0 + v * 68 + d);
                    const float4 rv = *(const float4*)(rp0 + v * 68 + d);
                    sv[v] += a.x * kk.x + a.y * kk.y + a.z * kk.z + a.w * kk.w
                           + c.x * rv.x + c.y * rv.y + c.z * rv.z + c.w * rv.w;
                }
            }
        }
        #pragma unroll
        for (int v = 0; v < 4; ++v) {
            sv[v] *= 0.125f;                                  // 1/sqrt(64)
            if (j0 + jj4 + v > i) sv[v] = -1e30f;             // causal mask
        }
        // online softmax (row group = 8 consecutive lanes)
        float cm = fmaxf(fmaxf(sv[0], sv[1]), fmaxf(sv[2], sv[3]));
        #pragma unroll
        for (int msk = 1; msk < 8; msk <<= 1) cm = fmaxf(cm, __shfl_xor(cm, msk, 64));
        float mnew = fmaxf(mrun, cm);
        float sc = __expf(mrun - mnew);
        float p[4], psum = 0.f;
        #pragma unroll
        for (int v = 0; v < 4; ++v) {
            p[v] = (j0 + jj4 + v <= i) ? __expf(sv[v] - mnew) : 0.f;
            psum += p[v];
        }
        #pragma unroll
        for (int msk = 1; msk < 8; msk <<= 1) psum += __shfl_xor(psum, msk, 64);
        mrun = mnew;
        lrun = lrun * sc + psum;
        Ps[q][jj4 + 0] = p[0]; Ps[q][jj4 + 1] = p[1];
        Ps[q][jj4 + 2] = p[2]; Ps[q][jj4 + 3] = p[3];
        #pragma unroll
        for (int u = 0; u < 8; ++u) acc[u] *= sc;
        __syncthreads();
        // PV: out[q][d8..d8+7] += sum_jj P[q][jj] * V[jj][:]
        #pragma unroll
        for (int jj = 0; jj < 32; ++jj) {
            float pv = Ps[q][jj];
            float4 v0 = *(const float4*)(&Vs[jj][d8]);
            float4 v1 = *(const float4*)(&Vs[jj][d8 + 4]);
            acc[0] += pv * v0.x; acc[1] += pv * v0.y; acc[2] += pv * v0.z; acc[3] += pv * v0.w;
            acc[4] += pv * v1.x; acc[5] += pv * v1.y; acc[6] += pv * v1.z; acc[7] += pv * v1.w;
        }
    }
    if (i < Q) {
        float inv = 1.f / lrun;
        float* op = outp + ((size_t)(i * B_ + b)) * 512 + n * 64 + d8;
        #pragma unroll
        for (int u = 0; u < 8; ++u) op[u] = acc[u] * inv;
    }
}

// ---------------------------------------------------------------------------
static inline void launch_gemm(int act, const float* X, const float* W,
                               const float* bias, float* Y, int M, int N, int K,
                               hipStream_t s) {
    dim3 g((M + 63) / 64, N / 64);
    if (act) k_gemm<1><<<g, 256, 0, s>>>(X, W, bias, Y, M, N, K);
    else     k_gemm<0><<<g, 256, 0, s>>>(X, W, bias, Y, M, N, K);
}

extern "C" void kernel_launch(void* const* d_in, const int* in_sizes, int n_in,
                              void* d_out, int out_size, void* d_ws, size_t ws_size,
                              hipStream_t stream) {
    const int*   data     = (const int*)  d_in[0];
    // d_in[1] boundaries_gt: deterministic (t%4==3) -> folded into indexing
    const float* word_emb = (const float*)d_in[2];
    const float* rwb      = (const float*)d_in[3];
    const float* rrb      = (const float*)d_in[4];
    const float* nullg    = (const float*)d_in[5];
    const float* dg       = (const float*)d_in[6];
    const float* db       = (const float*)d_in[7];
    const float* qkv_w    = (const float*)d_in[8];
    const float* rk_w     = (const float*)d_in[9];
    const float* o_w      = (const float*)d_in[10];
    const float* ln1g     = (const float*)d_in[11];
    const float* ln1b     = (const float*)d_in[12];
    const float* w1       = (const float*)d_in[13];
    const float* b1       = (const float*)d_in[14];
    const float* w2       = (const float*)d_in[15];
    const float* b2       = (const float*)d_in[16];
    const float* ln2g     = (const float*)d_in[17];
    const float* ln2b     = (const float*)d_in[18];
    const float* fw       = (const float*)d_in[19];
    const float* fb       = (const float*)d_in[20];
    float* out = (float*)d_out;
    float* ws  = (float*)d_ws;

    // workspace layout (floats); total = 18,483,712 floats = 73.9 MB
    float* x     = ws;                    // 4096*512
    float* r1    = x     + 2097152;       // 1024*512
    float* r2    = r1    + 524288;        // 257*512
    float* qkvb  = r2    + 131584;        // 4096*1536
    float* rkb   = qkvb  + 6291456;       // 1024*512
    float* attnb = rkb   + 524288;        // 4096*512
    float* tmp   = attnb + 2097152;       // 4096*512
    float* ffm   = tmp   + 2097152;       // 2048*2048
    float* xs    = ffm   + 4194304;       // 257*4*512

    k_embed<<<8192, 256, 0, stream>>>(data, word_emb, x);
    k_posemb<<<1024, 256, 0, stream>>>(r1, 1024);
    k_posemb<<<257, 256, 0, stream>>>(r2, 257);

    auto stage = [&](float* xb, const float* r, int Q, int lo, int hi) {
        const int M = Q * B_;
        dim3 gA((Q + 31) / 32, B_ * H_);
        for (int i = lo; i < hi; ++i) {
            launch_gemm(0, xb, qkv_w + (size_t)i * 1536 * 512, nullptr, qkvb, M, 1536, 512, stream);
            launch_gemm(0, r, rk_w + (size_t)i * 512 * 512, nullptr, rkb, Q, 512, 512, stream);
            k_attn<<<gA, 256, 0, stream>>>(qkvb, rkb, rwb, rrb, attnb, Q);
            launch_gemm(0, attnb, o_w + (size_t)i * 512 * 512, nullptr, tmp, M, 512, 512, stream);
            k_ln<<<M, 256, 0, stream>>>(xb, tmp, ln1g + (size_t)i * 512, ln1b + (size_t)i * 512);
            for (int c = 0; c < M; c += 2048) {
                int mc = min(2048, M - c);
                launch_gemm(1, xb + (size_t)c * 512, w1 + (size_t)i * 2048 * 512,
                            b1 + (size_t)i * 2048, ffm, mc, 2048, 512, stream);
                launch_gemm(0, ffm, w2 + (size_t)i * 512 * 2048,
                            b2 + (size_t)i * 512, tmp + (size_t)c * 512, mc, 512, 2048, stream);
            }
            k_ln<<<M, 256, 0, stream>>>(xb, tmp, ln2g + (size_t)i * 512, ln2b + (size_t)i * 512);
        }
    };

    stage(x, r1, 1024, 0, 2);                                   // pre
    k_down<<<(S_ + 1) * B_, 256, 0, stream>>>(x, nullg, xs);    // mean-pool + null row
    k_ln<<<(S_ + 1) * B_, 256, 0, stream>>>(xs, nullptr, dg, db);
    stage(xs, r2, S_ + 1, 2, 6);                                // shortened
    k_up<<<8192, 256, 0, stream>>>(x, xs);                      // upsample + residual
    stage(x, r1, 1024, 6, 8);                                   // post
    launch_gemm(0, x, fw, fb, out, T_ * B_, V_, 512, stream);   // logits
}

// Round 2
// 2487.377 us; speedup vs baseline: 2.2321x; 2.2321x over previous
//
#include <hip/hip_runtime.h>
#include <math.h>

#define T_  1024
#define B_  4
#define D_  512
#define H_  8
#define DH_ 64
#define DI_ 2048
#define V_  256
#define L_  8
#define S_  256   // segments

typedef _Float16 f16;
typedef f16   f16x8 __attribute__((ext_vector_type(8)));
typedef float f32x4 __attribute__((ext_vector_type(4)));

// ---------------------------------------------------------------------------
// Embedding: x[t,b,:] = word_emb[data[t,b],:]
__global__ __launch_bounds__(256) void k_embed(const int* __restrict__ data,
                                               const float* __restrict__ emb,
                                               float* __restrict__ x) {
    int idx = blockIdx.x * 256 + threadIdx.x;
    if (idx >= T_ * B_ * D_) return;
    int d  = idx & (D_ - 1);
    int tb = idx >> 9;
    x[idx] = emb[(size_t)data[tb] * D_ + d];
}

// ---------------------------------------------------------------------------
// Sinusoidal relative position embedding, positions qlen-1 .. 0
__global__ __launch_bounds__(256) void k_posemb(float* __restrict__ r, int qlen) {
    int p = blockIdx.x;
    int k = threadIdx.x;
    float pos = (float)(qlen - 1 - p);
    float inv = powf(10000.f, -((float)k) / 256.f);
    float ang = pos * inv;
    r[(size_t)p * D_ + k]       = sinf(ang);
    r[(size_t)p * D_ + 256 + k] = cosf(ang);
}

// ---------------------------------------------------------------------------
// MFMA fp16 GEMM: Y(M,N) = X(M,K) @ W(N,K)^T (+bias, +ReLU if ACT).
// fp32 in/out; converts to fp16 while staging to LDS. 128x128 tile, BK=32,
// 4 waves (2x2 of 64x64), 4x4 16x16x32 fragments per wave.
// Fragment reads are contiguous ds_read_b128 from [row][32] LDS layout.
// Requires N % 128 == 0, K % 32 == 0; M guarded.
template<int ACT>
__global__ __launch_bounds__(256) void k_gemm(const float* __restrict__ X,
                                              const float* __restrict__ W,
                                              const float* __restrict__ bias,
                                              float* __restrict__ Y,
                                              int M, int N, int K) {
    __shared__ f16 As[128 * 32];
    __shared__ f16 Bs[128 * 32];
    const int tid = threadIdx.x;
    const int bm = blockIdx.x * 128, bn = blockIdx.y * 128;
    // staging: thread -> (row = tid>>1, 16 contiguous k at (tid&1)*16)
    const int srow = tid >> 1, skq = (tid & 1) * 16;
    const int arow = bm + srow;
    const bool okA = arow < M;
    const float* xp = X + (size_t)arow * K + skq;
    const float* wp = W + (size_t)(bn + srow) * K + skq;
    f16* asw = &As[srow * 32 + skq];
    f16* bsw = &Bs[srow * 32 + skq];
    // fragment mapping
    const int w = tid >> 6, lane = tid & 63, l16 = lane & 15, lg = lane >> 4;
    const int wr = w >> 1, wc = w & 1;
    const f16* ar = &As[(wr * 64 + l16) * 32 + lg * 8];
    const f16* br = &Bs[(wc * 64 + l16) * 32 + lg * 8];
    const f32x4 z4 = {0.f, 0.f, 0.f, 0.f};
    f32x4 acc[4][4];
    #pragma unroll
    for (int i = 0; i < 4; ++i)
        #pragma unroll
        for (int j = 0; j < 4; ++j) acc[i][j] = z4;

    for (int k0 = 0; k0 < K; k0 += 32) {
        __syncthreads();
        float xv[16], wv[16];
        #pragma unroll
        for (int u = 0; u < 16; u += 4) {
            float4 a = okA ? *(const float4*)(xp + k0 + u) : make_float4(0.f, 0.f, 0.f, 0.f);
            float4 c = *(const float4*)(wp + k0 + u);
            xv[u] = a.x; xv[u + 1] = a.y; xv[u + 2] = a.z; xv[u + 3] = a.w;
            wv[u] = c.x; wv[u + 1] = c.y; wv[u + 2] = c.z; wv[u + 3] = c.w;
        }
        f16x8 pa0, pa1, pb0, pb1;
        #pragma unroll
        for (int u = 0; u < 8; ++u) {
            pa0[u] = (f16)xv[u]; pa1[u] = (f16)xv[u + 8];
            pb0[u] = (f16)wv[u]; pb1[u] = (f16)wv[u + 8];
        }
        *(f16x8*)asw = pa0; *(f16x8*)(asw + 8) = pa1;
        *(f16x8*)bsw = pb0; *(f16x8*)(bsw + 8) = pb1;
        __syncthreads();
        f16x8 af[4], bfv[4];
        #pragma unroll
        for (int i = 0; i < 4; ++i) af[i]  = *(const f16x8*)(ar + i * 16 * 32);
        #pragma unroll
        for (int j = 0; j < 4; ++j) bfv[j] = *(const f16x8*)(br + j * 16 * 32);
        #pragma unroll
        for (int i = 0; i < 4; ++i)
            #pragma unroll
            for (int j = 0; j < 4; ++j)
                acc[i][j] = __builtin_amdgcn_mfma_f32_16x16x32_f16(af[i], bfv[j], acc[i][j], 0, 0, 0);
    }
    // epilogue: C layout col=lane&15, row=(lane>>4)*4+reg  [m89]
    #pragma unroll
    for (int i = 0; i < 4; ++i) {
        #pragma unroll
        for (int r = 0; r < 4; ++r) {
            int row = bm + wr * 64 + i * 16 + lg * 4 + r;
            if (row >= M) continue;
            float* yp = Y + (size_t)row * N + bn + wc * 64 + l16;
            #pragma unroll
            for (int j = 0; j < 4; ++j) {
                float v = acc[i][j][r];
                if (bias) v += bias[bn + wc * 64 + j * 16 + l16];
                if (ACT) v = fmaxf(v, 0.f);
                yp[j * 16] = v;
            }
        }
    }
}

// ---------------------------------------------------------------------------
// Fused add + LayerNorm over D=512
__global__ __launch_bounds__(256) void k_ln(float* __restrict__ x,
                                            const float* __restrict__ add,
                                            const float* __restrict__ g,
                                            const float* __restrict__ b) {
    int row = blockIdx.x;
    float* xr = x + (size_t)row * D_;
    int t = threadIdx.x;
    float v0 = xr[t], v1 = xr[t + 256];
    if (add) {
        const float* arp = add + (size_t)row * D_;
        v0 += arp[t]; v1 += arp[t + 256];
    }
    float s  = v0 + v1;
    float sq = v0 * v0 + v1 * v1;
    #pragma unroll
    for (int off = 1; off < 64; off <<= 1) {
        s  += __shfl_xor(s,  off, 64);
        sq += __shfl_xor(sq, off, 64);
    }
    __shared__ float ls[4], lq[4];
    int wid = t >> 6;
    if ((t & 63) == 0) { ls[wid] = s; lq[wid] = sq; }
    __syncthreads();
    s  = ls[0] + ls[1] + ls[2] + ls[3];
    sq = lq[0] + lq[1] + lq[2] + lq[3];
    float mean = s * (1.f / (float)D_);
    float var  = sq * (1.f / (float)D_) - mean * mean;
    float rs   = rsqrtf(var + 1e-5f);
    xr[t]       = (v0 - mean) * rs * g[t]       + b[t];
    xr[t + 256] = (v1 - mean) * rs * g[t + 256] + b[t + 256];
}

// ---------------------------------------------------------------------------
__global__ __launch_bounds__(256) void k_down(const float* __restrict__ x,
                                              const float* __restrict__ nullg,
                                              float* __restrict__ xs) {
    int sb = blockIdx.x;
    int s = sb >> 2, b = sb & 3;
    for (int d = threadIdx.x; d < D_; d += 256) {
        float v;
        if (s == 0) v = nullg[d];
        else {
            int t0 = (s - 1) * 4;
            v = (x[((size_t)(t0 + 0) * B_ + b) * D_ + d] +
                 x[((size_t)(t0 + 1) * B_ + b) * D_ + d] +
                 x[((size_t)(t0 + 2) * B_ + b) * D_ + d] +
                 x[((size_t)(t0 + 3) * B_ + b) * D_ + d]) * 0.25f;
        }
        xs[((size_t)s * B_ + b) * D_ + d] = v;
    }
}

__global__ __launch_bounds__(256) void k_up(float* __restrict__ x,
                                            const float* __restrict__ xs) {
    int idx = blockIdx.x * 256 + threadIdx.x;
    if (idx >= T_ * B_ * D_) return;
    int d  = idx & (D_ - 1);
    int tb = idx >> 9;
    int t = tb >> 2, b = tb & 3;
    int seg = (t + 1) >> 2;
    x[idx] += xs[((size_t)seg * B_ + b) * D_ + d];
}

// ---------------------------------------------------------------------------
// MFMA flash attention with Transformer-XL relative positions (fp32 I/O).
// Block = 64 query rows x one (b,n); 4 waves of 16 rows each. Per 32-key
// chunk: S1 = Qw.K^T (MFMA), S2full = Qr.RKwin^T (MFMA over 48 shifted
// positions, staged to LDS, gathered per-row: BD[q][jj]=S2full[q][jj-q+15]),
// online softmax in C-fragment layout, P staged to LDS as fp16 A-fragments,
// PV via MFMA with V transposed in LDS.
__global__ __launch_bounds__(256) void k_attn(const float* __restrict__ qkv,
                                              const float* __restrict__ rkb,
                                              const float* __restrict__ rwb,
                                              const float* __restrict__ rrb,
                                              float* __restrict__ outp, int Q) {
    __shared__ f16 Qw[64 * 64], Qr[64 * 64];   // [q][d]
    __shared__ f16 Ks[32 * 64];                // [jj][d]
    __shared__ f16 Vt[64 * 32];                // [d][jj]
    __shared__ f16 RKs[96 * 64];               // [p-p0-j0][d]
    __shared__ float S2[4][16 * 48];           // per-wave [q][c]
    __shared__ f16 Pl[4][16 * 32];             // per-wave [q][jj]
    const int i0 = blockIdx.x * 64;
    const int b  = blockIdx.y >> 3;
    const int n  = blockIdx.y & 7;
    const int tid = threadIdx.x, w = tid >> 6, lane = tid & 63;
    const int l16 = lane & 15, lg = lane >> 4;

    // stage Q (+ biases), fp32->fp16
    {
        int row = tid >> 2, dq = (tid & 3) * 16;
        int i = i0 + row;
        const float* qp = qkv + ((size_t)i * B_ + b) * 1536 + n * 64 + dq;
        #pragma unroll
        for (int u = 0; u < 16; u += 4) {
            float4 qv = (i < Q) ? *(const float4*)(qp + u) : make_float4(0.f, 0.f, 0.f, 0.f);
            float4 wv = *(const float4*)(rwb + n * 64 + dq + u);
            float4 rv = *(const float4*)(rrb + n * 64 + dq + u);
            Qw[row * 64 + dq + u + 0] = (f16)(qv.x + wv.x);
            Qw[row * 64 + dq + u + 1] = (f16)(qv.y + wv.y);
            Qw[row * 64 + dq + u + 2] = (f16)(qv.z + wv.z);
            Qw[row * 64 + dq + u + 3] = (f16)(qv.w + wv.w);
            Qr[row * 64 + dq + u + 0] = (f16)(qv.x + rv.x);
            Qr[row * 64 + dq + u + 1] = (f16)(qv.y + rv.y);
            Qr[row * 64 + dq + u + 2] = (f16)(qv.z + rv.z);
            Qr[row * 64 + dq + u + 3] = (f16)(qv.w + rv.w);
        }
    }
    __syncthreads();
    // Q A-fragments (row=lane&15, k=(lane>>4)*8+j), two K=32 halves
    f16x8 aqw[2], aqr[2];
    #pragma unroll
    for (int h = 0; h < 2; ++h) {
        aqw[h] = *(const f16x8*)&Qw[(w * 16 + l16) * 64 + h * 32 + lg * 8];
        aqr[h] = *(const f16x8*)&Qr[(w * 16 + l16) * 64 + h * 32 + lg * 8];
    }

    const f32x4 z4 = {0.f, 0.f, 0.f, 0.f};
    f32x4 accv[4]; accv[0] = z4; accv[1] = z4; accv[2] = z4; accv[3] = z4;
    float mrun[4] = {-1e30f, -1e30f, -1e30f, -1e30f};
    float lrun[4] = {0.f, 0.f, 0.f, 0.f};
    const int p0 = Q - 64 - i0;
    const int jmax = min(i0 + 63, Q - 1);

    for (int j0 = 0; j0 <= jmax; j0 += 32) {
        __syncthreads();
        {   // stage K (row-major) and V (transposed)
            int jj = tid >> 3, d8 = (tid & 7) * 8;
            int j = j0 + jj;
            bool ok = j < Q;
            const float* kp = qkv + ((size_t)j * B_ + b) * 1536 + 512 + n * 64 + d8;
            float4 k0v, k1v, v0v, v1v;
            if (ok) {
                k0v = *(const float4*)(kp);       k1v = *(const float4*)(kp + 4);
                v0v = *(const float4*)(kp + 512); v1v = *(const float4*)(kp + 516);
            } else {
                k0v = k1v = v0v = v1v = make_float4(0.f, 0.f, 0.f, 0.f);
            }
            f16* kd = &Ks[jj * 64 + d8];
            kd[0] = (f16)k0v.x; kd[1] = (f16)k0v.y; kd[2] = (f16)k0v.z; kd[3] = (f16)k0v.w;
            kd[4] = (f16)k1v.x; kd[5] = (f16)k1v.y; kd[6] = (f16)k1v.z; kd[7] = (f16)k1v.w;
            Vt[(d8 + 0) * 32 + jj] = (f16)v0v.x; Vt[(d8 + 1) * 32 + jj] = (f16)v0v.y;
            Vt[(d8 + 2) * 32 + jj] = (f16)v0v.z; Vt[(d8 + 3) * 32 + jj] = (f16)v0v.w;
            Vt[(d8 + 4) * 32 + jj] = (f16)v1v.x; Vt[(d8 + 5) * 32 + jj] = (f16)v1v.y;
            Vt[(d8 + 6) * 32 + jj] = (f16)v1v.z; Vt[(d8 + 7) * 32 + jj] = (f16)v1v.w;
            // stage RK window: 96 rows, p = p0 + j0 + pr
            #pragma unroll
            for (int rep = 0; rep < 3; ++rep) {
                int pr = rep * 32 + (tid >> 3);
                int p = p0 + j0 + pr;
                bool pok = (p >= 0) && (p < Q);
                const float* rp = rkb + (size_t)p * 512 + n * 64 + d8;
                float4 r0v, r1v;
                if (pok) { r0v = *(const float4*)(rp); r1v = *(const float4*)(rp + 4); }
                else     { r0v = r1v = make_float4(0.f, 0.f, 0.f, 0.f); }
                f16* rd = &RKs[pr * 64 + d8];
                rd[0] = (f16)r0v.x; rd[1] = (f16)r0v.y; rd[2] = (f16)r0v.z; rd[3] = (f16)r0v.w;
                rd[4] = (f16)r1v.x; rd[5] = (f16)r1v.y; rd[6] = (f16)r1v.z; rd[7] = (f16)r1v.w;
            }
        }
        __syncthreads();
        if (j0 <= i0 + w * 16 + 15) {   // wave has unmasked rows in this chunk
            // S1 = Qw . K^T  (16x32)
            f32x4 s1[2]; s1[0] = z4; s1[1] = z4;
            #pragma unroll
            for (int f = 0; f < 2; ++f)
                #pragma unroll
                for (int h = 0; h < 2; ++h) {
                    f16x8 bv = *(const f16x8*)&Ks[(f * 16 + l16) * 64 + h * 32 + lg * 8];
                    s1[f] = __builtin_amdgcn_mfma_f32_16x16x32_f16(aqw[h], bv, s1[f], 0, 0, 0);
                }
            // S2full = Qr . RKwin^T  (16x48); wave window base wb = 48-16w
            f32x4 s2[3]; s2[0] = z4; s2[1] = z4; s2[2] = z4;
            const int wb = 48 - 16 * w;
            #pragma unroll
            for (int f = 0; f < 3; ++f)
                #pragma unroll
                for (int h = 0; h < 2; ++h) {
                    f16x8 bv = *(const f16x8*)&RKs[(wb + f * 16 + l16) * 64 + h * 32 + lg * 8];
                    s2[f] = __builtin_amdgcn_mfma_f32_16x16x32_f16(aqr[h], bv, s2[f], 0, 0, 0);
                }
            #pragma unroll
            for (int f = 0; f < 3; ++f)
                #pragma unroll
                for (int r = 0; r < 4; ++r)
                    S2[w][(lg * 4 + r) * 48 + f * 16 + l16] = s2[f][r];
            // scores + online softmax; C layout: row q = lg*4+r, col jj
            #pragma unroll
            for (int r = 0; r < 4; ++r) {
                const int q = lg * 4 + r;
                const int iq = i0 + w * 16 + q;
                float v0 = (s1[0][r] + S2[w][q * 48 + (l16 - q + 15)]) * 0.125f;
                float v1 = (s1[1][r] + S2[w][q * 48 + (16 + l16 - q + 15)]) * 0.125f;
                const int ja = j0 + l16, jb = j0 + 16 + l16;
                if (ja > iq || ja >= Q) v0 = -1e30f;
                if (jb > iq || jb >= Q) v1 = -1e30f;
                float cm = fmaxf(v0, v1);
                cm = fmaxf(cm, __shfl_xor(cm, 1, 64));
                cm = fmaxf(cm, __shfl_xor(cm, 2, 64));
                cm = fmaxf(cm, __shfl_xor(cm, 4, 64));
                cm = fmaxf(cm, __shfl_xor(cm, 8, 64));
                float mnew = fmaxf(mrun[r], cm);
                float sc = __expf(mrun[r] - mnew);
                float pv0 = __expf(v0 - mnew);
                float pv1 = __expf(v1 - mnew);
                float ps = pv0 + pv1;
                ps += __shfl_xor(ps, 1, 64);
                ps += __shfl_xor(ps, 2, 64);
                ps += __shfl_xor(ps, 4, 64);
                ps += __shfl_xor(ps, 8, 64);
                lrun[r] = lrun[r] * sc + ps;
                mrun[r] = mnew;
                #pragma unroll
                for (int f = 0; f < 4; ++f) accv[f][r] *= sc;
                Pl[w][q * 32 + l16]      = (f16)pv0;
                Pl[w][q * 32 + 16 + l16] = (f16)pv1;
            }
            // PV: A = P (16x32), B = V (32x64 via transposed LDS)
            f16x8 pa = *(const f16x8*)&Pl[w][l16 * 32 + lg * 8];
            #pragma unroll
            for (int f = 0; f < 4; ++f) {
                f16x8 bv = *(const f16x8*)&Vt[(f * 16 + l16) * 32 + lg * 8];
                accv[f] = __builtin_amdgcn_mfma_f32_16x16x32_f16(pa, bv, accv[f], 0, 0, 0);
            }
        }
    }
    // epilogue
    #pragma unroll
    for (int r = 0; r < 4; ++r) {
        int i = i0 + w * 16 + lg * 4 + r;
        if (i < Q) {
            float inv = 1.f / lrun[r];
            float* op = outp + ((size_t)i * B_ + b) * 512 + n * 64;
            #pragma unroll
            for (int f = 0; f < 4; ++f)
                op[f * 16 + l16] = accv[f][r] * inv;
        }
    }
}

// ---------------------------------------------------------------------------
static inline void launch_gemm(int act, const float* X, const float* W,
                               const float* bias, float* Y, int M, int N, int K,
                               hipStream_t s) {
    dim3 g((M + 127) / 128, N / 128);
    if (act) k_gemm<1><<<g, 256, 0, s>>>(X, W, bias, Y, M, N, K);
    else     k_gemm<0><<<g, 256, 0, s>>>(X, W, bias, Y, M, N, K);
}

extern "C" void kernel_launch(void* const* d_in, const int* in_sizes, int n_in,
                              void* d_out, int out_size, void* d_ws, size_t ws_size,
                              hipStream_t stream) {
    const int*   data     = (const int*)  d_in[0];
    // d_in[1] boundaries_gt: deterministic (t%4==3) -> folded into indexing
    const float* word_emb = (const float*)d_in[2];
    const float* rwb      = (const float*)d_in[3];
    const float* rrb      = (const float*)d_in[4];
    const float* nullg    = (const float*)d_in[5];
    const float* dg       = (const float*)d_in[6];
    const float* db       = (const float*)d_in[7];
    const float* qkv_w    = (const float*)d_in[8];
    const float* rk_w     = (const float*)d_in[9];
    const float* o_w      = (const float*)d_in[10];
    const float* ln1g     = (const float*)d_in[11];
    const float* ln1b     = (const float*)d_in[12];
    const float* w1       = (const float*)d_in[13];
    const float* b1       = (const float*)d_in[14];
    const float* w2       = (const float*)d_in[15];
    const float* b2       = (const float*)d_in[16];
    const float* ln2g     = (const float*)d_in[17];
    const float* ln2b     = (const float*)d_in[18];
    const float* fw       = (const float*)d_in[19];
    const float* fb       = (const float*)d_in[20];
    float* out = (float*)d_out;
    float* ws  = (float*)d_ws;

    // workspace (floats), total 16,386,560 = 65.5 MB.
    // big = qkv output / ff intermediate (disjoint lifetimes within a layer).
    float* x     = ws;                    // 2097152
    float* r1    = x     + 2097152;       // 524288
    float* r2    = r1    + 524288;        // 131584
    float* rkb   = r2    + 131584;        // 524288
    float* attnb = rkb   + 524288;        // 2097152
    float* tmp   = attnb + 2097152;       // 2097152
    float* xs    = tmp   + 2097152;       // 526336
    float* big   = xs    + 526336;        // 8388608

    k_embed<<<8192, 256, 0, stream>>>(data, word_emb, x);
    k_posemb<<<1024, 256, 0, stream>>>(r1, 1024);
    k_posemb<<<257, 256, 0, stream>>>(r2, 257);

    auto stage = [&](float* xb, const float* r, int Q, int lo, int hi) {
        const int M = Q * B_;
        dim3 gA((Q + 63) / 64, B_ * H_);
        for (int i = lo; i < hi; ++i) {
            launch_gemm(0, xb, qkv_w + (size_t)i * 1536 * 512, nullptr, big, M, 1536, 512, stream);
            launch_gemm(0, r, rk_w + (size_t)i * 512 * 512, nullptr, rkb, Q, 512, 512, stream);
            k_attn<<<gA, 256, 0, stream>>>(big, rkb, rwb, rrb, attnb, Q);
            launch_gemm(0, attnb, o_w + (size_t)i * 512 * 512, nullptr, tmp, M, 512, 512, stream);
            k_ln<<<M, 256, 0, stream>>>(xb, tmp, ln1g + (size_t)i * 512, ln1b + (size_t)i * 512);
            launch_gemm(1, xb, w1 + (size_t)i * 2048 * 512, b1 + (size_t)i * 2048, big, M, 2048, 512, stream);
            launch_gemm(0, big, w2 + (size_t)i * 512 * 2048, b2 + (size_t)i * 512, tmp, M, 512, 2048, stream);
            k_ln<<<M, 256, 0, stream>>>(xb, tmp, ln2g + (size_t)i * 512, ln2b + (size_t)i * 512);
        }
    };

    stage(x, r1, 1024, 0, 2);                                   // pre
    k_down<<<(S_ + 1) * B_, 256, 0, stream>>>(x, nullg, xs);    // mean-pool + null
    k_ln<<<(S_ + 1) * B_, 256, 0, stream>>>(xs, nullptr, dg, db);
    stage(xs, r2, S_ + 1, 2, 6);                                // shortened
    k_up<<<8192, 256, 0, stream>>>(x, xs);                      // upsample + residual
    stage(x, r1, 1024, 6, 8);                                   // post
    launch_gemm(0, x, fw, fb, out, T_ * B_, V_, 512, stream);   // logits
}

// Round 3
// 1434.861 us; speedup vs baseline: 3.8695x; 1.7335x over previous
//
#include <hip/hip_runtime.h>
#include <math.h>

#define T_  1024
#define B_  4
#define D_  512
#define H_  8
#define DH_ 64
#define DI_ 2048
#define V_  256
#define L_  8
#define S_  256   // segments

typedef _Float16 f16;
typedef f16   f16x8 __attribute__((ext_vector_type(8)));
typedef float f32x4 __attribute__((ext_vector_type(4)));

__device__ __forceinline__ void gload16(const void* g, void* l) {
    __builtin_amdgcn_global_load_lds(
        (const __attribute__((address_space(1))) void*)g,
        (__attribute__((address_space(3))) void*)l, 16, 0, 0);
}

// ---------------------------------------------------------------------------
// fp32 -> fp16 conversion (weights), grid-stride
__global__ __launch_bounds__(256) void k_f2h(const float* __restrict__ s,
                                             f16* __restrict__ d, int n) {
    int i = (blockIdx.x * 256 + threadIdx.x) * 4;
    int stride = gridDim.x * 1024;
    for (; i < n; i += stride) {
        float4 v = *(const float4*)(s + i);
        d[i + 0] = (f16)v.x; d[i + 1] = (f16)v.y;
        d[i + 2] = (f16)v.z; d[i + 3] = (f16)v.w;
    }
}

// ---------------------------------------------------------------------------
// Embedding: x[t,b,:] = word_emb[data[t,b],:]  (fp32 + fp16 mirror)
__global__ __launch_bounds__(256) void k_embed(const int* __restrict__ data,
                                               const float* __restrict__ emb,
                                               float* __restrict__ x,
                                               f16* __restrict__ xh) {
    int idx = blockIdx.x * 256 + threadIdx.x;
    if (idx >= T_ * B_ * D_) return;
    int d  = idx & (D_ - 1);
    int tb = idx >> 9;
    float v = emb[(size_t)data[tb] * D_ + d];
    x[idx] = v; xh[idx] = (f16)v;
}

// ---------------------------------------------------------------------------
// Sinusoidal relative position embedding (fp16 out), positions qlen-1 .. 0
__global__ __launch_bounds__(256) void k_posemb(f16* __restrict__ r, int qlen) {
    int p = blockIdx.x;
    int k = threadIdx.x;
    float pos = (float)(qlen - 1 - p);
    float inv = powf(10000.f, -((float)k) / 256.f);
    float ang = pos * inv;
    r[(size_t)p * D_ + k]       = (f16)sinf(ang);
    r[(size_t)p * D_ + 256 + k] = (f16)cosf(ang);
}

// ---------------------------------------------------------------------------
// MFMA fp16 GEMM, m97 structure: global_load_lds(16B) staging, BK=64,
// 2-barrier K-loop. Y(M,N) = X(M,K) @ W(N,K)^T (+bias fp32, +ReLU if ACT).
// BM=128: 4 waves 2x2, 4x4 frags. BM=64: waves 1x4, 4x2 frags.
// N % 128 == 0, K % 64 == 0; M guarded at store (loads may read padded rows).
template<int BM, int OUT16, int ACT>
__global__ __launch_bounds__(256) void k_gemm(const f16* __restrict__ X,
                                              const f16* __restrict__ W,
                                              const float* __restrict__ bias,
                                              void* __restrict__ Yv,
                                              int M, int N, int K) {
    __shared__ f16 As[BM * 64];
    __shared__ f16 Bs[128 * 64];
    const int tid = threadIdx.x, w = tid >> 6, lane = tid & 63;
    const int l16 = lane & 15, lg = lane >> 4;
    const int bm = blockIdx.x * BM, bn = blockIdx.y * 128;
    const int lrow = lane >> 3, lcol = (lane & 7) * 8;
    constexpr int AI = BM / 32;                 // A issues per wave
    constexpr int MI = 4;
    constexpr int NJ = (BM == 128) ? 4 : 2;
    const int rbase = (BM == 128) ? (w >> 1) * 64 : 0;
    const int cbase = (BM == 128) ? (w & 1) * 64 : w * 32;
    const f32x4 z4 = {0.f, 0.f, 0.f, 0.f};
    f32x4 acc[MI][NJ];
    #pragma unroll
    for (int i = 0; i < MI; ++i)
        #pragma unroll
        for (int j = 0; j < NJ; ++j) acc[i][j] = z4;

    for (int k0 = 0; k0 < K; k0 += 64) {
        __syncthreads();
        #pragma unroll
        for (int u = 0; u < AI; ++u) {
            int rb = w * (8 * AI) + u * 8;
            gload16(X + (size_t)(bm + rb + lrow) * K + k0 + lcol, &As[rb * 64]);
        }
        #pragma unroll
        for (int u = 0; u < 4; ++u) {
            int rb = w * 32 + u * 8;
            gload16(W + (size_t)(bn + rb + lrow) * K + k0 + lcol, &Bs[rb * 64]);
        }
        __syncthreads();
        #pragma unroll
        for (int h = 0; h < 2; ++h) {
            f16x8 af[MI], bf[NJ];
            #pragma unroll
            for (int i = 0; i < MI; ++i)
                af[i] = *(const f16x8*)&As[(rbase + i * 16 + l16) * 64 + h * 32 + lg * 8];
            #pragma unroll
            for (int j = 0; j < NJ; ++j)
                bf[j] = *(const f16x8*)&Bs[(cbase + j * 16 + l16) * 64 + h * 32 + lg * 8];
            #pragma unroll
            for (int i = 0; i < MI; ++i)
                #pragma unroll
                for (int j = 0; j < NJ; ++j)
                    acc[i][j] = __builtin_amdgcn_mfma_f32_16x16x32_f16(af[i], bf[j], acc[i][j], 0, 0, 0);
        }
    }
    #pragma unroll
    for (int i = 0; i < MI; ++i) {
        #pragma unroll
        for (int r = 0; r < 4; ++r) {
            int row = bm + rbase + i * 16 + lg * 4 + r;
            if (row >= M) continue;
            int colb = bn + cbase + l16;
            #pragma unroll
            for (int j = 0; j < NJ; ++j) {
                float v = acc[i][j][r];
                if (bias) v += bias[colb + j * 16];
                if (ACT) v = fmaxf(v, 0.f);
                if (OUT16) ((f16*)Yv)[(size_t)row * N + colb + j * 16] = (f16)v;
                else       ((float*)Yv)[(size_t)row * N + colb + j * 16] = v;
            }
        }
    }
}

// ---------------------------------------------------------------------------
// Fused add + LayerNorm over D=512; writes fp32 x and fp16 mirror
__global__ __launch_bounds__(256) void k_ln(float* __restrict__ x,
                                            const float* __restrict__ add,
                                            const float* __restrict__ g,
                                            const float* __restrict__ b,
                                            f16* __restrict__ xh) {
    int row = blockIdx.x;
    float* xr = x + (size_t)row * D_;
    int t = threadIdx.x;
    float v0 = xr[t], v1 = xr[t + 256];
    if (add) {
        const float* arp = add + (size_t)row * D_;
        v0 += arp[t]; v1 += arp[t + 256];
    }
    float s  = v0 + v1;
    float sq = v0 * v0 + v1 * v1;
    #pragma unroll
    for (int off = 1; off < 64; off <<= 1) {
        s  += __shfl_xor(s,  off, 64);
        sq += __shfl_xor(sq, off, 64);
    }
    __shared__ float ls[4], lq[4];
    int wid = t >> 6;
    if ((t & 63) == 0) { ls[wid] = s; lq[wid] = sq; }
    __syncthreads();
    s  = ls[0] + ls[1] + ls[2] + ls[3];
    sq = lq[0] + lq[1] + lq[2] + lq[3];
    float mean = s * (1.f / (float)D_);
    float var  = sq * (1.f / (float)D_) - mean * mean;
    float rs   = rsqrtf(var + 1e-5f);
    float o0 = (v0 - mean) * rs * g[t]       + b[t];
    float o1 = (v1 - mean) * rs * g[t + 256] + b[t + 256];
    xr[t] = o0; xr[t + 256] = o1;
    f16* hr = xh + (size_t)row * D_;
    hr[t] = (f16)o0; hr[t + 256] = (f16)o1;
}

// ---------------------------------------------------------------------------
__global__ __launch_bounds__(256) void k_down(const float* __restrict__ x,
                                              const float* __restrict__ nullg,
                                              float* __restrict__ xs) {
    int sb = blockIdx.x;
    int s = sb >> 2, b = sb & 3;
    for (int d = threadIdx.x; d < D_; d += 256) {
        float v;
        if (s == 0) v = nullg[d];
        else {
            int t0 = (s - 1) * 4;
            v = (x[((size_t)(t0 + 0) * B_ + b) * D_ + d] +
                 x[((size_t)(t0 + 1) * B_ + b) * D_ + d] +
                 x[((size_t)(t0 + 2) * B_ + b) * D_ + d] +
                 x[((size_t)(t0 + 3) * B_ + b) * D_ + d]) * 0.25f;
        }
        xs[((size_t)s * B_ + b) * D_ + d] = v;
    }
}

__global__ __launch_bounds__(256) void k_up(float* __restrict__ x,
                                            const float* __restrict__ xs,
                                            f16* __restrict__ xh) {
    int idx = blockIdx.x * 256 + threadIdx.x;
    if (idx >= T_ * B_ * D_) return;
    int d  = idx & (D_ - 1);
    int tb = idx >> 9;
    int t = tb >> 2, b = tb & 3;
    int seg = (t + 1) >> 2;
    float v = x[idx] + xs[((size_t)seg * B_ + b) * D_ + d];
    x[idx] = v; xh[idx] = (f16)v;
}

// ---------------------------------------------------------------------------
// MFMA flash attention, fp16 I/O, rel-pos via 96-row RK window (Toeplitz
// gather). K and RK staged via global_load_lds; V reg-staged transposed.
// Block = 64 q-rows x (b,n); 4 waves of 16 rows. Heavy blocks launch first.
__global__ __launch_bounds__(256) void k_attn(const f16* __restrict__ qkv,
                                              const f16* __restrict__ rkb,
                                              const float* __restrict__ rwb,
                                              const float* __restrict__ rrb,
                                              f16* __restrict__ outp, int Q) {
    __shared__ f16 Qw[64 * 64], Qr[64 * 64];
    __shared__ f16 Ks[32 * 64];
    __shared__ f16 Vt[64 * 32];
    __shared__ f16 RKs[96 * 64];
    __shared__ float S2[4][16 * 48];
    __shared__ f16 Pl[4][16 * 32];
    const int i0 = (gridDim.x - 1 - blockIdx.x) * 64;   // heavy first
    const int b  = blockIdx.y >> 3;
    const int n  = blockIdx.y & 7;
    const int tid = threadIdx.x, w = tid >> 6, lane = tid & 63;
    const int l16 = lane & 15, lg = lane >> 4;
    const int lrow = lane >> 3, lcol = (lane & 7) * 8;

    {   // stage Q (+ biases)
        int row = tid >> 2, dq = (tid & 3) * 16;
        int i = i0 + row;
        const f16* qp = qkv + ((size_t)i * B_ + b) * 1536 + n * 64 + dq;
        #pragma unroll
        for (int u = 0; u < 16; ++u) {
            float qv = (i < Q) ? (float)qp[u] : 0.f;
            Qw[row * 64 + dq + u] = (f16)(qv + rwb[n * 64 + dq + u]);
            Qr[row * 64 + dq + u] = (f16)(qv + rrb[n * 64 + dq + u]);
        }
    }
    __syncthreads();
    f16x8 aqw[2], aqr[2];
    #pragma unroll
    for (int h = 0; h < 2; ++h) {
        aqw[h] = *(const f16x8*)&Qw[(w * 16 + l16) * 64 + h * 32 + lg * 8];
        aqr[h] = *(const f16x8*)&Qr[(w * 16 + l16) * 64 + h * 32 + lg * 8];
    }

    const f32x4 z4 = {0.f, 0.f, 0.f, 0.f};
    f32x4 accv[4]; accv[0] = z4; accv[1] = z4; accv[2] = z4; accv[3] = z4;
    float mrun[4] = {-1e30f, -1e30f, -1e30f, -1e30f};
    float lrun[4] = {0.f, 0.f, 0.f, 0.f};
    const int p0 = Q - 64 - i0;
    const int jmax = min(i0 + 63, Q - 1);
    const int jj = tid >> 3, d8 = (tid & 7) * 8;

    for (int j0 = 0; j0 <= jmax; j0 += 32) {
        __syncthreads();
        // K rows (32 x 128B) + RK window (96 x 128B) via global_load_lds
        gload16(qkv + ((size_t)(j0 + w * 8 + lrow) * B_ + b) * 1536 + 512 + n * 64 + lcol,
                &Ks[(w * 8) * 64]);
        #pragma unroll
        for (int u = 0; u < 3; ++u) {
            int rb = w * 24 + u * 8;
            gload16(rkb + (long long)(p0 + j0 + rb + lrow) * 512 + n * 64 + lcol,
                    &RKs[rb * 64]);
        }
        // V reg-staged, transposed into LDS
        {
            int j = j0 + jj;
            f16x8 vv;
            if (j < Q) vv = *(const f16x8*)(qkv + ((size_t)j * B_ + b) * 1536 + 1024 + n * 64 + d8);
            else       vv = (f16x8)(f16)0.f;
            #pragma unroll
            for (int u = 0; u < 8; ++u) Vt[(d8 + u) * 32 + jj] = vv[u];
        }
        __syncthreads();
        if (j0 <= i0 + w * 16 + 15) {
            f32x4 s1[2]; s1[0] = z4; s1[1] = z4;
            #pragma unroll
            for (int f = 0; f < 2; ++f)
                #pragma unroll
                for (int h = 0; h < 2; ++h) {
                    f16x8 bv = *(const f16x8*)&Ks[(f * 16 + l16) * 64 + h * 32 + lg * 8];
                    s1[f] = __builtin_amdgcn_mfma_f32_16x16x32_f16(aqw[h], bv, s1[f], 0, 0, 0);
                }
            f32x4 s2[3]; s2[0] = z4; s2[1] = z4; s2[2] = z4;
            const int wb = 48 - 16 * w;
            #pragma unroll
            for (int f = 0; f < 3; ++f)
                #pragma unroll
                for (int h = 0; h < 2; ++h) {
                    f16x8 bv = *(const f16x8*)&RKs[(wb + f * 16 + l16) * 64 + h * 32 + lg * 8];
                    s2[f] = __builtin_amdgcn_mfma_f32_16x16x32_f16(aqr[h], bv, s2[f], 0, 0, 0);
                }
            #pragma unroll
            for (int f = 0; f < 3; ++f)
                #pragma unroll
                for (int r = 0; r < 4; ++r)
                    S2[w][(lg * 4 + r) * 48 + f * 16 + l16] = s2[f][r];
            #pragma unroll
            for (int r = 0; r < 4; ++r) {
                const int q = lg * 4 + r;
                const int iq = i0 + w * 16 + q;
                float v0 = (s1[0][r] + S2[w][q * 48 + (l16 - q + 15)]) * 0.125f;
                float v1 = (s1[1][r] + S2[w][q * 48 + (16 + l16 - q + 15)]) * 0.125f;
                const int ja = j0 + l16, jb = j0 + 16 + l16;
                if (ja > iq || ja >= Q) v0 = -1e30f;
                if (jb > iq || jb >= Q) v1 = -1e30f;
                float cm = fmaxf(v0, v1);
                cm = fmaxf(cm, __shfl_xor(cm, 1, 64));
                cm = fmaxf(cm, __shfl_xor(cm, 2, 64));
                cm = fmaxf(cm, __shfl_xor(cm, 4, 64));
                cm = fmaxf(cm, __shfl_xor(cm, 8, 64));
                float mnew = fmaxf(mrun[r], cm);
                float sc = __expf(mrun[r] - mnew);
                float pv0 = __expf(v0 - mnew);
                float pv1 = __expf(v1 - mnew);
                float ps = pv0 + pv1;
                ps += __shfl_xor(ps, 1, 64);
                ps += __shfl_xor(ps, 2, 64);
                ps += __shfl_xor(ps, 4, 64);
                ps += __shfl_xor(ps, 8, 64);
                lrun[r] = lrun[r] * sc + ps;
                mrun[r] = mnew;
                #pragma unroll
                for (int f = 0; f < 4; ++f) accv[f][r] *= sc;
                Pl[w][q * 32 + l16]      = (f16)pv0;
                Pl[w][q * 32 + 16 + l16] = (f16)pv1;
            }
            f16x8 pa = *(const f16x8*)&Pl[w][l16 * 32 + lg * 8];
            #pragma unroll
            for (int f = 0; f < 4; ++f) {
                f16x8 bv = *(const f16x8*)&Vt[(f * 16 + l16) * 32 + lg * 8];
                accv[f] = __builtin_amdgcn_mfma_f32_16x16x32_f16(pa, bv, accv[f], 0, 0, 0);
            }
        }
    }
    #pragma unroll
    for (int r = 0; r < 4; ++r) {
        int i = i0 + w * 16 + lg * 4 + r;
        if (i < Q) {
            float inv = 1.f / lrun[r];
            f16* op = outp + ((size_t)i * B_ + b) * 512 + n * 64;
            #pragma unroll
            for (int f = 0; f < 4; ++f)
                op[f * 16 + l16] = (f16)(accv[f][r] * inv);
        }
    }
}

// ---------------------------------------------------------------------------
extern "C" void kernel_launch(void* const* d_in, const int* in_sizes, int n_in,
                              void* d_out, int out_size, void* d_ws, size_t ws_size,
                              hipStream_t stream) {
    const int*   data     = (const int*)  d_in[0];
    // d_in[1] boundaries_gt: deterministic (t%4==3) -> folded into indexing
    const float* word_emb = (const float*)d_in[2];
    const float* rwb      = (const float*)d_in[3];
    const float* rrb      = (const float*)d_in[4];
    const float* nullg    = (const float*)d_in[5];
    const float* dg       = (const float*)d_in[6];
    const float* db       = (const float*)d_in[7];
    const float* qkv_w    = (const float*)d_in[8];
    const float* rk_w     = (const float*)d_in[9];
    const float* o_w      = (const float*)d_in[10];
    const float* ln1g     = (const float*)d_in[11];
    const float* ln1b     = (const float*)d_in[12];
    const float* w1       = (const float*)d_in[13];
    const float* b1       = (const float*)d_in[14];
    const float* w2       = (const float*)d_in[15];
    const float* b2       = (const float*)d_in[16];
    const float* ln2g     = (const float*)d_in[17];
    const float* ln2b     = (const float*)d_in[18];
    const float* fw       = (const float*)d_in[19];
    const float* fb       = (const float*)d_in[20];
    float* out = (float*)d_out;
    float* ws  = (float*)d_ws;

    // ---- workspace layout: fp32 region then fp16 region (~98 MB total) ----
    float* x    = ws;                          // 2097152 f
    float* tmp  = x + 2097152;                 // 2097152 f
    float* xs   = tmp + 2097152;               // 589824 f (1152 rows)
    f16* xh     = (f16*)(xs + 589824);         // 2097152 h
    f16* xsh    = xh + 2097152;                // 589824 h
    f16* attnh  = xsh + 589824;                // 2097152 h
    f16* r1h    = attnh + 2097152;             // 524288 h
    f16* r2h    = r1h + 524288;                // 163840 h (320 rows)
    f16* rkh    = r2h + 163840;                // 524288 h
    f16* bigh   = rkh + 524288;                // 8388608 h (qkv / ff1 out)
    f16* qkv_wh = bigh + 8388608;              // 6291456 h
    f16* rk_wh  = qkv_wh + 6291456;            // 2097152 h
    f16* o_wh   = rk_wh + 2097152;             // 2097152 h
    f16* w1h    = o_wh + 2097152;              // 8388608 h
    f16* w2h    = w1h + 8388608;               // 8388608 h
    f16* fwh    = w2h + 8388608;               // 131072 h

    auto conv = [&](const float* s, f16* d, int n) {
        int blocks = min(2048, (n + 1023) / 1024);
        k_f2h<<<blocks, 256, 0, stream>>>(s, d, n);
    };
    conv(qkv_w, qkv_wh, L_ * 1536 * 512);
    conv(rk_w,  rk_wh,  L_ * 512 * 512);
    conv(o_w,   o_wh,   L_ * 512 * 512);
    conv(w1,    w1h,    L_ * 2048 * 512);
    conv(w2,    w2h,    L_ * 512 * 2048);
    conv(fw,    fwh,    256 * 512);

    auto gemm = [&](const f16* Xp, const f16* Wp, const float* bp, void* Yp,
                    int M, int N, int K, int out16, int act) {
        if (N <= 512 || M < 2048) {
            dim3 g((M + 63) / 64, N / 128);
            if (out16) {
                if (act) k_gemm<64, 1, 1><<<g, 256, 0, stream>>>(Xp, Wp, bp, Yp, M, N, K);
                else     k_gemm<64, 1, 0><<<g, 256, 0, stream>>>(Xp, Wp, bp, Yp, M, N, K);
            } else      k_gemm<64, 0, 0><<<g, 256, 0, stream>>>(Xp, Wp, bp, Yp, M, N, K);
        } else {
            dim3 g((M + 127) / 128, N / 128);
            if (act) k_gemm<128, 1, 1><<<g, 256, 0, stream>>>(Xp, Wp, bp, Yp, M, N, K);
            else     k_gemm<128, 1, 0><<<g, 256, 0, stream>>>(Xp, Wp, bp, Yp, M, N, K);
        }
    };

    k_embed<<<8192, 256, 0, stream>>>(data, word_emb, x, xh);
    k_posemb<<<1024, 256, 0, stream>>>(r1h, 1024);
    k_posemb<<<257, 256, 0, stream>>>(r2h, 257);

    auto stage = [&](float* xb, f16* xbh, const f16* rh, int Q, int lo, int hi) {
        const int M = Q * B_;
        dim3 gA((Q + 63) / 64, B_ * H_);
        for (int i = lo; i < hi; ++i) {
            gemm(xbh, qkv_wh + (size_t)i * 1536 * 512, nullptr, bigh, M, 1536, 512, 1, 0);
            gemm(rh, rk_wh + (size_t)i * 512 * 512, nullptr, rkh, Q, 512, 512, 1, 0);
            k_attn<<<gA, 256, 0, stream>>>(bigh, rkh, rwb, rrb, attnh, Q);
            gemm(attnh, o_wh + (size_t)i * 512 * 512, nullptr, tmp, M, 512, 512, 0, 0);
            k_ln<<<M, 256, 0, stream>>>(xb, tmp, ln1g + (size_t)i * 512, ln1b + (size_t)i * 512, xbh);
            gemm(xbh, w1h + (size_t)i * 2048 * 512, b1 + (size_t)i * 2048, bigh, M, 2048, 512, 1, 1);
            gemm(bigh, w2h + (size_t)i * 512 * 2048, b2 + (size_t)i * 512, tmp, M, 512, 2048, 0, 0);
            k_ln<<<M, 256, 0, stream>>>(xb, tmp, ln2g + (size_t)i * 512, ln2b + (size_t)i * 512, xbh);
        }
    };

    stage(x, xh, r1h, 1024, 0, 2);                               // pre
    k_down<<<(S_ + 1) * B_, 256, 0, stream>>>(x, nullg, xs);     // mean-pool + null
    k_ln<<<(S_ + 1) * B_, 256, 0, stream>>>(xs, nullptr, dg, db, xsh);
    stage(xs, xsh, r2h, S_ + 1, 2, 6);                           // shortened
    k_up<<<8192, 256, 0, stream>>>(x, xs, xh);                   // upsample + residual
    stage(x, xh, r1h, 1024, 6, 8);                               // post
    gemm(xh, fwh, fb, out, T_ * B_, V_, 512, 0, 0);              // logits
}

// Round 4
// 1191.188 us; speedup vs baseline: 4.6610x; 1.2046x over previous
//
#include <hip/hip_runtime.h>
#include <math.h>

#define T_  1024
#define B_  4
#define D_  512
#define H_  8
#define DH_ 64
#define DI_ 2048
#define V_  256
#define L_  8
#define S_  256   // segments

typedef _Float16 f16;
typedef f16   f16x8 __attribute__((ext_vector_type(8)));
typedef float f32x4 __attribute__((ext_vector_type(4)));

__device__ __forceinline__ void gload16(const void* g, void* l) {
    __builtin_amdgcn_global_load_lds(
        (const __attribute__((address_space(1))) void*)g,
        (__attribute__((address_space(3))) void*)l, 16, 0, 0);
}

// ---------------------------------------------------------------------------
__global__ __launch_bounds__(256) void k_f2h(const float* __restrict__ s,
                                             f16* __restrict__ d, int n) {
    int i = (blockIdx.x * 256 + threadIdx.x) * 4;
    int stride = gridDim.x * 1024;
    for (; i < n; i += stride) {
        float4 v = *(const float4*)(s + i);
        d[i + 0] = (f16)v.x; d[i + 1] = (f16)v.y;
        d[i + 2] = (f16)v.z; d[i + 3] = (f16)v.w;
    }
}

// ---------------------------------------------------------------------------
__global__ __launch_bounds__(256) void k_embed(const int* __restrict__ data,
                                               const float* __restrict__ emb,
                                               float* __restrict__ x,
                                               f16* __restrict__ xh) {
    int idx = blockIdx.x * 256 + threadIdx.x;
    if (idx >= T_ * B_ * D_) return;
    int d  = idx & (D_ - 1);
    int tb = idx >> 9;
    float v = emb[(size_t)data[tb] * D_ + d];
    x[idx] = v; xh[idx] = (f16)v;
}

// ---------------------------------------------------------------------------
__global__ __launch_bounds__(256) void k_posemb(f16* __restrict__ r, int qlen) {
    int p = blockIdx.x;
    int k = threadIdx.x;
    float pos = (float)(qlen - 1 - p);
    float inv = powf(10000.f, -((float)k) / 256.f);
    float ang = pos * inv;
    r[(size_t)p * D_ + k]       = (f16)sinf(ang);
    r[(size_t)p * D_ + 256 + k] = (f16)cosf(ang);
}

// ---------------------------------------------------------------------------
// MFMA fp16 GEMM, m97 structure (unchanged from R3).
template<int BM, int OUT16, int ACT>
__global__ __launch_bounds__(256) void k_gemm(const f16* __restrict__ X,
                                              const f16* __restrict__ W,
                                              const float* __restrict__ bias,
                                              void* __restrict__ Yv,
                                              int M, int N, int K) {
    __shared__ f16 As[BM * 64];
    __shared__ f16 Bs[128 * 64];
    const int tid = threadIdx.x, w = tid >> 6, lane = tid & 63;
    const int l16 = lane & 15, lg = lane >> 4;
    const int bm = blockIdx.x * BM, bn = blockIdx.y * 128;
    const int lrow = lane >> 3, lcol = (lane & 7) * 8;
    constexpr int AI = BM / 32;
    constexpr int MI = 4;
    constexpr int NJ = (BM == 128) ? 4 : 2;
    const int rbase = (BM == 128) ? (w >> 1) * 64 : 0;
    const int cbase = (BM == 128) ? (w & 1) * 64 : w * 32;
    const f32x4 z4 = {0.f, 0.f, 0.f, 0.f};
    f32x4 acc[MI][NJ];
    #pragma unroll
    for (int i = 0; i < MI; ++i)
        #pragma unroll
        for (int j = 0; j < NJ; ++j) acc[i][j] = z4;

    for (int k0 = 0; k0 < K; k0 += 64) {
        __syncthreads();
        #pragma unroll
        for (int u = 0; u < AI; ++u) {
            int rb = w * (8 * AI) + u * 8;
            gload16(X + (size_t)(bm + rb + lrow) * K + k0 + lcol, &As[rb * 64]);
        }
        #pragma unroll
        for (int u = 0; u < 4; ++u) {
            int rb = w * 32 + u * 8;
            gload16(W + (size_t)(bn + rb + lrow) * K + k0 + lcol, &Bs[rb * 64]);
        }
        __syncthreads();
        #pragma unroll
        for (int h = 0; h < 2; ++h) {
            f16x8 af[MI], bf[NJ];
            #pragma unroll
            for (int i = 0; i < MI; ++i)
                af[i] = *(const f16x8*)&As[(rbase + i * 16 + l16) * 64 + h * 32 + lg * 8];
            #pragma unroll
            for (int j = 0; j < NJ; ++j)
                bf[j] = *(const f16x8*)&Bs[(cbase + j * 16 + l16) * 64 + h * 32 + lg * 8];
            #pragma unroll
            for (int i = 0; i < MI; ++i)
                #pragma unroll
                for (int j = 0; j < NJ; ++j)
                    acc[i][j] = __builtin_amdgcn_mfma_f32_16x16x32_f16(af[i], bf[j], acc[i][j], 0, 0, 0);
        }
    }
    #pragma unroll
    for (int i = 0; i < MI; ++i) {
        #pragma unroll
        for (int r = 0; r < 4; ++r) {
            int row = bm + rbase + i * 16 + lg * 4 + r;
            if (row >= M) continue;
            int colb = bn + cbase + l16;
            #pragma unroll
            for (int j = 0; j < NJ; ++j) {
                float v = acc[i][j][r];
                if (bias) v += bias[colb + j * 16];
                if (ACT) v = fmaxf(v, 0.f);
                if (OUT16) ((f16*)Yv)[(size_t)row * N + colb + j * 16] = (f16)v;
                else       ((float*)Yv)[(size_t)row * N + colb + j * 16] = v;
            }
        }
    }
}

// ---------------------------------------------------------------------------
// Add + LayerNorm, one WAVE per row (no cross-wave sync), 4 rows/block.
__global__ __launch_bounds__(256) void k_ln(float* __restrict__ x,
                                            const float* __restrict__ add,
                                            const float* __restrict__ g,
                                            const float* __restrict__ b,
                                            f16* __restrict__ xh, int rows) {
    int row = blockIdx.x * 4 + (threadIdx.x >> 6);
    if (row >= rows) return;
    int lane = threadIdx.x & 63;
    float* xr = x + (size_t)row * D_ + lane * 8;
    float v[8];
    {
        float4 a0 = *(const float4*)xr;
        float4 a1 = *(const float4*)(xr + 4);
        v[0] = a0.x; v[1] = a0.y; v[2] = a0.z; v[3] = a0.w;
        v[4] = a1.x; v[5] = a1.y; v[6] = a1.z; v[7] = a1.w;
    }
    if (add) {
        const float* ar = add + (size_t)row * D_ + lane * 8;
        float4 a0 = *(const float4*)ar;
        float4 a1 = *(const float4*)(ar + 4);
        v[0] += a0.x; v[1] += a0.y; v[2] += a0.z; v[3] += a0.w;
        v[4] += a1.x; v[5] += a1.y; v[6] += a1.z; v[7] += a1.w;
    }
    float s = 0.f, sq = 0.f;
    #pragma unroll
    for (int u = 0; u < 8; ++u) { s += v[u]; sq += v[u] * v[u]; }
    #pragma unroll
    for (int off = 1; off < 64; off <<= 1) {
        s  += __shfl_xor(s,  off, 64);
        sq += __shfl_xor(sq, off, 64);
    }
    float mean = s * (1.f / (float)D_);
    float var  = sq * (1.f / (float)D_) - mean * mean;
    float rs   = rsqrtf(var + 1e-5f);
    const float* gp = g + lane * 8;
    const float* bp = b + lane * 8;
    float4 g0 = *(const float4*)gp, g1 = *(const float4*)(gp + 4);
    float4 b0 = *(const float4*)bp, b1 = *(const float4*)(bp + 4);
    float gg[8] = {g0.x, g0.y, g0.z, g0.w, g1.x, g1.y, g1.z, g1.w};
    float bb[8] = {b0.x, b0.y, b0.z, b0.w, b1.x, b1.y, b1.z, b1.w};
    float o[8];
    #pragma unroll
    for (int u = 0; u < 8; ++u) o[u] = (v[u] - mean) * rs * gg[u] + bb[u];
    *(float4*)xr       = make_float4(o[0], o[1], o[2], o[3]);
    *(float4*)(xr + 4) = make_float4(o[4], o[5], o[6], o[7]);
    f16x8 hv;
    #pragma unroll
    for (int u = 0; u < 8; ++u) hv[u] = (f16)o[u];
    *(f16x8*)(xh + (size_t)row * D_ + lane * 8) = hv;
}

// ---------------------------------------------------------------------------
__global__ __launch_bounds__(256) void k_down(const float* __restrict__ x,
                                              const float* __restrict__ nullg,
                                              float* __restrict__ xs) {
    int sb = blockIdx.x;
    int s = sb >> 2, b = sb & 3;
    for (int d = threadIdx.x; d < D_; d += 256) {
        float v;
        if (s == 0) v = nullg[d];
        else {
            int t0 = (s - 1) * 4;
            v = (x[((size_t)(t0 + 0) * B_ + b) * D_ + d] +
                 x[((size_t)(t0 + 1) * B_ + b) * D_ + d] +
                 x[((size_t)(t0 + 2) * B_ + b) * D_ + d] +
                 x[((size_t)(t0 + 3) * B_ + b) * D_ + d]) * 0.25f;
        }
        xs[((size_t)s * B_ + b) * D_ + d] = v;
    }
}

__global__ __launch_bounds__(256) void k_up(float* __restrict__ x,
                                            const float* __restrict__ xs,
                                            f16* __restrict__ xh) {
    int idx = blockIdx.x * 256 + threadIdx.x;
    if (idx >= T_ * B_ * D_) return;
    int d  = idx & (D_ - 1);
    int tb = idx >> 9;
    int t = tb >> 2, b = tb & 3;
    int seg = (t + 1) >> 2;
    float v = x[idx] + xs[((size_t)seg * B_ + b) * D_ + d];
    x[idx] = v; xh[idx] = (f16)v;
}

// ---------------------------------------------------------------------------
// MFMA flash attention v2: KVBLK=64, XOR-swizzled LDS (conflict-free reads),
// circular 192-row RK window (stage 64 new rows/chunk), shuffle-based Toeplitz
// gather for the BD term (no LDS round-trip), 1-deep prefetch pipeline.
// Block = 64 q-rows x (b,n); 4 waves of 16 rows. ~50 KB LDS -> 3 blocks/CU.
__global__ __launch_bounds__(256) void k_attn(const f16* __restrict__ qkv,
                                              const f16* __restrict__ rkb,
                                              const float* __restrict__ rwb,
                                              const float* __restrict__ rrb,
                                              f16* __restrict__ outp, int Q) {
    __shared__ f16 RKs[192 * 64];     // circular window; aliased for Q staging
    __shared__ f16 Ks[64 * 64];
    __shared__ f16 Vt[64 * 72];       // [d][jj] padded
    __shared__ f16 Pl[4][16 * 72];    // per-wave [q][jj] padded
    f16* Qw = RKs;                    // prologue alias
    f16* Qr = RKs + 4096;

    const int it = gridDim.x - 1 - blockIdx.x;          // heavy first
    const int i0 = it * 64;
    const int nt = it + 1;                              // 64-key chunks
    const int b  = blockIdx.y >> 3;
    const int n  = blockIdx.y & 7;
    const int tid = threadIdx.x, w = tid >> 6, lane = tid & 63;
    const int l16 = lane & 15, lg = lane >> 4;
    const int xsw = (l16 & 7) << 3;                     // read-side swizzle
    const int gr8 = lane >> 3;                          // gload row-in-8
    const int gsl = ((lane & 7) ^ gr8) * 8;             // pre-swizzled col slot

    // ---- stage Q (+biases) into RK alias, swizzled ----
    {
        int row = tid >> 2, dq = (tid & 3) * 16;
        const f16* qp = qkv + ((size_t)(i0 + row) * B_ + b) * 1536 + n * 64 + dq;
        f16x8 q0 = *(const f16x8*)qp, q1 = *(const f16x8*)(qp + 8);
        int rsw = (row & 7) << 3;
        #pragma unroll
        for (int u = 0; u < 8; ++u) {
            float qa = (float)q0[u], qb2 = (float)q1[u];
            Qw[row * 64 + ((dq + u) ^ rsw)]     = (f16)(qa + rwb[n * 64 + dq + u]);
            Qw[row * 64 + ((dq + 8 + u) ^ rsw)] = (f16)(qb2 + rwb[n * 64 + dq + 8 + u]);
            Qr[row * 64 + ((dq + u) ^ rsw)]     = (f16)(qa + rrb[n * 64 + dq + u]);
            Qr[row * 64 + ((dq + 8 + u) ^ rsw)] = (f16)(qb2 + rrb[n * 64 + dq + 8 + u]);
        }
    }
    __syncthreads();
    f16x8 aqw[2], aqr[2];
    #pragma unroll
    for (int h = 0; h < 2; ++h) {
        aqw[h] = *(const f16x8*)&Qw[(w * 16 + l16) * 64 + ((h * 32 + lg * 8) ^ xsw)];
        aqr[h] = *(const f16x8*)&Qr[(w * 16 + l16) * 64 + ((h * 32 + lg * 8) ^ xsw)];
    }
    __syncthreads();   // all Q-frag reads done before RK staging overwrites

    const long long pb = (long long)Q - 64 - i0;
    // ---- prologue staging: RK slots 0..127, K chunk 0, V chunk 0 -> regs ----
    #pragma unroll
    for (int u = 0; u < 4; ++u) {
        int rb = w * 32 + u * 8;
        long long p = pb + rb + gr8;
        gload16(rkb + p * 512 + n * 64 + gsl, &RKs[rb * 64]);
    }
    #pragma unroll
    for (int u = 0; u < 2; ++u) {
        int rb = w * 16 + u * 8;
        gload16(qkv + ((size_t)(rb + gr8) * B_ + b) * 1536 + 512 + n * 64 + gsl, &Ks[rb * 64]);
    }
    const int vjj = tid >> 2, vdb = (tid & 3) * 16;
    f16x8 vr0, vr1;
    {
        const f16* vp = qkv + ((size_t)vjj * B_ + b) * 1536 + 1024 + n * 64 + vdb;
        vr0 = *(const f16x8*)vp; vr1 = *(const f16x8*)(vp + 8);
    }

    const f32x4 z4 = {0.f, 0.f, 0.f, 0.f};
    f32x4 acc[4]; acc[0] = z4; acc[1] = z4; acc[2] = z4; acc[3] = z4;
    float mrun[4] = {-1e30f, -1e30f, -1e30f, -1e30f};
    float lrun[4] = {0.f, 0.f, 0.f, 0.f};
    const int wb = 48 - w * 16;
    int base = 0;                                       // (64t) % 192

    for (int t = 0; t < nt; ++t) {
        const int j0 = t * 64;
        __syncthreads();   // A: staged K/RK in LDS, Vregs arrived, Vt free
        // write V tile (transposed, swizzled)
        #pragma unroll
        for (int u = 0; u < 8; ++u) {
            Vt[(vdb + u) * 72 + (vjj ^ ((u & 7) << 3))]     = vr0[u];
            Vt[(vdb + 8 + u) * 72 + (vjj ^ ((u & 7) << 3))] = vr1[u];
        }
        // prefetch RK rows for window t+1 (disjoint circular slots)
        if (t + 1 < nt) {
            int sb = base + 128; if (sb >= 192) sb -= 192;
            #pragma unroll
            for (int u = 0; u < 2; ++u) {
                int rb = w * 16 + u * 8;
                long long p = pb + j0 + 128 + rb + gr8;
                gload16(rkb + p * 512 + n * 64 + gsl, &RKs[(sb + rb) * 64]);
            }
        }
        // S1 = Qw . K^T  (16 x 64)
        f32x4 s1[4]; s1[0] = z4; s1[1] = z4; s1[2] = z4; s1[3] = z4;
        #pragma unroll
        for (int f = 0; f < 4; ++f)
            #pragma unroll
            for (int h = 0; h < 2; ++h) {
                f16x8 bv = *(const f16x8*)&Ks[(f * 16 + l16) * 64 + ((h * 32 + lg * 8) ^ xsw)];
                s1[f] = __builtin_amdgcn_mfma_f32_16x16x32_f16(aqw[h], bv, s1[f], 0, 0, 0);
            }
        // prefetch V(t+1) -> regs
        if (t + 1 < nt) {
            const f16* vp = qkv + ((size_t)(j0 + 64 + vjj) * B_ + b) * 1536 + 1024 + n * 64 + vdb;
            vr0 = *(const f16x8*)vp; vr1 = *(const f16x8*)(vp + 8);
        }
        // S2 = Qr . RKwin^T  (16 x 80, shifted window per wave)
        f32x4 s2[5]; s2[0] = z4; s2[1] = z4; s2[2] = z4; s2[3] = z4; s2[4] = z4;
        #pragma unroll
        for (int f = 0; f < 5; ++f) {
            int slot = base + wb + f * 16 + l16; if (slot >= 192) slot -= 192;
            #pragma unroll
            for (int h = 0; h < 2; ++h) {
                f16x8 bv = *(const f16x8*)&RKs[slot * 64 + ((h * 32 + lg * 8) ^ xsw)];
                s2[f] = __builtin_amdgcn_mfma_f32_16x16x32_f16(aqr[h], bv, s2[f], 0, 0, 0);
            }
        }
        // gather BD via shuffles + online softmax, per accumulator row r
        #pragma unroll
        for (int r = 0; r < 4; ++r) {
            const int q = lg * 4 + r;
            const int iq = i0 + w * 16 + q;
            const int src = (lane & 48) | ((l16 + 15 - q) & 15);
            float g0 = __shfl(s2[0][r], src, 64);
            float g1 = __shfl(s2[1][r], src, 64);
            float g2 = __shfl(s2[2][r], src, 64);
            float g3 = __shfl(s2[3][r], src, 64);
            float g4 = __shfl(s2[4][r], src, 64);
            const bool hi = l16 > q;
            float sv[4];
            sv[0] = (s1[0][r] + (hi ? g1 : g0)) * 0.125f;
            sv[1] = (s1[1][r] + (hi ? g2 : g1)) * 0.125f;
            sv[2] = (s1[2][r] + (hi ? g3 : g2)) * 0.125f;
            sv[3] = (s1[3][r] + (hi ? g4 : g3)) * 0.125f;
            #pragma unroll
            for (int h = 0; h < 4; ++h) {
                int j = j0 + h * 16 + l16;
                if (j > iq || j >= Q) sv[h] = -1e30f;
            }
            float cm = fmaxf(fmaxf(sv[0], sv[1]), fmaxf(sv[2], sv[3]));
            cm = fmaxf(cm, __shfl_xor(cm, 1, 64));
            cm = fmaxf(cm, __shfl_xor(cm, 2, 64));
            cm = fmaxf(cm, __shfl_xor(cm, 4, 64));
            cm = fmaxf(cm, __shfl_xor(cm, 8, 64));
            float mnew = fmaxf(mrun[r], cm);
            float sc = __expf(mrun[r] - mnew);
            float p0 = __expf(sv[0] - mnew), p1 = __expf(sv[1] - mnew);
            float p2 = __expf(sv[2] - mnew), p3 = __expf(sv[3] - mnew);
            float ps = p0 + p1 + p2 + p3;
            ps += __shfl_xor(ps, 1, 64);
            ps += __shfl_xor(ps, 2, 64);
            ps += __shfl_xor(ps, 4, 64);
            ps += __shfl_xor(ps, 8, 64);
            lrun[r] = lrun[r] * sc + ps;
            mrun[r] = mnew;
            acc[0][r] *= sc; acc[1][r] *= sc; acc[2][r] *= sc; acc[3][r] *= sc;
            Pl[w][q * 72 + l16]      = (f16)p0;
            Pl[w][q * 72 + 16 + l16] = (f16)p1;
            Pl[w][q * 72 + 32 + l16] = (f16)p2;
            Pl[w][q * 72 + 48 + l16] = (f16)p3;
        }
        __syncthreads();   // B: Vt (all waves) + Pl visible
        // PV: A = P (16x64), B = V via transposed swizzled LDS
        f16x8 pa0 = *(const f16x8*)&Pl[w][l16 * 72 + lg * 8];
        f16x8 pa1 = *(const f16x8*)&Pl[w][l16 * 72 + 32 + lg * 8];
        #pragma unroll
        for (int f = 0; f < 4; ++f) {
            f16x8 bv0 = *(const f16x8*)&Vt[(f * 16 + l16) * 72 + ((lg * 8) ^ xsw)];
            acc[f] = __builtin_amdgcn_mfma_f32_16x16x32_f16(pa0, bv0, acc[f], 0, 0, 0);
            f16x8 bv1 = *(const f16x8*)&Vt[(f * 16 + l16) * 72 + ((32 + lg * 8) ^ xsw)];
            acc[f] = __builtin_amdgcn_mfma_f32_16x16x32_f16(pa1, bv1, acc[f], 0, 0, 0);
        }
        // prefetch K(t+1) (safe: all waves past S1 via barrier B)
        if (t + 1 < nt) {
            #pragma unroll
            for (int u = 0; u < 2; ++u) {
                int rb = w * 16 + u * 8;
                gload16(qkv + ((size_t)(j0 + 64 + rb + gr8) * B_ + b) * 1536 + 512 + n * 64 + gsl,
                        &Ks[rb * 64]);
            }
        }
        base += 64; if (base >= 192) base -= 192;
    }
    // epilogue
    #pragma unroll
    for (int r = 0; r < 4; ++r) {
        int i = i0 + w * 16 + lg * 4 + r;
        if (i < Q) {
            float inv = 1.f / lrun[r];
            f16* op = outp + ((size_t)i * B_ + b) * 512 + n * 64;
            #pragma unroll
            for (int f = 0; f < 4; ++f)
                op[f * 16 + l16] = (f16)(acc[f][r] * inv);
        }
    }
}

// ---------------------------------------------------------------------------
extern "C" void kernel_launch(void* const* d_in, const int* in_sizes, int n_in,
                              void* d_out, int out_size, void* d_ws, size_t ws_size,
                              hipStream_t stream) {
    const int*   data     = (const int*)  d_in[0];
    const float* word_emb = (const float*)d_in[2];
    const float* rwb      = (const float*)d_in[3];
    const float* rrb      = (const float*)d_in[4];
    const float* nullg    = (const float*)d_in[5];
    const float* dg       = (const float*)d_in[6];
    const float* db       = (const float*)d_in[7];
    const float* qkv_w    = (const float*)d_in[8];
    const float* rk_w     = (const float*)d_in[9];
    const float* o_w      = (const float*)d_in[10];
    const float* ln1g     = (const float*)d_in[11];
    const float* ln1b     = (const float*)d_in[12];
    const float* w1       = (const float*)d_in[13];
    const float* b1       = (const float*)d_in[14];
    const float* w2       = (const float*)d_in[15];
    const float* b2       = (const float*)d_in[16];
    const float* ln2g     = (const float*)d_in[17];
    const float* ln2b     = (const float*)d_in[18];
    const float* fw       = (const float*)d_in[19];
    const float* fb       = (const float*)d_in[20];
    float* out = (float*)d_out;
    float* ws  = (float*)d_ws;

    float* x    = ws;                          // 2097152 f
    float* tmp  = x + 2097152;                 // 2097152 f
    float* xs   = tmp + 2097152;               // 589824 f
    f16* xh     = (f16*)(xs + 589824);         // 2097152 h
    f16* xsh    = xh + 2097152;                // 589824 h
    f16* attnh  = xsh + 589824;                // 2097152 h
    f16* r1h    = attnh + 2097152;             // 524288 h
    f16* r2h    = r1h + 524288;                // 163840 h
    f16* rkh    = r2h + 163840;                // 524288 h
    f16* bigh   = rkh + 524288;                // 8388608 h
    f16* qkv_wh = bigh + 8388608;              // 6291456 h
    f16* rk_wh  = qkv_wh + 6291456;            // 2097152 h
    f16* o_wh   = rk_wh + 2097152;             // 2097152 h
    f16* w1h    = o_wh + 2097152;              // 8388608 h
    f16* w2h    = w1h + 8388608;               // 8388608 h
    f16* fwh    = w2h + 8388608;               // 131072 h

    auto conv = [&](const float* s, f16* d, int n) {
        int blocks = min(2048, (n + 1023) / 1024);
        k_f2h<<<blocks, 256, 0, stream>>>(s, d, n);
    };
    conv(qkv_w, qkv_wh, L_ * 1536 * 512);
    conv(rk_w,  rk_wh,  L_ * 512 * 512);
    conv(o_w,   o_wh,   L_ * 512 * 512);
    conv(w1,    w1h,    L_ * 2048 * 512);
    conv(w2,    w2h,    L_ * 512 * 2048);
    conv(fw,    fwh,    256 * 512);

    auto gemm = [&](const f16* Xp, const f16* Wp, const float* bp, void* Yp,
                    int M, int N, int K, int out16, int act) {
        if (N <= 512 || M < 2048) {
            dim3 g((M + 63) / 64, N / 128);
            if (out16) {
                if (act) k_gemm<64, 1, 1><<<g, 256, 0, stream>>>(Xp, Wp, bp, Yp, M, N, K);
                else     k_gemm<64, 1, 0><<<g, 256, 0, stream>>>(Xp, Wp, bp, Yp, M, N, K);
            } else      k_gemm<64, 0, 0><<<g, 256, 0, stream>>>(Xp, Wp, bp, Yp, M, N, K);
        } else {
            dim3 g((M + 127) / 128, N / 128);
            if (act) k_gemm<128, 1, 1><<<g, 256, 0, stream>>>(Xp, Wp, bp, Yp, M, N, K);
            else     k_gemm<128, 1, 0><<<g, 256, 0, stream>>>(Xp, Wp, bp, Yp, M, N, K);
        }
    };

    k_embed<<<8192, 256, 0, stream>>>(data, word_emb, x, xh);
    k_posemb<<<1024, 256, 0, stream>>>(r1h, 1024);
    k_posemb<<<257, 256, 0, stream>>>(r2h, 257);

    auto stage = [&](float* xb, f16* xbh, const f16* rh, int Q, int lo, int hi) {
        const int M = Q * B_;
        dim3 gA((Q + 63) / 64, B_ * H_);
        dim3 gL((M + 3) / 4);
        for (int i = lo; i < hi; ++i) {
            gemm(xbh, qkv_wh + (size_t)i * 1536 * 512, nullptr, bigh, M, 1536, 512, 1, 0);
            gemm(rh, rk_wh + (size_t)i * 512 * 512, nullptr, rkh, Q, 512, 512, 1, 0);
            k_attn<<<gA, 256, 0, stream>>>(bigh, rkh, rwb, rrb, attnh, Q);
            gemm(attnh, o_wh + (size_t)i * 512 * 512, nullptr, tmp, M, 512, 512, 0, 0);
            k_ln<<<gL, 256, 0, stream>>>(xb, tmp, ln1g + (size_t)i * 512, ln1b + (size_t)i * 512, xbh, M);
            gemm(xbh, w1h + (size_t)i * 2048 * 512, b1 + (size_t)i * 2048, bigh, M, 2048, 512, 1, 1);
            gemm(bigh, w2h + (size_t)i * 512 * 2048, b2 + (size_t)i * 512, tmp, M, 512, 2048, 0, 0);
            k_ln<<<gL, 256, 0, stream>>>(xb, tmp, ln2g + (size_t)i * 512, ln2b + (size_t)i * 512, xbh, M);
        }
    };

    stage(x, xh, r1h, 1024, 0, 2);                               // pre
    k_down<<<(S_ + 1) * B_, 256, 0, stream>>>(x, nullg, xs);     // mean-pool + null
    k_ln<<<(S_ * B_ + B_ + 3) / 4, 256, 0, stream>>>(xs, nullptr, dg, db, xsh, (S_ + 1) * B_);
    stage(xs, xsh, r2h, S_ + 1, 2, 6);                           // shortened
    k_up<<<8192, 256, 0, stream>>>(x, xs, xh);                   // upsample + residual
    stage(x, xh, r1h, 1024, 6, 8);                               // post
    gemm(xh, fwh, fb, out, T_ * B_, V_, 512, 0, 0);              // logits
}

// Round 5
// 1167.945 us; speedup vs baseline: 4.7538x; 1.0199x over previous
//
#include <hip/hip_runtime.h>
#include <math.h>

#define T_  1024
#define B_  4
#define D_  512
#define H_  8
#define DH_ 64
#define DI_ 2048
#define V_  256
#define L_  8
#define S_  256   // segments

typedef _Float16 f16;
typedef f16   f16x8 __attribute__((ext_vector_type(8)));
typedef float f32x4 __attribute__((ext_vector_type(4)));

__device__ __forceinline__ void gload16(const void* g, void* l) {
    __builtin_amdgcn_global_load_lds(
        (const __attribute__((address_space(1))) void*)g,
        (__attribute__((address_space(3))) void*)l, 16, 0, 0);
}

// ---------------------------------------------------------------------------
__global__ __launch_bounds__(256) void k_f2h(const float* __restrict__ s,
                                             f16* __restrict__ d, int n) {
    int i = (blockIdx.x * 256 + threadIdx.x) * 4;
    int stride = gridDim.x * 1024;
    for (; i < n; i += stride) {
        float4 v = *(const float4*)(s + i);
        d[i + 0] = (f16)v.x; d[i + 1] = (f16)v.y;
        d[i + 2] = (f16)v.z; d[i + 3] = (f16)v.w;
    }
}

// ---------------------------------------------------------------------------
__global__ __launch_bounds__(256) void k_embed(const int* __restrict__ data,
                                               const float* __restrict__ emb,
                                               float* __restrict__ x,
                                               f16* __restrict__ xh) {
    int idx = blockIdx.x * 256 + threadIdx.x;
    if (idx >= T_ * B_ * D_) return;
    int d  = idx & (D_ - 1);
    int tb = idx >> 9;
    float v = emb[(size_t)data[tb] * D_ + d];
    x[idx] = v; xh[idx] = (f16)v;
}

// ---------------------------------------------------------------------------
__global__ __launch_bounds__(256) void k_posemb(f16* __restrict__ r, int qlen) {
    int p = blockIdx.x;
    int k = threadIdx.x;
    float pos = (float)(qlen - 1 - p);
    float inv = powf(10000.f, -((float)k) / 256.f);
    float ang = pos * inv;
    r[(size_t)p * D_ + k]       = (f16)sinf(ang);
    r[(size_t)p * D_ + 256 + k] = (f16)cosf(ang);
}

// ---------------------------------------------------------------------------
// MFMA fp16 GEMM, m97 structure + XCD-chunked block swizzle (T1).
template<int BM, int OUT16, int ACT>
__global__ __launch_bounds__(256) void k_gemm(const f16* __restrict__ X,
                                              const f16* __restrict__ W,
                                              const float* __restrict__ bias,
                                              void* __restrict__ Yv,
                                              int M, int N, int K) {
    __shared__ f16 As[BM * 64];
    __shared__ f16 Bs[128 * 64];
    const int tid = threadIdx.x, w = tid >> 6, lane = tid & 63;
    const int l16 = lane & 15, lg = lane >> 4;
    int nwg = gridDim.x * gridDim.y;
    int bid = blockIdx.y * gridDim.x + blockIdx.x;
    if ((nwg & 7) == 0) bid = (bid & 7) * (nwg >> 3) + (bid >> 3);   // XCD chunked
    const int bm = (bid % gridDim.x) * BM, bn = (bid / gridDim.x) * 128;
    const int lrow = lane >> 3, lcol = (lane & 7) * 8;
    constexpr int AI = BM / 32;
    constexpr int MI = 4;
    constexpr int NJ = (BM == 128) ? 4 : 2;
    const int rbase = (BM == 128) ? (w >> 1) * 64 : 0;
    const int cbase = (BM == 128) ? (w & 1) * 64 : w * 32;
    const f32x4 z4 = {0.f, 0.f, 0.f, 0.f};
    f32x4 acc[MI][NJ];
    #pragma unroll
    for (int i = 0; i < MI; ++i)
        #pragma unroll
        for (int j = 0; j < NJ; ++j) acc[i][j] = z4;

    for (int k0 = 0; k0 < K; k0 += 64) {
        __syncthreads();
        #pragma unroll
        for (int u = 0; u < AI; ++u) {
            int rb = w * (8 * AI) + u * 8;
            gload16(X + (size_t)(bm + rb + lrow) * K + k0 + lcol, &As[rb * 64]);
        }
        #pragma unroll
        for (int u = 0; u < 4; ++u) {
            int rb = w * 32 + u * 8;
            gload16(W + (size_t)(bn + rb + lrow) * K + k0 + lcol, &Bs[rb * 64]);
        }
        __syncthreads();
        __builtin_amdgcn_s_setprio(1);
        #pragma unroll
        for (int h = 0; h < 2; ++h) {
            f16x8 af[MI], bf[NJ];
            #pragma unroll
            for (int i = 0; i < MI; ++i)
                af[i] = *(const f16x8*)&As[(rbase + i * 16 + l16) * 64 + h * 32 + lg * 8];
            #pragma unroll
            for (int j = 0; j < NJ; ++j)
                bf[j] = *(const f16x8*)&Bs[(cbase + j * 16 + l16) * 64 + h * 32 + lg * 8];
            #pragma unroll
            for (int i = 0; i < MI; ++i)
                #pragma unroll
                for (int j = 0; j < NJ; ++j)
                    acc[i][j] = __builtin_amdgcn_mfma_f32_16x16x32_f16(af[i], bf[j], acc[i][j], 0, 0, 0);
        }
        __builtin_amdgcn_s_setprio(0);
    }
    #pragma unroll
    for (int i = 0; i < MI; ++i) {
        #pragma unroll
        for (int r = 0; r < 4; ++r) {
            int row = bm + rbase + i * 16 + lg * 4 + r;
            if (row >= M) continue;
            int colb = bn + cbase + l16;
            #pragma unroll
            for (int j = 0; j < NJ; ++j) {
                float v = acc[i][j][r];
                if (bias) v += bias[colb + j * 16];
                if (ACT) v = fmaxf(v, 0.f);
                if (OUT16) ((f16*)Yv)[(size_t)row * N + colb + j * 16] = (f16)v;
                else       ((float*)Yv)[(size_t)row * N + colb + j * 16] = v;
            }
        }
    }
}

// ---------------------------------------------------------------------------
// Add + LayerNorm, one WAVE per row, 4 rows/block.
__global__ __launch_bounds__(256) void k_ln(float* __restrict__ x,
                                            const float* __restrict__ add,
                                            const float* __restrict__ g,
                                            const float* __restrict__ b,
                                            f16* __restrict__ xh, int rows) {
    int row = blockIdx.x * 4 + (threadIdx.x >> 6);
    if (row >= rows) return;
    int lane = threadIdx.x & 63;
    float* xr = x + (size_t)row * D_ + lane * 8;
    float v[8];
    {
        float4 a0 = *(const float4*)xr;
        float4 a1 = *(const float4*)(xr + 4);
        v[0] = a0.x; v[1] = a0.y; v[2] = a0.z; v[3] = a0.w;
        v[4] = a1.x; v[5] = a1.y; v[6] = a1.z; v[7] = a1.w;
    }
    if (add) {
        const float* ar = add + (size_t)row * D_ + lane * 8;
        float4 a0 = *(const float4*)ar;
        float4 a1 = *(const float4*)(ar + 4);
        v[0] += a0.x; v[1] += a0.y; v[2] += a0.z; v[3] += a0.w;
        v[4] += a1.x; v[5] += a1.y; v[6] += a1.z; v[7] += a1.w;
    }
    float s = 0.f, sq = 0.f;
    #pragma unroll
    for (int u = 0; u < 8; ++u) { s += v[u]; sq += v[u] * v[u]; }
    #pragma unroll
    for (int off = 1; off < 64; off <<= 1) {
        s  += __shfl_xor(s,  off, 64);
        sq += __shfl_xor(sq, off, 64);
    }
    float mean = s * (1.f / (float)D_);
    float var  = sq * (1.f / (float)D_) - mean * mean;
    float rs   = rsqrtf(var + 1e-5f);
    const float* gp = g + lane * 8;
    const float* bp = b + lane * 8;
    float4 g0 = *(const float4*)gp, g1 = *(const float4*)(gp + 4);
    float4 b0 = *(const float4*)bp, b1 = *(const float4*)(bp + 4);
    float gg[8] = {g0.x, g0.y, g0.z, g0.w, g1.x, g1.y, g1.z, g1.w};
    float bb[8] = {b0.x, b0.y, b0.z, b0.w, b1.x, b1.y, b1.z, b1.w};
    float o[8];
    #pragma unroll
    for (int u = 0; u < 8; ++u) o[u] = (v[u] - mean) * rs * gg[u] + bb[u];
    *(float4*)xr       = make_float4(o[0], o[1], o[2], o[3]);
    *(float4*)(xr + 4) = make_float4(o[4], o[5], o[6], o[7]);
    f16x8 hv;
    #pragma unroll
    for (int u = 0; u < 8; ++u) hv[u] = (f16)o[u];
    *(f16x8*)(xh + (size_t)row * D_ + lane * 8) = hv;
}

// ---------------------------------------------------------------------------
// Fused downsample (mean-pool + null row) + LayerNorm. Wave per output row.
__global__ __launch_bounds__(256) void k_downln(const float* __restrict__ x,
                                                const float* __restrict__ nullg,
                                                const float* __restrict__ g,
                                                const float* __restrict__ bi,
                                                float* __restrict__ xs,
                                                f16* __restrict__ xsh) {
    int row = blockIdx.x * 4 + (threadIdx.x >> 6);
    if (row >= (S_ + 1) * B_) return;
    int lane = threadIdx.x & 63;
    int s = row >> 2, b = row & 3;
    float v[8];
    if (s == 0) {
        const float* np = nullg + lane * 8;
        float4 a0 = *(const float4*)np, a1 = *(const float4*)(np + 4);
        v[0] = a0.x; v[1] = a0.y; v[2] = a0.z; v[3] = a0.w;
        v[4] = a1.x; v[5] = a1.y; v[6] = a1.z; v[7] = a1.w;
    } else {
        int t0 = (s - 1) * 4;
        #pragma unroll
        for (int u = 0; u < 8; ++u) v[u] = 0.f;
        #pragma unroll
        for (int k = 0; k < 4; ++k) {
            const float* xp = x + ((size_t)(t0 + k) * B_ + b) * D_ + lane * 8;
            float4 a0 = *(const float4*)xp, a1 = *(const float4*)(xp + 4);
            v[0] += a0.x; v[1] += a0.y; v[2] += a0.z; v[3] += a0.w;
            v[4] += a1.x; v[5] += a1.y; v[6] += a1.z; v[7] += a1.w;
        }
        #pragma unroll
        for (int u = 0; u < 8; ++u) v[u] *= 0.25f;
    }
    float sm = 0.f, sq = 0.f;
    #pragma unroll
    for (int u = 0; u < 8; ++u) { sm += v[u]; sq += v[u] * v[u]; }
    #pragma unroll
    for (int off = 1; off < 64; off <<= 1) {
        sm += __shfl_xor(sm, off, 64);
        sq += __shfl_xor(sq, off, 64);
    }
    float mean = sm * (1.f / (float)D_);
    float var  = sq * (1.f / (float)D_) - mean * mean;
    float rs   = rsqrtf(var + 1e-5f);
    float o[8];
    #pragma unroll
    for (int u = 0; u < 8; ++u)
        o[u] = (v[u] - mean) * rs * g[lane * 8 + u] + bi[lane * 8 + u];
    float* xp = xs + (size_t)row * D_ + lane * 8;
    *(float4*)xp       = make_float4(o[0], o[1], o[2], o[3]);
    *(float4*)(xp + 4) = make_float4(o[4], o[5], o[6], o[7]);
    f16x8 hv;
    #pragma unroll
    for (int u = 0; u < 8; ++u) hv[u] = (f16)o[u];
    *(f16x8*)(xsh + (size_t)row * D_ + lane * 8) = hv;
}

__global__ __launch_bounds__(256) void k_up(float* __restrict__ x,
                                            const float* __restrict__ xs,
                                            f16* __restrict__ xh) {
    int idx = blockIdx.x * 256 + threadIdx.x;
    if (idx >= T_ * B_ * D_) return;
    int d  = idx & (D_ - 1);
    int tb = idx >> 9;
    int t = tb >> 2, b = tb & 3;
    int seg = (t + 1) >> 2;
    float v = x[idx] + xs[((size_t)seg * B_ + b) * D_ + d];
    x[idx] = v; xh[idx] = (f16)v;
}

// ---------------------------------------------------------------------------
// MFMA flash attention v3: XCD-locality block mapping (each XCD owns one
// (b, 4-head) slice -> K/V/RK L2-resident), deferred softmax (no online max,
// lane-local row-sum, single reduce at end), setprio around MFMA clusters.
// KVBLK=64, swizzled LDS, circular RK window, 1-deep prefetch (from R4).
__global__ __launch_bounds__(256) void k_attn(const f16* __restrict__ qkv,
                                              const f16* __restrict__ rkb,
                                              const float* __restrict__ rwb,
                                              const float* __restrict__ rrb,
                                              f16* __restrict__ outp, int Q) {
    __shared__ f16 RKs[192 * 64];
    __shared__ f16 Ks[64 * 64];
    __shared__ f16 Vt[64 * 72];
    __shared__ f16 Pl[4][16 * 72];
    f16* Qw = RKs;
    f16* Qr = RKs + 4096;

    int it, b, n;
    if (gridDim.x == 16) {          // Q=1024: XCD-locality mapping
        int p = blockIdx.y * 16 + blockIdx.x;
        int xcd = p & 7, s = p >> 3;
        b = xcd >> 1;
        n = (xcd & 1) * 4 + (s & 3);
        it = 15 - (s >> 2);         // heavy-first within XCD
    } else {
        it = gridDim.x - 1 - blockIdx.x;
        b = blockIdx.y >> 3;
        n = blockIdx.y & 7;
    }
    const int i0 = it * 64;
    const int nt = it + 1;
    const int tid = threadIdx.x, w = tid >> 6, lane = tid & 63;
    const int l16 = lane & 15, lg = lane >> 4;
    const int xsw = (l16 & 7) << 3;
    const int gr8 = lane >> 3;
    const int gsl = ((lane & 7) ^ gr8) * 8;

    {   // stage Q (+biases) into RK alias, swizzled
        int row = tid >> 2, dq = (tid & 3) * 16;
        const f16* qp = qkv + ((size_t)(i0 + row) * B_ + b) * 1536 + n * 64 + dq;
        f16x8 q0 = *(const f16x8*)qp, q1 = *(const f16x8*)(qp + 8);
        int rsw = (row & 7) << 3;
        #pragma unroll
        for (int u = 0; u < 8; ++u) {
            float qa = (float)q0[u], qb2 = (float)q1[u];
            Qw[row * 64 + ((dq + u) ^ rsw)]     = (f16)(qa + rwb[n * 64 + dq + u]);
            Qw[row * 64 + ((dq + 8 + u) ^ rsw)] = (f16)(qb2 + rwb[n * 64 + dq + 8 + u]);
            Qr[row * 64 + ((dq + u) ^ rsw)]     = (f16)(qa + rrb[n * 64 + dq + u]);
            Qr[row * 64 + ((dq + 8 + u) ^ rsw)] = (f16)(qb2 + rrb[n * 64 + dq + 8 + u]);
        }
    }
    __syncthreads();
    f16x8 aqw[2], aqr[2];
    #pragma unroll
    for (int h = 0; h < 2; ++h) {
        aqw[h] = *(const f16x8*)&Qw[(w * 16 + l16) * 64 + ((h * 32 + lg * 8) ^ xsw)];
        aqr[h] = *(const f16x8*)&Qr[(w * 16 + l16) * 64 + ((h * 32 + lg * 8) ^ xsw)];
    }
    __syncthreads();

    const long long pb = (long long)Q - 64 - i0;
    #pragma unroll
    for (int u = 0; u < 4; ++u) {
        int rb = w * 32 + u * 8;
        long long p = pb + rb + gr8;
        gload16(rkb + p * 512 + n * 64 + gsl, &RKs[rb * 64]);
    }
    #pragma unroll
    for (int u = 0; u < 2; ++u) {
        int rb = w * 16 + u * 8;
        gload16(qkv + ((size_t)(rb + gr8) * B_ + b) * 1536 + 512 + n * 64 + gsl, &Ks[rb * 64]);
    }
    const int vjj = tid >> 2, vdb = (tid & 3) * 16;
    f16x8 vr0, vr1;
    {
        const f16* vp = qkv + ((size_t)vjj * B_ + b) * 1536 + 1024 + n * 64 + vdb;
        vr0 = *(const f16x8*)vp; vr1 = *(const f16x8*)(vp + 8);
    }

    const f32x4 z4 = {0.f, 0.f, 0.f, 0.f};
    f32x4 acc[4]; acc[0] = z4; acc[1] = z4; acc[2] = z4; acc[3] = z4;
    float psum[4] = {0.f, 0.f, 0.f, 0.f};
    const int wb = 48 - w * 16;
    int base = 0;

    for (int t = 0; t < nt; ++t) {
        const int j0 = t * 64;
        __syncthreads();   // A
        #pragma unroll
        for (int u = 0; u < 8; ++u) {
            Vt[(vdb + u) * 72 + (vjj ^ ((u & 7) << 3))]     = vr0[u];
            Vt[(vdb + 8 + u) * 72 + (vjj ^ ((u & 7) << 3))] = vr1[u];
        }
        if (t + 1 < nt) {
            int sb = base + 128; if (sb >= 192) sb -= 192;
            #pragma unroll
            for (int u = 0; u < 2; ++u) {
                int rb = w * 16 + u * 8;
                long long p = pb + j0 + 128 + rb + gr8;
                gload16(rkb + p * 512 + n * 64 + gsl, &RKs[(sb + rb) * 64]);
            }
        }
        // S1 = Qw . K^T
        f32x4 s1[4]; s1[0] = z4; s1[1] = z4; s1[2] = z4; s1[3] = z4;
        __builtin_amdgcn_s_setprio(1);
        #pragma unroll
        for (int f = 0; f < 4; ++f)
            #pragma unroll
            for (int h = 0; h < 2; ++h) {
                f16x8 bv = *(const f16x8*)&Ks[(f * 16 + l16) * 64 + ((h * 32 + lg * 8) ^ xsw)];
                s1[f] = __builtin_amdgcn_mfma_f32_16x16x32_f16(aqw[h], bv, s1[f], 0, 0, 0);
            }
        __builtin_amdgcn_s_setprio(0);
        if (t + 1 < nt) {
            const f16* vp = qkv + ((size_t)(j0 + 64 + vjj) * B_ + b) * 1536 + 1024 + n * 64 + vdb;
            vr0 = *(const f16x8*)vp; vr1 = *(const f16x8*)(vp + 8);
        }
        // S2 = Qr . RKwin^T
        f32x4 s2[5]; s2[0] = z4; s2[1] = z4; s2[2] = z4; s2[3] = z4; s2[4] = z4;
        __builtin_amdgcn_s_setprio(1);
        #pragma unroll
        for (int f = 0; f < 5; ++f) {
            int slot = base + wb + f * 16 + l16; if (slot >= 192) slot -= 192;
            #pragma unroll
            for (int h = 0; h < 2; ++h) {
                f16x8 bv = *(const f16x8*)&RKs[slot * 64 + ((h * 32 + lg * 8) ^ xsw)];
                s2[f] = __builtin_amdgcn_mfma_f32_16x16x32_f16(aqr[h], bv, s2[f], 0, 0, 0);
            }
        }
        __builtin_amdgcn_s_setprio(0);
        // deferred softmax: p = exp(s*scale) directly; lane-local row-sum
        #pragma unroll
        for (int r = 0; r < 4; ++r) {
            const int q = lg * 4 + r;
            const int iq = i0 + w * 16 + q;
            const int src = (lane & 48) | ((l16 + 15 - q) & 15);
            float g0 = __shfl(s2[0][r], src, 64);
            float g1 = __shfl(s2[1][r], src, 64);
            float g2 = __shfl(s2[2][r], src, 64);
            float g3 = __shfl(s2[3][r], src, 64);
            float g4 = __shfl(s2[4][r], src, 64);
            const bool hi = l16 > q;
            float sv[4];
            sv[0] = (s1[0][r] + (hi ? g1 : g0)) * 0.125f;
            sv[1] = (s1[1][r] + (hi ? g2 : g1)) * 0.125f;
            sv[2] = (s1[2][r] + (hi ? g3 : g2)) * 0.125f;
            sv[3] = (s1[3][r] + (hi ? g4 : g3)) * 0.125f;
            #pragma unroll
            for (int h = 0; h < 4; ++h) {
                int j = j0 + h * 16 + l16;
                if (j > iq || j >= Q) sv[h] = -1e30f;
            }
            float p0 = __expf(sv[0]), p1 = __expf(sv[1]);
            float p2 = __expf(sv[2]), p3 = __expf(sv[3]);
            psum[r] += (p0 + p1) + (p2 + p3);
            Pl[w][q * 72 + l16]      = (f16)p0;
            Pl[w][q * 72 + 16 + l16] = (f16)p1;
            Pl[w][q * 72 + 32 + l16] = (f16)p2;
            Pl[w][q * 72 + 48 + l16] = (f16)p3;
        }
        __syncthreads();   // B
        f16x8 pa0 = *(const f16x8*)&Pl[w][l16 * 72 + lg * 8];
        f16x8 pa1 = *(const f16x8*)&Pl[w][l16 * 72 + 32 + lg * 8];
        __builtin_amdgcn_s_setprio(1);
        #pragma unroll
        for (int f = 0; f < 4; ++f) {
            f16x8 bv0 = *(const f16x8*)&Vt[(f * 16 + l16) * 72 + ((lg * 8) ^ xsw)];
            acc[f] = __builtin_amdgcn_mfma_f32_16x16x32_f16(pa0, bv0, acc[f], 0, 0, 0);
            f16x8 bv1 = *(const f16x8*)&Vt[(f * 16 + l16) * 72 + ((32 + lg * 8) ^ xsw)];
            acc[f] = __builtin_amdgcn_mfma_f32_16x16x32_f16(pa1, bv1, acc[f], 0, 0, 0);
        }
        __builtin_amdgcn_s_setprio(0);
        if (t + 1 < nt) {
            #pragma unroll
            for (int u = 0; u < 2; ++u) {
                int rb = w * 16 + u * 8;
                gload16(qkv + ((size_t)(j0 + 64 + rb + gr8) * B_ + b) * 1536 + 512 + n * 64 + gsl,
                        &Ks[rb * 64]);
            }
        }
        base += 64; if (base >= 192) base -= 192;
    }
    // epilogue: single cross-lane row-sum reduce, then normalize
    #pragma unroll
    for (int r = 0; r < 4; ++r) {
        float ps = psum[r];
        ps += __shfl_xor(ps, 1, 64);
        ps += __shfl_xor(ps, 2, 64);
        ps += __shfl_xor(ps, 4, 64);
        ps += __shfl_xor(ps, 8, 64);
        int i = i0 + w * 16 + lg * 4 + r;
        if (i < Q) {
            float inv = 1.f / ps;
            f16* op = outp + ((size_t)i * B_ + b) * 512 + n * 64;
            #pragma unroll
            for (int f = 0; f < 4; ++f)
                op[f * 16 + l16] = (f16)(acc[f][r] * inv);
        }
    }
}

// ---------------------------------------------------------------------------
extern "C" void kernel_launch(void* const* d_in, const int* in_sizes, int n_in,
                              void* d_out, int out_size, void* d_ws, size_t ws_size,
                              hipStream_t stream) {
    const int*   data     = (const int*)  d_in[0];
    const float* word_emb = (const float*)d_in[2];
    const float* rwb      = (const float*)d_in[3];
    const float* rrb      = (const float*)d_in[4];
    const float* nullg    = (const float*)d_in[5];
    const float* dg       = (const float*)d_in[6];
    const float* db       = (const float*)d_in[7];
    const float* qkv_w    = (const float*)d_in[8];
    const float* rk_w     = (const float*)d_in[9];
    const float* o_w      = (const float*)d_in[10];
    const float* ln1g     = (const float*)d_in[11];
    const float* ln1b     = (const float*)d_in[12];
    const float* w1       = (const float*)d_in[13];
    const float* b1       = (const float*)d_in[14];
    const float* w2       = (const float*)d_in[15];
    const float* b2       = (const float*)d_in[16];
    const float* ln2g     = (const float*)d_in[17];
    const float* ln2b     = (const float*)d_in[18];
    const float* fw       = (const float*)d_in[19];
    const float* fb       = (const float*)d_in[20];
    float* out = (float*)d_out;
    float* ws  = (float*)d_ws;

    float* x    = ws;                          // 2097152 f
    float* tmp  = x + 2097152;                 // 2097152 f
    float* xs   = tmp + 2097152;               // 589824 f
    f16* xh     = (f16*)(xs + 589824);         // 2097152 h
    f16* xsh    = xh + 2097152;                // 589824 h
    f16* attnh  = xsh + 589824;                // 2097152 h
    f16* r1h    = attnh + 2097152;             // 524288 h
    f16* r2h    = r1h + 524288;                // 163840 h
    f16* rkh    = r2h + 163840;                // 524288 h
    f16* bigh   = rkh + 524288;                // 8388608 h
    f16* qkv_wh = bigh + 8388608;              // 6291456 h
    f16* rk_wh  = qkv_wh + 6291456;            // 2097152 h
    f16* o_wh   = rk_wh + 2097152;             // 2097152 h
    f16* w1h    = o_wh + 2097152;              // 8388608 h
    f16* w2h    = w1h + 8388608;               // 8388608 h
    f16* fwh    = w2h + 8388608;               // 131072 h

    auto conv = [&](const float* s, f16* d, int n) {
        int blocks = min(2048, (n + 1023) / 1024);
        k_f2h<<<blocks, 256, 0, stream>>>(s, d, n);
    };
    conv(qkv_w, qkv_wh, L_ * 1536 * 512);
    conv(rk_w,  rk_wh,  L_ * 512 * 512);
    conv(o_w,   o_wh,   L_ * 512 * 512);
    conv(w1,    w1h,    L_ * 2048 * 512);
    conv(w2,    w2h,    L_ * 512 * 2048);
    conv(fw,    fwh,    256 * 512);

    auto gemm = [&](const f16* Xp, const f16* Wp, const float* bp, void* Yp,
                    int M, int N, int K, int out16, int act) {
        if (N <= 512 || M < 2048) {
            dim3 g((M + 63) / 64, N / 128);
            if (out16) {
                if (act) k_gemm<64, 1, 1><<<g, 256, 0, stream>>>(Xp, Wp, bp, Yp, M, N, K);
                else     k_gemm<64, 1, 0><<<g, 256, 0, stream>>>(Xp, Wp, bp, Yp, M, N, K);
            } else      k_gemm<64, 0, 0><<<g, 256, 0, stream>>>(Xp, Wp, bp, Yp, M, N, K);
        } else {
            dim3 g((M + 127) / 128, N / 128);
            if (act) k_gemm<128, 1, 1><<<g, 256, 0, stream>>>(Xp, Wp, bp, Yp, M, N, K);
            else     k_gemm<128, 1, 0><<<g, 256, 0, stream>>>(Xp, Wp, bp, Yp, M, N, K);
        }
    };

    k_embed<<<8192, 256, 0, stream>>>(data, word_emb, x, xh);
    k_posemb<<<1024, 256, 0, stream>>>(r1h, 1024);
    k_posemb<<<257, 256, 0, stream>>>(r2h, 257);

    auto stage = [&](float* xb, f16* xbh, const f16* rh, int Q, int lo, int hi) {
        const int M = Q * B_;
        dim3 gA((Q + 63) / 64, B_ * H_);
        dim3 gL((M + 3) / 4);
        for (int i = lo; i < hi; ++i) {
            gemm(xbh, qkv_wh + (size_t)i * 1536 * 512, nullptr, bigh, M, 1536, 512, 1, 0);
            gemm(rh, rk_wh + (size_t)i * 512 * 512, nullptr, rkh, Q, 512, 512, 1, 0);
            k_attn<<<gA, 256, 0, stream>>>(bigh, rkh, rwb, rrb, attnh, Q);
            gemm(attnh, o_wh + (size_t)i * 512 * 512, nullptr, tmp, M, 512, 512, 0, 0);
            k_ln<<<gL, 256, 0, stream>>>(xb, tmp, ln1g + (size_t)i * 512, ln1b + (size_t)i * 512, xbh, M);
            gemm(xbh, w1h + (size_t)i * 2048 * 512, b1 + (size_t)i * 2048, bigh, M, 2048, 512, 1, 1);
            gemm(bigh, w2h + (size_t)i * 512 * 2048, b2 + (size_t)i * 512, tmp, M, 512, 2048, 0, 0);
            k_ln<<<gL, 256, 0, stream>>>(xb, tmp, ln2g + (size_t)i * 512, ln2b + (size_t)i * 512, xbh, M);
        }
    };

    stage(x, xh, r1h, 1024, 0, 2);                               // pre
    k_downln<<<257, 256, 0, stream>>>(x, nullg, dg, db, xs, xsh);
    stage(xs, xsh, r2h, S_ + 1, 2, 6);                           // shortened
    k_up<<<8192, 256, 0, stream>>>(x, xs, xh);                   // upsample + residual
    stage(x, xh, r1h, 1024, 6, 8);                               // post
    gemm(xh, fwh, fb, out, T_ * B_, V_, 512, 0, 0);              // logits
}

// Round 6
// 1138.285 us; speedup vs baseline: 4.8776x; 1.0261x over previous
//
#include <hip/hip_runtime.h>
#include <math.h>

#define T_  1024
#define B_  4
#define D_  512
#define H_  8
#define DH_ 64
#define DI_ 2048
#define V_  256
#define L_  8
#define S_  256   // segments

typedef _Float16 f16;
typedef f16   f16x8 __attribute__((ext_vector_type(8)));
typedef float f32x4 __attribute__((ext_vector_type(4)));

__device__ __forceinline__ void gload16(const void* g, void* l) {
    __builtin_amdgcn_global_load_lds(
        (const __attribute__((address_space(1))) void*)g,
        (__attribute__((address_space(3))) void*)l, 16, 0, 0);
}

// ---------------------------------------------------------------------------
__global__ __launch_bounds__(256) void k_f2h(const float* __restrict__ s,
                                             f16* __restrict__ d, int n) {
    int i = (blockIdx.x * 256 + threadIdx.x) * 4;
    int stride = gridDim.x * 1024;
    for (; i < n; i += stride) {
        float4 v = *(const float4*)(s + i);
        d[i + 0] = (f16)v.x; d[i + 1] = (f16)v.y;
        d[i + 2] = (f16)v.z; d[i + 3] = (f16)v.w;
    }
}

// ---------------------------------------------------------------------------
__global__ __launch_bounds__(256) void k_embed(const int* __restrict__ data,
                                               const float* __restrict__ emb,
                                               float* __restrict__ x,
                                               f16* __restrict__ xh) {
    int idx = blockIdx.x * 256 + threadIdx.x;
    if (idx >= T_ * B_ * D_) return;
    int d  = idx & (D_ - 1);
    int tb = idx >> 9;
    float v = emb[(size_t)data[tb] * D_ + d];
    x[idx] = v; xh[idx] = (f16)v;
}

// ---------------------------------------------------------------------------
__global__ __launch_bounds__(256) void k_posemb(f16* __restrict__ r, int qlen) {
    int p = blockIdx.x;
    int k = threadIdx.x;
    float pos = (float)(qlen - 1 - p);
    float inv = powf(10000.f, -((float)k) / 256.f);
    float ang = pos * inv;
    r[(size_t)p * D_ + k]       = (f16)sinf(ang);
    r[(size_t)p * D_ + 256 + k] = (f16)cosf(ang);
}

// ---------------------------------------------------------------------------
// MFMA fp16 GEMM, m97 structure + XCD-chunked swizzle. X has row stride lda.
template<int BM, int OUT16, int ACT>
__global__ __launch_bounds__(256) void k_gemm(const f16* __restrict__ X, int lda,
                                              const f16* __restrict__ W,
                                              const float* __restrict__ bias,
                                              void* __restrict__ Yv,
                                              int M, int N, int K) {
    __shared__ f16 As[BM * 64];
    __shared__ f16 Bs[128 * 64];
    const int tid = threadIdx.x, w = tid >> 6, lane = tid & 63;
    const int l16 = lane & 15, lg = lane >> 4;
    int nwg = gridDim.x * gridDim.y;
    int bid = blockIdx.y * gridDim.x + blockIdx.x;
    if ((nwg & 7) == 0) bid = (bid & 7) * (nwg >> 3) + (bid >> 3);   // XCD chunked
    const int bm = (bid % gridDim.x) * BM, bn = (bid / gridDim.x) * 128;
    const int lrow = lane >> 3, lcol = (lane & 7) * 8;
    constexpr int AI = BM / 32;
    constexpr int MI = 4;
    constexpr int NJ = (BM == 128) ? 4 : 2;
    const int rbase = (BM == 128) ? (w >> 1) * 64 : 0;
    const int cbase = (BM == 128) ? (w & 1) * 64 : w * 32;
    const f32x4 z4 = {0.f, 0.f, 0.f, 0.f};
    f32x4 acc[MI][NJ];
    #pragma unroll
    for (int i = 0; i < MI; ++i)
        #pragma unroll
        for (int j = 0; j < NJ; ++j) acc[i][j] = z4;

    for (int k0 = 0; k0 < K; k0 += 64) {
        __syncthreads();
        #pragma unroll
        for (int u = 0; u < AI; ++u) {
            int rb = w * (8 * AI) + u * 8;
            gload16(X + (size_t)(bm + rb + lrow) * lda + k0 + lcol, &As[rb * 64]);
        }
        #pragma unroll
        for (int u = 0; u < 4; ++u) {
            int rb = w * 32 + u * 8;
            gload16(W + (size_t)(bn + rb + lrow) * K + k0 + lcol, &Bs[rb * 64]);
        }
        __syncthreads();
        __builtin_amdgcn_s_setprio(1);
        #pragma unroll
        for (int h = 0; h < 2; ++h) {
            f16x8 af[MI], bf[NJ];
            #pragma unroll
            for (int i = 0; i < MI; ++i)
                af[i] = *(const f16x8*)&As[(rbase + i * 16 + l16) * 64 + h * 32 + lg * 8];
            #pragma unroll
            for (int j = 0; j < NJ; ++j)
                bf[j] = *(const f16x8*)&Bs[(cbase + j * 16 + l16) * 64 + h * 32 + lg * 8];
            #pragma unroll
            for (int i = 0; i < MI; ++i)
                #pragma unroll
                for (int j = 0; j < NJ; ++j)
                    acc[i][j] = __builtin_amdgcn_mfma_f32_16x16x32_f16(af[i], bf[j], acc[i][j], 0, 0, 0);
        }
        __builtin_amdgcn_s_setprio(0);
    }
    #pragma unroll
    for (int i = 0; i < MI; ++i) {
        #pragma unroll
        for (int r = 0; r < 4; ++r) {
            int row = bm + rbase + i * 16 + lg * 4 + r;
            if (row >= M) continue;
            int colb = bn + cbase + l16;
            #pragma unroll
            for (int j = 0; j < NJ; ++j) {
                float v = acc[i][j][r];
                if (bias) v += bias[colb + j * 16];
                if (ACT) v = fmaxf(v, 0.f);
                if (OUT16) ((f16*)Yv)[(size_t)row * N + colb + j * 16] = (f16)v;
                else       ((float*)Yv)[(size_t)row * N + colb + j * 16] = v;
            }
        }
    }
}

// ---------------------------------------------------------------------------
// Add + LayerNorm, one WAVE per row, 4 rows/block.
__global__ __launch_bounds__(256) void k_ln(float* __restrict__ x,
                                            const float* __restrict__ add,
                                            const float* __restrict__ g,
                                            const float* __restrict__ b,
                                            f16* __restrict__ xh, int rows) {
    int row = blockIdx.x * 4 + (threadIdx.x >> 6);
    if (row >= rows) return;
    int lane = threadIdx.x & 63;
    float* xr = x + (size_t)row * D_ + lane * 8;
    float v[8];
    {
        float4 a0 = *(const float4*)xr;
        float4 a1 = *(const float4*)(xr + 4);
        v[0] = a0.x; v[1] = a0.y; v[2] = a0.z; v[3] = a0.w;
        v[4] = a1.x; v[5] = a1.y; v[6] = a1.z; v[7] = a1.w;
    }
    if (add) {
        const float* ar = add + (size_t)row * D_ + lane * 8;
        float4 a0 = *(const float4*)ar;
        float4 a1 = *(const float4*)(ar + 4);
        v[0] += a0.x; v[1] += a0.y; v[2] += a0.z; v[3] += a0.w;
        v[4] += a1.x; v[5] += a1.y; v[6] += a1.z; v[7] += a1.w;
    }
    float s = 0.f, sq = 0.f;
    #pragma unroll
    for (int u = 0; u < 8; ++u) { s += v[u]; sq += v[u] * v[u]; }
    #pragma unroll
    for (int off = 1; off < 64; off <<= 1) {
        s  += __shfl_xor(s,  off, 64);
        sq += __shfl_xor(sq, off, 64);
    }
    float mean = s * (1.f / (float)D_);
    float var  = sq * (1.f / (float)D_) - mean * mean;
    float rs   = rsqrtf(var + 1e-5f);
    const float* gp = g + lane * 8;
    const float* bp = b + lane * 8;
    float4 g0 = *(const float4*)gp, g1 = *(const float4*)(gp + 4);
    float4 b0 = *(const float4*)bp, b1 = *(const float4*)(bp + 4);
    float gg[8] = {g0.x, g0.y, g0.z, g0.w, g1.x, g1.y, g1.z, g1.w};
    float bb[8] = {b0.x, b0.y, b0.z, b0.w, b1.x, b1.y, b1.z, b1.w};
    float o[8];
    #pragma unroll
    for (int u = 0; u < 8; ++u) o[u] = (v[u] - mean) * rs * gg[u] + bb[u];
    *(float4*)xr       = make_float4(o[0], o[1], o[2], o[3]);
    *(float4*)(xr + 4) = make_float4(o[4], o[5], o[6], o[7]);
    f16x8 hv;
    #pragma unroll
    for (int u = 0; u < 8; ++u) hv[u] = (f16)o[u];
    *(f16x8*)(xh + (size_t)row * D_ + lane * 8) = hv;
}

// ---------------------------------------------------------------------------
// Fused downsample (mean-pool + null row) + LayerNorm. Wave per output row.
__global__ __launch_bounds__(256) void k_downln(const float* __restrict__ x,
                                                const float* __restrict__ nullg,
                                                const float* __restrict__ g,
                                                const float* __restrict__ bi,
                                                float* __restrict__ xs,
                                                f16* __restrict__ xsh) {
    int row = blockIdx.x * 4 + (threadIdx.x >> 6);
    if (row >= (S_ + 1) * B_) return;
    int lane = threadIdx.x & 63;
    int s = row >> 2, b = row & 3;
    float v[8];
    if (s == 0) {
        const float* np = nullg + lane * 8;
        float4 a0 = *(const float4*)np, a1 = *(const float4*)(np + 4);
        v[0] = a0.x; v[1] = a0.y; v[2] = a0.z; v[3] = a0.w;
        v[4] = a1.x; v[5] = a1.y; v[6] = a1.z; v[7] = a1.w;
    } else {
        int t0 = (s - 1) * 4;
        #pragma unroll
        for (int u = 0; u < 8; ++u) v[u] = 0.f;
        #pragma unroll
        for (int k = 0; k < 4; ++k) {
            const float* xp = x + ((size_t)(t0 + k) * B_ + b) * D_ + lane * 8;
            float4 a0 = *(const float4*)xp, a1 = *(const float4*)(xp + 4);
            v[0] += a0.x; v[1] += a0.y; v[2] += a0.z; v[3] += a0.w;
            v[4] += a1.x; v[5] += a1.y; v[6] += a1.z; v[7] += a1.w;
        }
        #pragma unroll
        for (int u = 0; u < 8; ++u) v[u] *= 0.25f;
    }
    float sm = 0.f, sq = 0.f;
    #pragma unroll
    for (int u = 0; u < 8; ++u) { sm += v[u]; sq += v[u] * v[u]; }
    #pragma unroll
    for (int off = 1; off < 64; off <<= 1) {
        sm += __shfl_xor(sm, off, 64);
        sq += __shfl_xor(sq, off, 64);
    }
    float mean = sm * (1.f / (float)D_);
    float var  = sq * (1.f / (float)D_) - mean * mean;
    float rs   = rsqrtf(var + 1e-5f);
    float o[8];
    #pragma unroll
    for (int u = 0; u < 8; ++u)
        o[u] = (v[u] - mean) * rs * g[lane * 8 + u] + bi[lane * 8 + u];
    float* xp = xs + (size_t)row * D_ + lane * 8;
    *(float4*)xp       = make_float4(o[0], o[1], o[2], o[3]);
    *(float4*)(xp + 4) = make_float4(o[4], o[5], o[6], o[7]);
    f16x8 hv;
    #pragma unroll
    for (int u = 0; u < 8; ++u) hv[u] = (f16)o[u];
    *(f16x8*)(xsh + (size_t)row * D_ + lane * 8) = hv;
}

__global__ __launch_bounds__(256) void k_up(float* __restrict__ x,
                                            const float* __restrict__ xs,
                                            f16* __restrict__ xh) {
    int idx = blockIdx.x * 256 + threadIdx.x;
    if (idx >= T_ * B_ * D_) return;
    int d  = idx & (D_ - 1);
    int tb = idx >> 9;
    int t = tb >> 2, b = tb & 3;
    int seg = (t + 1) >> 2;
    float v = x[idx] + xs[((size_t)seg * B_ + b) * D_ + d];
    x[idx] = v; xh[idx] = (f16)v;
}

// ---------------------------------------------------------------------------
// MFMA flash attention v4: pair-balanced q-tiles (Q=1024: block does tiles
// {15-a, a} = constant 17 chunks; 256 blocks = 1/CU, no CU sharing) with
// XCD-locality mapping. Deferred softmax, swizzled LDS, circular RK window,
// 1-deep prefetch. Output written over the Q-slice of the qkv buffer
// (stride 1536) -- safe: each (rows,head) Q-slice is read only by the block
// that overwrites it, staged before the epilogue write.
__global__ __launch_bounds__(256) void k_attn(f16* __restrict__ qkv,
                                              const f16* __restrict__ rkb,
                                              int ldr,
                                              const float* __restrict__ rwb,
                                              const float* __restrict__ rrb,
                                              int Q) {
    __shared__ f16 RKs[192 * 64];
    __shared__ f16 Ks[64 * 64];
    __shared__ f16 Vt[64 * 72];
    __shared__ f16 Pl[4][16 * 72];
    f16* Qw = RKs;
    f16* Qr = RKs + 4096;

    int itH, itL, nhalf, b, n;
    if (Q == 1024) {                 // paired, XCD-local: grid (8, 32)
        int p = blockIdx.y * gridDim.x + blockIdx.x;
        int xcd = p & 7, s = p >> 3;
        b = xcd >> 1;
        n = (xcd & 1) * 4 + (s & 3);
        int a = s >> 2;              // 0..7
        itH = 15 - a; itL = a; nhalf = 2;
    } else {
        itH = gridDim.x - 1 - blockIdx.x;
        b = blockIdx.y >> 3; n = blockIdx.y & 7;
        itL = 0; nhalf = 1;
    }
    const int tid = threadIdx.x, w = tid >> 6, lane = tid & 63;
    const int l16 = lane & 15, lg = lane >> 4;
    const int xsw = (l16 & 7) << 3;
    const int gr8 = lane >> 3;
    const int gsl = ((lane & 7) ^ gr8) * 8;
    const int vjj = tid >> 2, vdb = (tid & 3) * 16;
    const int qrow = tid >> 2, qdq = (tid & 3) * 16;
    const int wb = 48 - w * 16;
    const f32x4 z4 = {0.f, 0.f, 0.f, 0.f};

    for (int half = 0; half < nhalf; ++half) {
        const int it = half ? itL : itH;
        const int i0 = it * 64;
        const int nt = it + 1;
        {   // stage Q (+biases) into RK alias, swizzled
            const f16* qp = qkv + ((size_t)(i0 + qrow) * B_ + b) * 1536 + n * 64 + qdq;
            f16x8 q0 = *(const f16x8*)qp, q1 = *(const f16x8*)(qp + 8);
            int rsw = (qrow & 7) << 3;
            #pragma unroll
            for (int u = 0; u < 8; ++u) {
                float qa = (float)q0[u], qb2 = (float)q1[u];
                Qw[qrow * 64 + ((qdq + u) ^ rsw)]     = (f16)(qa + rwb[n * 64 + qdq + u]);
                Qw[qrow * 64 + ((qdq + 8 + u) ^ rsw)] = (f16)(qb2 + rwb[n * 64 + qdq + 8 + u]);
                Qr[qrow * 64 + ((qdq + u) ^ rsw)]     = (f16)(qa + rrb[n * 64 + qdq + u]);
                Qr[qrow * 64 + ((qdq + 8 + u) ^ rsw)] = (f16)(qb2 + rrb[n * 64 + qdq + 8 + u]);
            }
        }
        __syncthreads();
        f16x8 aqw[2], aqr[2];
        #pragma unroll
        for (int h = 0; h < 2; ++h) {
            aqw[h] = *(const f16x8*)&Qw[(w * 16 + l16) * 64 + ((h * 32 + lg * 8) ^ xsw)];
            aqr[h] = *(const f16x8*)&Qr[(w * 16 + l16) * 64 + ((h * 32 + lg * 8) ^ xsw)];
        }
        __syncthreads();   // Q-frag reads done before RK staging overwrites

        const long long pb = (long long)Q - 64 - i0;
        #pragma unroll
        for (int u = 0; u < 4; ++u) {
            int rb = w * 32 + u * 8;
            long long p = pb + rb + gr8;
            gload16(rkb + p * ldr + n * 64 + gsl, &RKs[rb * 64]);
        }
        #pragma unroll
        for (int u = 0; u < 2; ++u) {
            int rb = w * 16 + u * 8;
            gload16(qkv + ((size_t)(rb + gr8) * B_ + b) * 1536 + 512 + n * 64 + gsl, &Ks[rb * 64]);
        }
        f16x8 vr0, vr1;
        {
            const f16* vp = qkv + ((size_t)vjj * B_ + b) * 1536 + 1024 + n * 64 + vdb;
            vr0 = *(const f16x8*)vp; vr1 = *(const f16x8*)(vp + 8);
        }

        f32x4 acc[4]; acc[0] = z4; acc[1] = z4; acc[2] = z4; acc[3] = z4;
        float psum[4] = {0.f, 0.f, 0.f, 0.f};
        int base = 0;

        for (int t = 0; t < nt; ++t) {
            const int j0 = t * 64;
            __syncthreads();   // A
            #pragma unroll
            for (int u = 0; u < 8; ++u) {
                Vt[(vdb + u) * 72 + (vjj ^ ((u & 7) << 3))]     = vr0[u];
                Vt[(vdb + 8 + u) * 72 + (vjj ^ ((u & 7) << 3))] = vr1[u];
            }
            if (t + 1 < nt) {
                int sb = base + 128; if (sb >= 192) sb -= 192;
                #pragma unroll
                for (int u = 0; u < 2; ++u) {
                    int rb = w * 16 + u * 8;
                    long long p = pb + j0 + 128 + rb + gr8;
                    gload16(rkb + p * ldr + n * 64 + gsl, &RKs[(sb + rb) * 64]);
                }
            }
            // S1 = Qw . K^T
            f32x4 s1[4]; s1[0] = z4; s1[1] = z4; s1[2] = z4; s1[3] = z4;
            __builtin_amdgcn_s_setprio(1);
            #pragma unroll
            for (int f = 0; f < 4; ++f)
                #pragma unroll
                for (int h = 0; h < 2; ++h) {
                    f16x8 bv = *(const f16x8*)&Ks[(f * 16 + l16) * 64 + ((h * 32 + lg * 8) ^ xsw)];
                    s1[f] = __builtin_amdgcn_mfma_f32_16x16x32_f16(aqw[h], bv, s1[f], 0, 0, 0);
                }
            __builtin_amdgcn_s_setprio(0);
            if (t + 1 < nt) {
                const f16* vp = qkv + ((size_t)(j0 + 64 + vjj) * B_ + b) * 1536 + 1024 + n * 64 + vdb;
                vr0 = *(const f16x8*)vp; vr1 = *(const f16x8*)(vp + 8);
            }
            // S2 = Qr . RKwin^T
            f32x4 s2[5]; s2[0] = z4; s2[1] = z4; s2[2] = z4; s2[3] = z4; s2[4] = z4;
            __builtin_amdgcn_s_setprio(1);
            #pragma unroll
            for (int f = 0; f < 5; ++f) {
                int slot = base + wb + f * 16 + l16; if (slot >= 192) slot -= 192;
                #pragma unroll
                for (int h = 0; h < 2; ++h) {
                    f16x8 bv = *(const f16x8*)&RKs[slot * 64 + ((h * 32 + lg * 8) ^ xsw)];
                    s2[f] = __builtin_amdgcn_mfma_f32_16x16x32_f16(aqr[h], bv, s2[f], 0, 0, 0);
                }
            }
            __builtin_amdgcn_s_setprio(0);
            // deferred softmax: p = exp(s*scale); lane-local row-sum
            #pragma unroll
            for (int r = 0; r < 4; ++r) {
                const int q = lg * 4 + r;
                const int iq = i0 + w * 16 + q;
                const int src = (lane & 48) | ((l16 + 15 - q) & 15);
                float g0 = __shfl(s2[0][r], src, 64);
                float g1 = __shfl(s2[1][r], src, 64);
                float g2 = __shfl(s2[2][r], src, 64);
                float g3 = __shfl(s2[3][r], src, 64);
                float g4 = __shfl(s2[4][r], src, 64);
                const bool hi = l16 > q;
                float sv[4];
                sv[0] = (s1[0][r] + (hi ? g1 : g0)) * 0.125f;
                sv[1] = (s1[1][r] + (hi ? g2 : g1)) * 0.125f;
                sv[2] = (s1[2][r] + (hi ? g3 : g2)) * 0.125f;
                sv[3] = (s1[3][r] + (hi ? g4 : g3)) * 0.125f;
                #pragma unroll
                for (int h = 0; h < 4; ++h) {
                    int j = j0 + h * 16 + l16;
                    if (j > iq || j >= Q) sv[h] = -1e30f;
                }
                float p0 = __expf(sv[0]), p1 = __expf(sv[1]);
                float p2 = __expf(sv[2]), p3 = __expf(sv[3]);
                psum[r] += (p0 + p1) + (p2 + p3);
                Pl[w][q * 72 + l16]      = (f16)p0;
                Pl[w][q * 72 + 16 + l16] = (f16)p1;
                Pl[w][q * 72 + 32 + l16] = (f16)p2;
                Pl[w][q * 72 + 48 + l16] = (f16)p3;
            }
            __syncthreads();   // B
            f16x8 pa0 = *(const f16x8*)&Pl[w][l16 * 72 + lg * 8];
            f16x8 pa1 = *(const f16x8*)&Pl[w][l16 * 72 + 32 + lg * 8];
            __builtin_amdgcn_s_setprio(1);
            #pragma unroll
            for (int f = 0; f < 4; ++f) {
                f16x8 bv0 = *(const f16x8*)&Vt[(f * 16 + l16) * 72 + ((lg * 8) ^ xsw)];
                acc[f] = __builtin_amdgcn_mfma_f32_16x16x32_f16(pa0, bv0, acc[f], 0, 0, 0);
                f16x8 bv1 = *(const f16x8*)&Vt[(f * 16 + l16) * 72 + ((32 + lg * 8) ^ xsw)];
                acc[f] = __builtin_amdgcn_mfma_f32_16x16x32_f16(pa1, bv1, acc[f], 0, 0, 0);
            }
            __builtin_amdgcn_s_setprio(0);
            if (t + 1 < nt) {
                #pragma unroll
                for (int u = 0; u < 2; ++u) {
                    int rb = w * 16 + u * 8;
                    gload16(qkv + ((size_t)(j0 + 64 + rb + gr8) * B_ + b) * 1536 + 512 + n * 64 + gsl,
                            &Ks[rb * 64]);
                }
            }
            base += 64; if (base >= 192) base -= 192;
        }
        // epilogue: row-sum reduce, normalize, write over Q-slice (stride 1536)
        #pragma unroll
        for (int r = 0; r < 4; ++r) {
            float ps = psum[r];
            ps += __shfl_xor(ps, 1, 64);
            ps += __shfl_xor(ps, 2, 64);
            ps += __shfl_xor(ps, 4, 64);
            ps += __shfl_xor(ps, 8, 64);
            int i = i0 + w * 16 + lg * 4 + r;
            if (i < Q) {
                float inv = 1.f / ps;
                f16* op = qkv + ((size_t)i * B_ + b) * 1536 + n * 64;
                #pragma unroll
                for (int f = 0; f < 4; ++f)
                    op[f * 16 + l16] = (f16)(acc[f][r] * inv);
            }
        }
    }
}

// ---------------------------------------------------------------------------
extern "C" void kernel_launch(void* const* d_in, const int* in_sizes, int n_in,
                              void* d_out, int out_size, void* d_ws, size_t ws_size,
                              hipStream_t stream) {
    const int*   data     = (const int*)  d_in[0];
    const float* word_emb = (const float*)d_in[2];
    const float* rwb      = (const float*)d_in[3];
    const float* rrb      = (const float*)d_in[4];
    const float* nullg    = (const float*)d_in[5];
    const float* dg       = (const float*)d_in[6];
    const float* db       = (const float*)d_in[7];
    const float* qkv_w    = (const float*)d_in[8];
    const float* rk_w     = (const float*)d_in[9];
    const float* o_w      = (const float*)d_in[10];
    const float* ln1g     = (const float*)d_in[11];
    const float* ln1b     = (const float*)d_in[12];
    const float* w1       = (const float*)d_in[13];
    const float* b1       = (const float*)d_in[14];
    const float* w2       = (const float*)d_in[15];
    const float* b2       = (const float*)d_in[16];
    const float* ln2g     = (const float*)d_in[17];
    const float* ln2b     = (const float*)d_in[18];
    const float* fw       = (const float*)d_in[19];
    const float* fb       = (const float*)d_in[20];
    float* out = (float*)d_out;
    float* ws  = (float*)d_ws;

    // workspace (~98.2 MB, same footprint as R5)
    float* x    = ws;                          // 2097152 f
    float* tmp  = x + 2097152;                 // 2097152 f
    float* xs   = tmp + 2097152;               // 589824 f
    f16* xh     = (f16*)(xs + 589824);         // 2097152 h
    f16* xsh    = xh + 2097152;                // 589824 h
    f16* r1h    = xsh + 589824;                // 524288 h
    f16* r2h    = r1h + 524288;                // 163840 h
    f16* rkall  = r2h + 163840;                // 2623488 h (batched RK, all layers)
    f16* bigh   = rkall + 2623488;             // 8388608 h
    f16* qkv_wh = bigh + 8388608;              // 6291456 h
    f16* rk_wh  = qkv_wh + 6291456;            // 2097152 h
    f16* o_wh   = rk_wh + 2097152;             // 2097152 h
    f16* w1h    = o_wh + 2097152;              // 8388608 h
    f16* w2h    = w1h + 8388608;               // 8388608 h
    f16* fwh    = w2h + 8388608;               // 131072 h

    auto conv = [&](const float* s, f16* d, int n) {
        int blocks = min(2048, (n + 1023) / 1024);
        k_f2h<<<blocks, 256, 0, stream>>>(s, d, n);
    };
    conv(qkv_w, qkv_wh, L_ * 1536 * 512);
    conv(rk_w,  rk_wh,  L_ * 512 * 512);
    conv(o_w,   o_wh,   L_ * 512 * 512);
    conv(w1,    w1h,    L_ * 2048 * 512);
    conv(w2,    w2h,    L_ * 512 * 2048);
    conv(fw,    fwh,    256 * 512);

    auto gemm = [&](const f16* Xp, int lda, const f16* Wp, const float* bp,
                    void* Yp, int M, int N, int K, int out16, int act) {
        if (N <= 512 || M < 2048) {
            dim3 g((M + 63) / 64, N / 128);
            if (out16) {
                if (act) k_gemm<64, 1, 1><<<g, 256, 0, stream>>>(Xp, lda, Wp, bp, Yp, M, N, K);
                else     k_gemm<64, 1, 0><<<g, 256, 0, stream>>>(Xp, lda, Wp, bp, Yp, M, N, K);
            } else      k_gemm<64, 0, 0><<<g, 256, 0, stream>>>(Xp, lda, Wp, bp, Yp, M, N, K);
        } else {
            dim3 g((M + 127) / 128, N / 128);
            if (act) k_gemm<128, 1, 1><<<g, 256, 0, stream>>>(Xp, lda, Wp, bp, Yp, M, N, K);
            else     k_gemm<128, 1, 0><<<g, 256, 0, stream>>>(Xp, lda, Wp, bp, Yp, M, N, K);
        }
    };

    k_embed<<<8192, 256, 0, stream>>>(data, word_emb, x, xh);
    k_posemb<<<1024, 256, 0, stream>>>(r1h, 1024);
    k_posemb<<<257, 256, 0, stream>>>(r2h, 257);

    // batched RK precompute (r is layer-invariant):
    // layers 0,1 (ld 1024) | layers 6,7 (ld 1024) | layers 2-5 (ld 2048)
    gemm(r1h, 512, rk_wh,                nullptr, rkall,           1024, 1024, 512, 1, 0);
    gemm(r1h, 512, rk_wh + 6 * 262144,   nullptr, rkall + 1048576, 1024, 1024, 512, 1, 0);
    gemm(r2h, 512, rk_wh + 2 * 262144,   nullptr, rkall + 2097152,  257, 2048, 512, 1, 0);

    auto stage = [&](float* xb, f16* xbh, int Q, int lo, int hi) {
        const int M = Q * B_;
        dim3 gA = (Q == 1024) ? dim3(8, 32) : dim3((Q + 63) / 64, 32);
        dim3 gL((M + 3) / 4);
        for (int i = lo; i < hi; ++i) {
            const f16* rkp; int ldr;
            if (i < 2)       { rkp = rkall + i * 512;                 ldr = 1024; }
            else if (i >= 6) { rkp = rkall + 1048576 + (i - 6) * 512; ldr = 1024; }
            else             { rkp = rkall + 2097152 + (i - 2) * 512; ldr = 2048; }
            gemm(xbh, 512, qkv_wh + (size_t)i * 786432, nullptr, bigh, M, 1536, 512, 1, 0);
            k_attn<<<gA, 256, 0, stream>>>(bigh, rkp, ldr, rwb, rrb, Q);
            gemm(bigh, 1536, o_wh + (size_t)i * 262144, nullptr, tmp, M, 512, 512, 0, 0);
            k_ln<<<gL, 256, 0, stream>>>(xb, tmp, ln1g + (size_t)i * 512, ln1b + (size_t)i * 512, xbh, M);
            gemm(xbh, 512, w1h + (size_t)i * 1048576, b1 + (size_t)i * 2048, bigh, M, 2048, 512, 1, 1);
            gemm(bigh, 2048, w2h + (size_t)i * 1048576, b2 + (size_t)i * 512, tmp, M, 512, 2048, 0, 0);
            k_ln<<<gL, 256, 0, stream>>>(xb, tmp, ln2g + (size_t)i * 512, ln2b + (size_t)i * 512, xbh, M);
        }
    };

    stage(x, xh, 1024, 0, 2);                                    // pre
    k_downln<<<257, 256, 0, stream>>>(x, nullg, dg, db, xs, xsh);
    stage(xs, xsh, S_ + 1, 2, 6);                                // shortened
    k_up<<<8192, 256, 0, stream>>>(x, xs, xh);                   // upsample + residual
    stage(x, xh, 1024, 6, 8);                                    // post
    gemm(xh, 512, fwh, fb, out, T_ * B_, V_, 512, 0, 0);         // logits
}

// Round 7
// 1101.006 us; speedup vs baseline: 5.0428x; 1.0339x over previous
//
#include <hip/hip_runtime.h>
#include <math.h>

#define T_  1024
#define B_  4
#define D_  512
#define H_  8
#define DH_ 64
#define DI_ 2048
#define V_  256
#define L_  8
#define S_  256   // segments

typedef _Float16 f16;
typedef f16   f16x8 __attribute__((ext_vector_type(8)));
typedef float f32x4 __attribute__((ext_vector_type(4)));

__device__ __forceinline__ void gload16(const void* g, void* l) {
    __builtin_amdgcn_global_load_lds(
        (const __attribute__((address_space(1))) void*)g,
        (__attribute__((address_space(3))) void*)l, 16, 0, 0);
}

// task table for Q=1024: 24 tasks/(b,n), sizes 8,8,8,8,8,8,8,8,8,8,7,7,...,1,1
// split tiles (it>=8) have two tasks: [0,8) and [8,it+1). Heavy-first order.
__constant__ int cIT[24] = {15,15,14,13,12,11,10,9,8,7,14,6,13,5,12,4,11,3,10,2,9,1,8,0};
__constant__ int cT0[24] = { 0, 8, 0, 0, 0, 0, 0,0,0,0, 8,0, 8,0, 8,0, 8,0, 8,0,8,0,8,0};
__constant__ int cT1[24] = { 8,16, 8, 8, 8, 8, 8,8,8,8,15,7,14,6,13,5,12,4,11,3,10,2,9,1};

// ---------------------------------------------------------------------------
__global__ __launch_bounds__(256) void k_f2h(const float* __restrict__ s,
                                             f16* __restrict__ d, int n) {
    int i = (blockIdx.x * 256 + threadIdx.x) * 4;
    int stride = gridDim.x * 1024;
    for (; i < n; i += stride) {
        float4 v = *(const float4*)(s + i);
        d[i + 0] = (f16)v.x; d[i + 1] = (f16)v.y;
        d[i + 2] = (f16)v.z; d[i + 3] = (f16)v.w;
    }
}

// ---------------------------------------------------------------------------
__global__ __launch_bounds__(256) void k_embed(const int* __restrict__ data,
                                               const float* __restrict__ emb,
                                               float* __restrict__ x,
                                               f16* __restrict__ xh) {
    int idx = blockIdx.x * 256 + threadIdx.x;
    if (idx >= T_ * B_ * D_) return;
    int d  = idx & (D_ - 1);
    int tb = idx >> 9;
    float v = emb[(size_t)data[tb] * D_ + d];
    x[idx] = v; xh[idx] = (f16)v;
}

// ---------------------------------------------------------------------------
__global__ __launch_bounds__(256) void k_posemb(f16* __restrict__ r, int qlen) {
    int p = blockIdx.x;
    int k = threadIdx.x;
    float pos = (float)(qlen - 1 - p);
    float inv = powf(10000.f, -((float)k) / 256.f);
    float ang = pos * inv;
    r[(size_t)p * D_ + k]       = (f16)sinf(ang);
    r[(size_t)p * D_ + 256 + k] = (f16)cosf(ang);
}

// ---------------------------------------------------------------------------
// MFMA fp16 GEMM, m97 structure + XCD-chunked swizzle. X has row stride lda.
template<int BM, int OUT16, int ACT>
__global__ __launch_bounds__(256) void k_gemm(const f16* __restrict__ X, int lda,
                                              const f16* __restrict__ W,
                                              const float* __restrict__ bias,
                                              void* __restrict__ Yv,
                                              int M, int N, int K) {
    __shared__ f16 As[BM * 64];
    __shared__ f16 Bs[128 * 64];
    const int tid = threadIdx.x, w = tid >> 6, lane = tid & 63;
    const int l16 = lane & 15, lg = lane >> 4;
    int nwg = gridDim.x * gridDim.y;
    int bid = blockIdx.y * gridDim.x + blockIdx.x;
    if ((nwg & 7) == 0) bid = (bid & 7) * (nwg >> 3) + (bid >> 3);   // XCD chunked
    const int bm = (bid % gridDim.x) * BM, bn = (bid / gridDim.x) * 128;
    const int lrow = lane >> 3, lcol = (lane & 7) * 8;
    constexpr int AI = BM / 32;
    constexpr int MI = 4;
    constexpr int NJ = (BM == 128) ? 4 : 2;
    const int rbase = (BM == 128) ? (w >> 1) * 64 : 0;
    const int cbase = (BM == 128) ? (w & 1) * 64 : w * 32;
    const f32x4 z4 = {0.f, 0.f, 0.f, 0.f};
    f32x4 acc[MI][NJ];
    #pragma unroll
    for (int i = 0; i < MI; ++i)
        #pragma unroll
        for (int j = 0; j < NJ; ++j) acc[i][j] = z4;

    for (int k0 = 0; k0 < K; k0 += 64) {
        __syncthreads();
        #pragma unroll
        for (int u = 0; u < AI; ++u) {
            int rb = w * (8 * AI) + u * 8;
            gload16(X + (size_t)(bm + rb + lrow) * lda + k0 + lcol, &As[rb * 64]);
        }
        #pragma unroll
        for (int u = 0; u < 4; ++u) {
            int rb = w * 32 + u * 8;
            gload16(W + (size_t)(bn + rb + lrow) * K + k0 + lcol, &Bs[rb * 64]);
        }
        __syncthreads();
        __builtin_amdgcn_s_setprio(1);
        #pragma unroll
        for (int h = 0; h < 2; ++h) {
            f16x8 af[MI], bf[NJ];
            #pragma unroll
            for (int i = 0; i < MI; ++i)
                af[i] = *(const f16x8*)&As[(rbase + i * 16 + l16) * 64 + h * 32 + lg * 8];
            #pragma unroll
            for (int j = 0; j < NJ; ++j)
                bf[j] = *(const f16x8*)&Bs[(cbase + j * 16 + l16) * 64 + h * 32 + lg * 8];
            #pragma unroll
            for (int i = 0; i < MI; ++i)
                #pragma unroll
                for (int j = 0; j < NJ; ++j)
                    acc[i][j] = __builtin_amdgcn_mfma_f32_16x16x32_f16(af[i], bf[j], acc[i][j], 0, 0, 0);
        }
        __builtin_amdgcn_s_setprio(0);
    }
    #pragma unroll
    for (int i = 0; i < MI; ++i) {
        #pragma unroll
        for (int r = 0; r < 4; ++r) {
            int row = bm + rbase + i * 16 + lg * 4 + r;
            if (row >= M) continue;
            int colb = bn + cbase + l16;
            #pragma unroll
            for (int j = 0; j < NJ; ++j) {
                float v = acc[i][j][r];
                if (bias) v += bias[colb + j * 16];
                if (ACT) v = fmaxf(v, 0.f);
                if (OUT16) ((f16*)Yv)[(size_t)row * N + colb + j * 16] = (f16)v;
                else       ((float*)Yv)[(size_t)row * N + colb + j * 16] = v;
            }
        }
    }
}

// ---------------------------------------------------------------------------
// Add + LayerNorm, one WAVE per row, 4 rows/block.
__global__ __launch_bounds__(256) void k_ln(float* __restrict__ x,
                                            const float* __restrict__ add,
                                            const float* __restrict__ g,
                                            const float* __restrict__ b,
                                            f16* __restrict__ xh, int rows) {
    int row = blockIdx.x * 4 + (threadIdx.x >> 6);
    if (row >= rows) return;
    int lane = threadIdx.x & 63;
    float* xr = x + (size_t)row * D_ + lane * 8;
    float v[8];
    {
        float4 a0 = *(const float4*)xr;
        float4 a1 = *(const float4*)(xr + 4);
        v[0] = a0.x; v[1] = a0.y; v[2] = a0.z; v[3] = a0.w;
        v[4] = a1.x; v[5] = a1.y; v[6] = a1.z; v[7] = a1.w;
    }
    if (add) {
        const float* ar = add + (size_t)row * D_ + lane * 8;
        float4 a0 = *(const float4*)ar;
        float4 a1 = *(const float4*)(ar + 4);
        v[0] += a0.x; v[1] += a0.y; v[2] += a0.z; v[3] += a0.w;
        v[4] += a1.x; v[5] += a1.y; v[6] += a1.z; v[7] += a1.w;
    }
    float s = 0.f, sq = 0.f;
    #pragma unroll
    for (int u = 0; u < 8; ++u) { s += v[u]; sq += v[u] * v[u]; }
    #pragma unroll
    for (int off = 1; off < 64; off <<= 1) {
        s  += __shfl_xor(s,  off, 64);
        sq += __shfl_xor(sq, off, 64);
    }
    float mean = s * (1.f / (float)D_);
    float var  = sq * (1.f / (float)D_) - mean * mean;
    float rs   = rsqrtf(var + 1e-5f);
    const float* gp = g + lane * 8;
    const float* bp = b + lane * 8;
    float4 g0 = *(const float4*)gp, g1 = *(const float4*)(gp + 4);
    float4 b0 = *(const float4*)bp, b1 = *(const float4*)(bp + 4);
    float gg[8] = {g0.x, g0.y, g0.z, g0.w, g1.x, g1.y, g1.z, g1.w};
    float bb[8] = {b0.x, b0.y, b0.z, b0.w, b1.x, b1.y, b1.z, b1.w};
    float o[8];
    #pragma unroll
    for (int u = 0; u < 8; ++u) o[u] = (v[u] - mean) * rs * gg[u] + bb[u];
    *(float4*)xr       = make_float4(o[0], o[1], o[2], o[3]);
    *(float4*)(xr + 4) = make_float4(o[4], o[5], o[6], o[7]);
    f16x8 hv;
    #pragma unroll
    for (int u = 0; u < 8; ++u) hv[u] = (f16)o[u];
    *(f16x8*)(xh + (size_t)row * D_ + lane * 8) = hv;
}

// ---------------------------------------------------------------------------
// Fused downsample (mean-pool + null row) + LayerNorm. Wave per output row.
__global__ __launch_bounds__(256) void k_downln(const float* __restrict__ x,
                                                const float* __restrict__ nullg,
                                                const float* __restrict__ g,
                                                const float* __restrict__ bi,
                                                float* __restrict__ xs,
                                                f16* __restrict__ xsh) {
    int row = blockIdx.x * 4 + (threadIdx.x >> 6);
    if (row >= (S_ + 1) * B_) return;
    int lane = threadIdx.x & 63;
    int s = row >> 2, b = row & 3;
    float v[8];
    if (s == 0) {
        const float* np = nullg + lane * 8;
        float4 a0 = *(const float4*)np, a1 = *(const float4*)(np + 4);
        v[0] = a0.x; v[1] = a0.y; v[2] = a0.z; v[3] = a0.w;
        v[4] = a1.x; v[5] = a1.y; v[6] = a1.z; v[7] = a1.w;
    } else {
        int t0 = (s - 1) * 4;
        #pragma unroll
        for (int u = 0; u < 8; ++u) v[u] = 0.f;
        #pragma unroll
        for (int k = 0; k < 4; ++k) {
            const float* xp = x + ((size_t)(t0 + k) * B_ + b) * D_ + lane * 8;
            float4 a0 = *(const float4*)xp, a1 = *(const float4*)(xp + 4);
            v[0] += a0.x; v[1] += a0.y; v[2] += a0.z; v[3] += a0.w;
            v[4] += a1.x; v[5] += a1.y; v[6] += a1.z; v[7] += a1.w;
        }
        #pragma unroll
        for (int u = 0; u < 8; ++u) v[u] *= 0.25f;
    }
    float sm = 0.f, sq = 0.f;
    #pragma unroll
    for (int u = 0; u < 8; ++u) { sm += v[u]; sq += v[u] * v[u]; }
    #pragma unroll
    for (int off = 1; off < 64; off <<= 1) {
        sm += __shfl_xor(sm, off, 64);
        sq += __shfl_xor(sq, off, 64);
    }
    float mean = sm * (1.f / (float)D_);
    float var  = sq * (1.f / (float)D_) - mean * mean;
    float rs   = rsqrtf(var + 1e-5f);
    float o[8];
    #pragma unroll
    for (int u = 0; u < 8; ++u)
        o[u] = (v[u] - mean) * rs * g[lane * 8 + u] + bi[lane * 8 + u];
    float* xp = xs + (size_t)row * D_ + lane * 8;
    *(float4*)xp       = make_float4(o[0], o[1], o[2], o[3]);
    *(float4*)(xp + 4) = make_float4(o[4], o[5], o[6], o[7]);
    f16x8 hv;
    #pragma unroll
    for (int u = 0; u < 8; ++u) hv[u] = (f16)o[u];
    *(f16x8*)(xsh + (size_t)row * D_ + lane * 8) = hv;
}

__global__ __launch_bounds__(256) void k_up(float* __restrict__ x,
                                            const float* __restrict__ xs,
                                            f16* __restrict__ xh) {
    int idx = blockIdx.x * 256 + threadIdx.x;
    if (idx >= T_ * B_ * D_) return;
    int d  = idx & (D_ - 1);
    int tb = idx >> 9;
    int t = tb >> 2, b = tb & 3;
    int seg = (t + 1) >> 2;
    float v = x[idx] + xs[((size_t)seg * B_ + b) * D_ + d];
    x[idx] = v; xh[idx] = (f16)v;
}

// ---------------------------------------------------------------------------
// MFMA flash attention v5: key-split uniform tasks. Q=1024: 24 tasks/(b,n)
// (tiles with >8 chunks split at j=512; deferred softmax makes partials
// combine by plain addition), 768 blocks = 3/CU, heavy-first, XCD-local.
// Split tasks write fp32 partials (acc 64x64 + psum 64) to `part`; k_comb
// reduces. Swizzled LDS, circular RK window, 1-deep prefetch.
__global__ __launch_bounds__(256) void k_attn(f16* __restrict__ qkv,
                                              const f16* __restrict__ rkb,
                                              int ldr,
                                              const float* __restrict__ rwb,
                                              const float* __restrict__ rrb,
                                              int Q, float* __restrict__ part) {
    __shared__ f16 RKs[192 * 64];
    __shared__ f16 Ks[64 * 64];
    __shared__ f16 Vt[64 * 72];
    __shared__ f16 Pl[4][16 * 72];
    f16* Qw = RKs;
    f16* Qr = RKs + 4096;

    int it, t0, t1, b, n;
    if (Q == 1024) {                 // task-table + XCD-locality, grid (24,32)
        int p = blockIdx.y * gridDim.x + blockIdx.x;
        int xcd = p & 7, qq = p >> 3;
        b = xcd >> 1;
        n = (xcd & 1) * 4 + (qq & 3);
        int slot = qq >> 2;          // 0..23, heavy first
        it = cIT[slot]; t0 = cT0[slot]; t1 = cT1[slot];
    } else {
        it = gridDim.x - 1 - blockIdx.x;
        b = blockIdx.y >> 3; n = blockIdx.y & 7;
        t0 = 0; t1 = it + 1;
    }
    const int i0 = it * 64;
    const bool partial = (Q == 1024) && (it >= 8);
    const int tid = threadIdx.x, w = tid >> 6, lane = tid & 63;
    const int l16 = lane & 15, lg = lane >> 4;
    const int xsw = (l16 & 7) << 3;
    const int gr8 = lane >> 3;
    const int gsl = ((lane & 7) ^ gr8) * 8;
    const int vjj = tid >> 2, vdb = (tid & 3) * 16;
    const int wb = 48 - w * 16;
    const f32x4 z4 = {0.f, 0.f, 0.f, 0.f};

    {   // stage Q (+biases) into RK alias, swizzled
        int row = tid >> 2, dq = (tid & 3) * 16;
        const f16* qp = qkv + ((size_t)(i0 + row) * B_ + b) * 1536 + n * 64 + dq;
        f16x8 q0 = *(const f16x8*)qp, q1 = *(const f16x8*)(qp + 8);
        int rsw = (row & 7) << 3;
        #pragma unroll
        for (int u = 0; u < 8; ++u) {
            float qa = (float)q0[u], qb2 = (float)q1[u];
            Qw[row * 64 + ((dq + u) ^ rsw)]     = (f16)(qa + rwb[n * 64 + dq + u]);
            Qw[row * 64 + ((dq + 8 + u) ^ rsw)] = (f16)(qb2 + rwb[n * 64 + dq + 8 + u]);
            Qr[row * 64 + ((dq + u) ^ rsw)]     = (f16)(qa + rrb[n * 64 + dq + u]);
            Qr[row * 64 + ((dq + 8 + u) ^ rsw)] = (f16)(qb2 + rrb[n * 64 + dq + 8 + u]);
        }
    }
    __syncthreads();
    f16x8 aqw[2], aqr[2];
    #pragma unroll
    for (int h = 0; h < 2; ++h) {
        aqw[h] = *(const f16x8*)&Qw[(w * 16 + l16) * 64 + ((h * 32 + lg * 8) ^ xsw)];
        aqr[h] = *(const f16x8*)&Qr[(w * 16 + l16) * 64 + ((h * 32 + lg * 8) ^ xsw)];
    }
    __syncthreads();   // Q-frag reads done before RK staging overwrites

    const long long pb = (long long)Q - 64 - i0;
    #pragma unroll
    for (int u = 0; u < 4; ++u) {
        int rb = w * 32 + u * 8;
        long long p = pb + t0 * 64 + rb + gr8;
        gload16(rkb + p * ldr + n * 64 + gsl, &RKs[rb * 64]);
    }
    #pragma unroll
    for (int u = 0; u < 2; ++u) {
        int rb = w * 16 + u * 8;
        gload16(qkv + ((size_t)(t0 * 64 + rb + gr8) * B_ + b) * 1536 + 512 + n * 64 + gsl,
                &Ks[rb * 64]);
    }
    f16x8 vr0, vr1;
    {
        const f16* vp = qkv + ((size_t)(t0 * 64 + vjj) * B_ + b) * 1536 + 1024 + n * 64 + vdb;
        vr0 = *(const f16x8*)vp; vr1 = *(const f16x8*)(vp + 8);
    }

    f32x4 acc[4]; acc[0] = z4; acc[1] = z4; acc[2] = z4; acc[3] = z4;
    float psum[4] = {0.f, 0.f, 0.f, 0.f};
    int base = 0;

    for (int t = t0; t < t1; ++t) {
        const int j0 = t * 64;
        __syncthreads();   // A
        #pragma unroll
        for (int u = 0; u < 8; ++u) {
            Vt[(vdb + u) * 72 + (vjj ^ ((u & 7) << 3))]     = vr0[u];
            Vt[(vdb + 8 + u) * 72 + (vjj ^ ((u & 7) << 3))] = vr1[u];
        }
        if (t + 1 < t1) {
            int sb = base + 128; if (sb >= 192) sb -= 192;
            #pragma unroll
            for (int u = 0; u < 2; ++u) {
                int rb = w * 16 + u * 8;
                long long p = pb + j0 + 128 + rb + gr8;
                gload16(rkb + p * ldr + n * 64 + gsl, &RKs[(sb + rb) * 64]);
            }
        }
        // S1 = Qw . K^T
        f32x4 s1[4]; s1[0] = z4; s1[1] = z4; s1[2] = z4; s1[3] = z4;
        __builtin_amdgcn_s_setprio(1);
        #pragma unroll
        for (int f = 0; f < 4; ++f)
            #pragma unroll
            for (int h = 0; h < 2; ++h) {
                f16x8 bv = *(const f16x8*)&Ks[(f * 16 + l16) * 64 + ((h * 32 + lg * 8) ^ xsw)];
                s1[f] = __builtin_amdgcn_mfma_f32_16x16x32_f16(aqw[h], bv, s1[f], 0, 0, 0);
            }
        __builtin_amdgcn_s_setprio(0);
        if (t + 1 < t1) {
            const f16* vp = qkv + ((size_t)(j0 + 64 + vjj) * B_ + b) * 1536 + 1024 + n * 64 + vdb;
            vr0 = *(const f16x8*)vp; vr1 = *(const f16x8*)(vp + 8);
        }
        // S2 = Qr . RKwin^T
        f32x4 s2[5]; s2[0] = z4; s2[1] = z4; s2[2] = z4; s2[3] = z4; s2[4] = z4;
        __builtin_amdgcn_s_setprio(1);
        #pragma unroll
        for (int f = 0; f < 5; ++f) {
            int slot = base + wb + f * 16 + l16; if (slot >= 192) slot -= 192;
            #pragma unroll
            for (int h = 0; h < 2; ++h) {
                f16x8 bv = *(const f16x8*)&RKs[slot * 64 + ((h * 32 + lg * 8) ^ xsw)];
                s2[f] = __builtin_amdgcn_mfma_f32_16x16x32_f16(aqr[h], bv, s2[f], 0, 0, 0);
            }
        }
        __builtin_amdgcn_s_setprio(0);
        // deferred softmax: p = exp(s*scale); lane-local row-sum
        #pragma unroll
        for (int r = 0; r < 4; ++r) {
            const int q = lg * 4 + r;
            const int iq = i0 + w * 16 + q;
            const int src = (lane & 48) | ((l16 + 15 - q) & 15);
            float g0 = __shfl(s2[0][r], src, 64);
            float g1 = __shfl(s2[1][r], src, 64);
            float g2 = __shfl(s2[2][r], src, 64);
            float g3 = __shfl(s2[3][r], src, 64);
            float g4 = __shfl(s2[4][r], src, 64);
            const bool hi = l16 > q;
            float sv[4];
            sv[0] = (s1[0][r] + (hi ? g1 : g0)) * 0.125f;
            sv[1] = (s1[1][r] + (hi ? g2 : g1)) * 0.125f;
            sv[2] = (s1[2][r] + (hi ? g3 : g2)) * 0.125f;
            sv[3] = (s1[3][r] + (hi ? g4 : g3)) * 0.125f;
            #pragma unroll
            for (int h = 0; h < 4; ++h) {
                int j = j0 + h * 16 + l16;
                if (j > iq || j >= Q) sv[h] = -1e30f;
            }
            float p0 = __expf(sv[0]), p1 = __expf(sv[1]);
            float p2 = __expf(sv[2]), p3 = __expf(sv[3]);
            psum[r] += (p0 + p1) + (p2 + p3);
            Pl[w][q * 72 + l16]      = (f16)p0;
            Pl[w][q * 72 + 16 + l16] = (f16)p1;
            Pl[w][q * 72 + 32 + l16] = (f16)p2;
            Pl[w][q * 72 + 48 + l16] = (f16)p3;
        }
        __syncthreads();   // B
        f16x8 pa0 = *(const f16x8*)&Pl[w][l16 * 72 + lg * 8];
        f16x8 pa1 = *(const f16x8*)&Pl[w][l16 * 72 + 32 + lg * 8];
        __builtin_amdgcn_s_setprio(1);
        #pragma unroll
        for (int f = 0; f < 4; ++f) {
            f16x8 bv0 = *(const f16x8*)&Vt[(f * 16 + l16) * 72 + ((lg * 8) ^ xsw)];
            acc[f] = __builtin_amdgcn_mfma_f32_16x16x32_f16(pa0, bv0, acc[f], 0, 0, 0);
            f16x8 bv1 = *(const f16x8*)&Vt[(f * 16 + l16) * 72 + ((32 + lg * 8) ^ xsw)];
            acc[f] = __builtin_amdgcn_mfma_f32_16x16x32_f16(pa1, bv1, acc[f], 0, 0, 0);
        }
        __builtin_amdgcn_s_setprio(0);
        if (t + 1 < t1) {
            #pragma unroll
            for (int u = 0; u < 2; ++u) {
                int rb = w * 16 + u * 8;
                gload16(qkv + ((size_t)(j0 + 64 + rb + gr8) * B_ + b) * 1536 + 512 + n * 64 + gsl,
                        &Ks[rb * 64]);
            }
        }
        base += 64; if (base >= 192) base -= 192;
    }
    // epilogue
    if (partial) {
        // write fp32 partials: acc[64][64] + psum[64]
        int idxp = (b * 8 + n) * 8 + (it - 8);
        float* Pp = part + (size_t)idxp * 8320 + (t0 ? 4160 : 0);
        #pragma unroll
        for (int r = 0; r < 4; ++r) {
            float ps = psum[r];
            ps += __shfl_xor(ps, 1, 64);
            ps += __shfl_xor(ps, 2, 64);
            ps += __shfl_xor(ps, 4, 64);
            ps += __shfl_xor(ps, 8, 64);
            int row = w * 16 + lg * 4 + r;
            #pragma unroll
            for (int f = 0; f < 4; ++f)
                Pp[row * 64 + f * 16 + l16] = acc[f][r];
            if (l16 == 0) Pp[4096 + row] = ps;
        }
    } else {
        #pragma unroll
        for (int r = 0; r < 4; ++r) {
            float ps = psum[r];
            ps += __shfl_xor(ps, 1, 64);
            ps += __shfl_xor(ps, 2, 64);
            ps += __shfl_xor(ps, 4, 64);
            ps += __shfl_xor(ps, 8, 64);
            int i = i0 + w * 16 + lg * 4 + r;
            if (i < Q) {
                float inv = 1.f / ps;
                f16* op = qkv + ((size_t)i * B_ + b) * 1536 + n * 64;
                #pragma unroll
                for (int f = 0; f < 4; ++f)
                    op[f * 16 + l16] = (f16)(acc[f][r] * inv);
            }
        }
    }
}

// ---------------------------------------------------------------------------
// Combine split-attention partials: out = (accA+accB)/(psA+psB), write Q-slice.
__global__ __launch_bounds__(256) void k_comb(const float* __restrict__ part,
                                              f16* __restrict__ qkv) {
    int idxp = blockIdx.x;           // (b*8+n)*8 + (it-8)
    int itm = idxp & 7;
    int bn = idxp >> 3;
    int b = bn >> 3, n = bn & 7;
    int i0 = (itm + 8) * 64;
    int row = threadIdx.x >> 2, dp = (threadIdx.x & 3) * 16;
    const float* A  = part + (size_t)idxp * 8320;
    const float* Bp = A + 4160;
    float inv = 1.f / (A[4096 + row] + Bp[4096 + row]);
    f16* op = qkv + ((size_t)(i0 + row) * B_ + b) * 1536 + n * 64 + dp;
    #pragma unroll
    for (int k = 0; k < 16; k += 4) {
        float4 a  = *(const float4*)(A  + row * 64 + dp + k);
        float4 bb = *(const float4*)(Bp + row * 64 + dp + k);
        op[k + 0] = (f16)((a.x + bb.x) * inv);
        op[k + 1] = (f16)((a.y + bb.y) * inv);
        op[k + 2] = (f16)((a.z + bb.z) * inv);
        op[k + 3] = (f16)((a.w + bb.w) * inv);
    }
}

// ---------------------------------------------------------------------------
extern "C" void kernel_launch(void* const* d_in, const int* in_sizes, int n_in,
                              void* d_out, int out_size, void* d_ws, size_t ws_size,
                              hipStream_t stream) {
    const int*   data     = (const int*)  d_in[0];
    const float* word_emb = (const float*)d_in[2];
    const float* rwb      = (const float*)d_in[3];
    const float* rrb      = (const float*)d_in[4];
    const float* nullg    = (const float*)d_in[5];
    const float* dg       = (const float*)d_in[6];
    const float* db       = (const float*)d_in[7];
    const float* qkv_w    = (const float*)d_in[8];
    const float* rk_w     = (const float*)d_in[9];
    const float* o_w      = (const float*)d_in[10];
    const float* ln1g     = (const float*)d_in[11];
    const float* ln1b     = (const float*)d_in[12];
    const float* w1       = (const float*)d_in[13];
    const float* b1       = (const float*)d_in[14];
    const float* w2       = (const float*)d_in[15];
    const float* b2       = (const float*)d_in[16];
    const float* ln2g     = (const float*)d_in[17];
    const float* ln2b     = (const float*)d_in[18];
    const float* fw       = (const float*)d_in[19];
    const float* fb       = (const float*)d_in[20];
    float* out = (float*)d_out;
    float* ws  = (float*)d_ws;

    // workspace (~98.2 MB). NOTE: during Q=1024 attention, tmp (+ start of
    // xs) doubles as the fp32 partial buffer (2,129,920 floats) — both are
    // dead there (tmp used only after attn; xs only during shortened stage).
    float* x    = ws;                          // 2097152 f
    float* tmp  = x + 2097152;                 // 2097152 f
    float* xs   = tmp + 2097152;               // 589824 f
    f16* xh     = (f16*)(xs + 589824);         // 2097152 h
    f16* xsh    = xh + 2097152;                // 589824 h
    f16* r1h    = xsh + 589824;                // 524288 h
    f16* r2h    = r1h + 524288;                // 163840 h
    f16* rkall  = r2h + 163840;                // 2623488 h (batched RK, all layers)
    f16* bigh   = rkall + 2623488;             // 8388608 h
    f16* qkv_wh = bigh + 8388608;              // 6291456 h
    f16* rk_wh  = qkv_wh + 6291456;            // 2097152 h
    f16* o_wh   = rk_wh + 2097152;             // 2097152 h
    f16* w1h    = o_wh + 2097152;              // 8388608 h
    f16* w2h    = w1h + 8388608;               // 8388608 h
    f16* fwh    = w2h + 8388608;               // 131072 h

    auto conv = [&](const float* s, f16* d, int n) {
        int blocks = min(2048, (n + 1023) / 1024);
        k_f2h<<<blocks, 256, 0, stream>>>(s, d, n);
    };
    conv(qkv_w, qkv_wh, L_ * 1536 * 512);
    conv(rk_w,  rk_wh,  L_ * 512 * 512);
    conv(o_w,   o_wh,   L_ * 512 * 512);
    conv(w1,    w1h,    L_ * 2048 * 512);
    conv(w2,    w2h,    L_ * 512 * 2048);
    conv(fw,    fwh,    256 * 512);

    auto gemm = [&](const f16* Xp, int lda, const f16* Wp, const float* bp,
                    void* Yp, int M, int N, int K, int out16, int act) {
        if (N <= 512 || M < 2048) {
            dim3 g((M + 63) / 64, N / 128);
            if (out16) {
                if (act) k_gemm<64, 1, 1><<<g, 256, 0, stream>>>(Xp, lda, Wp, bp, Yp, M, N, K);
                else     k_gemm<64, 1, 0><<<g, 256, 0, stream>>>(Xp, lda, Wp, bp, Yp, M, N, K);
            } else      k_gemm<64, 0, 0><<<g, 256, 0, stream>>>(Xp, lda, Wp, bp, Yp, M, N, K);
        } else {
            dim3 g((M + 127) / 128, N / 128);
            if (act) k_gemm<128, 1, 1><<<g, 256, 0, stream>>>(Xp, lda, Wp, bp, Yp, M, N, K);
            else     k_gemm<128, 1, 0><<<g, 256, 0, stream>>>(Xp, lda, Wp, bp, Yp, M, N, K);
        }
    };

    k_embed<<<8192, 256, 0, stream>>>(data, word_emb, x, xh);
    k_posemb<<<1024, 256, 0, stream>>>(r1h, 1024);
    k_posemb<<<257, 256, 0, stream>>>(r2h, 257);

    // batched RK precompute (r is layer-invariant):
    gemm(r1h, 512, rk_wh,                nullptr, rkall,           1024, 1024, 512, 1, 0);
    gemm(r1h, 512, rk_wh + 6 * 262144,   nullptr, rkall + 1048576, 1024, 1024, 512, 1, 0);
    gemm(r2h, 512, rk_wh + 2 * 262144,   nullptr, rkall + 2097152,  257, 2048, 512, 1, 0);

    auto stage = [&](float* xb, f16* xbh, int Q, int lo, int hi) {
        const int M = Q * B_;
        dim3 gA = (Q == 1024) ? dim3(24, 32) : dim3((Q + 63) / 64, 32);
        dim3 gL((M + 3) / 4);
        for (int i = lo; i < hi; ++i) {
            const f16* rkp; int ldr;
            if (i < 2)       { rkp = rkall + i * 512;                 ldr = 1024; }
            else if (i >= 6) { rkp = rkall + 1048576 + (i - 6) * 512; ldr = 1024; }
            else             { rkp = rkall + 2097152 + (i - 2) * 512; ldr = 2048; }
            gemm(xbh, 512, qkv_wh + (size_t)i * 786432, nullptr, bigh, M, 1536, 512, 1, 0);
            k_attn<<<gA, 256, 0, stream>>>(bigh, rkp, ldr, rwb, rrb, Q, tmp);
            if (Q == 1024) k_comb<<<256, 256, 0, stream>>>(tmp, bigh);
            gemm(bigh, 1536, o_wh + (size_t)i * 262144, nullptr, tmp, M, 512, 512, 0, 0);
            k_ln<<<gL, 256, 0, stream>>>(xb, tmp, ln1g + (size_t)i * 512, ln1b + (size_t)i * 512, xbh, M);
            gemm(xbh, 512, w1h + (size_t)i * 1048576, b1 + (size_t)i * 2048, bigh, M, 2048, 512, 1, 1);
            gemm(bigh, 2048, w2h + (size_t)i * 1048576, b2 + (size_t)i * 512, tmp, M, 512, 2048, 0, 0);
            k_ln<<<gL, 256, 0, stream>>>(xb, tmp, ln2g + (size_t)i * 512, ln2b + (size_t)i * 512, xbh, M);
        }
    };

    stage(x, xh, 1024, 0, 2);                                    // pre
    k_downln<<<257, 256, 0, stream>>>(x, nullg, dg, db, xs, xsh);
    stage(xs, xsh, S_ + 1, 2, 6);                                // shortened
    k_up<<<8192, 256, 0, stream>>>(x, xs, xh);                   // upsample + residual
    stage(x, xh, 1024, 6, 8);                                    // post
    gemm(xh, 512, fwh, fb, out, T_ * B_, V_, 512, 0, 0);         // logits
}

// Round 8
// 873.233 us; speedup vs baseline: 6.3582x; 1.2608x over previous
//
#include <hip/hip_runtime.h>
#include <math.h>

#define T_  1024
#define B_  4
#define D_  512
#define H_  8
#define DH_ 64
#define DI_ 2048
#define V_  256
#define L_  8
#define S_  256   // segments

typedef _Float16 f16;
typedef f16   f16x8 __attribute__((ext_vector_type(8)));
typedef float f32x4 __attribute__((ext_vector_type(4)));

__device__ __forceinline__ void gload16(const void* g, void* l) {
    __builtin_amdgcn_global_load_lds(
        (const __attribute__((address_space(1))) void*)g,
        (__attribute__((address_space(3))) void*)l, 16, 0, 0);
}

// task table for Q=1024 attention: 24 tasks/(b,n); split tiles (it>=8) have
// two tasks [0,8) and [8,it+1). Heavy-first order.
__constant__ int cIT[24] = {15,15,14,13,12,11,10,9,8,7,14,6,13,5,12,4,11,3,10,2,9,1,8,0};
__constant__ int cT0[24] = { 0, 8, 0, 0, 0, 0, 0,0,0,0, 8,0, 8,0, 8,0, 8,0, 8,0,8,0,8,0};
__constant__ int cT1[24] = { 8,16, 8, 8, 8, 8, 8,8,8,8,15,7,14,6,13,5,12,4,11,3,10,2,9,1};

// ---------------------------------------------------------------------------
__global__ __launch_bounds__(256) void k_f2h(const float* __restrict__ s,
                                             f16* __restrict__ d, int n) {
    int i = (blockIdx.x * 256 + threadIdx.x) * 4;
    int stride = gridDim.x * 1024;
    for (; i < n; i += stride) {
        float4 v = *(const float4*)(s + i);
        d[i + 0] = (f16)v.x; d[i + 1] = (f16)v.y;
        d[i + 2] = (f16)v.z; d[i + 3] = (f16)v.w;
    }
}

// ---------------------------------------------------------------------------
__global__ __launch_bounds__(256) void k_embed(const int* __restrict__ data,
                                               const float* __restrict__ emb,
                                               float* __restrict__ x,
                                               f16* __restrict__ xh) {
    int idx = blockIdx.x * 256 + threadIdx.x;
    if (idx >= T_ * B_ * D_) return;
    int d  = idx & (D_ - 1);
    int tb = idx >> 9;
    float v = emb[(size_t)data[tb] * D_ + d];
    x[idx] = v; xh[idx] = (f16)v;
}

// ---------------------------------------------------------------------------
__global__ __launch_bounds__(256) void k_posemb(f16* __restrict__ r, int qlen) {
    int p = blockIdx.x;
    int k = threadIdx.x;
    float pos = (float)(qlen - 1 - p);
    float inv = powf(10000.f, -((float)k) / 256.f);
    float ang = pos * inv;
    r[(size_t)p * D_ + k]       = (f16)sinf(ang);
    r[(size_t)p * D_ + 256 + k] = (f16)cosf(ang);
}

// ---------------------------------------------------------------------------
// MFMA fp16 GEMM, m97 structure + XCD-chunked swizzle, parameterized tile.
// BM in {32,64}, BN in {64,128}. X has row stride lda.
template<int BM, int BN, int OUT16, int ACT>
__global__ __launch_bounds__(256) void k_gemm(const f16* __restrict__ X, int lda,
                                              const f16* __restrict__ W,
                                              const float* __restrict__ bias,
                                              void* __restrict__ Yv,
                                              int M, int N, int K) {
    __shared__ f16 As[BM * 64];
    __shared__ f16 Bs[BN * 64];
    const int tid = threadIdx.x, w = tid >> 6, lane = tid & 63;
    const int l16 = lane & 15, lg = lane >> 4;
    int nwg = gridDim.x * gridDim.y;
    int bid = blockIdx.y * gridDim.x + blockIdx.x;
    if ((nwg & 7) == 0) bid = (bid & 7) * (nwg >> 3) + (bid >> 3);   // XCD chunked
    const int bm = (bid % gridDim.x) * BM, bn = (bid / gridDim.x) * BN;
    const int lrow = lane >> 3, lcol = (lane & 7) * 8;
    constexpr int AI = (BM >= 32) ? BM / 32 : 1;   // A gloads per wave
    constexpr int BI = BN / 32;                    // B gloads per wave
    constexpr int MI = (BN == 128) ? 4 : BM / 32;
    constexpr int NJ = 2;
    const int rbase = (BN == 128) ? 0 : (w >> 1) * (BM / 2);
    const int cbase = (BN == 128) ? w * 32 : (w & 1) * 32;
    const f32x4 z4 = {0.f, 0.f, 0.f, 0.f};
    f32x4 acc[MI][NJ];
    #pragma unroll
    for (int i = 0; i < MI; ++i)
        #pragma unroll
        for (int j = 0; j < NJ; ++j) acc[i][j] = z4;

    for (int k0 = 0; k0 < K; k0 += 64) {
        __syncthreads();
        #pragma unroll
        for (int u = 0; u < AI; ++u) {
            int rb = w * (BM / 4) + u * 8;
            gload16(X + (size_t)(bm + rb + lrow) * lda + k0 + lcol, &As[rb * 64]);
        }
        #pragma unroll
        for (int u = 0; u < BI; ++u) {
            int rb = w * (BN / 4) + u * 8;
            gload16(W + (size_t)(bn + rb + lrow) * K + k0 + lcol, &Bs[rb * 64]);
        }
        __syncthreads();
        __builtin_amdgcn_s_setprio(1);
        #pragma unroll
        for (int h = 0; h < 2; ++h) {
            f16x8 af[MI], bf[NJ];
            #pragma unroll
            for (int i = 0; i < MI; ++i)
                af[i] = *(const f16x8*)&As[(rbase + i * 16 + l16) * 64 + h * 32 + lg * 8];
            #pragma unroll
            for (int j = 0; j < NJ; ++j)
                bf[j] = *(const f16x8*)&Bs[(cbase + j * 16 + l16) * 64 + h * 32 + lg * 8];
            #pragma unroll
            for (int i = 0; i < MI; ++i)
                #pragma unroll
                for (int j = 0; j < NJ; ++j)
                    acc[i][j] = __builtin_amdgcn_mfma_f32_16x16x32_f16(af[i], bf[j], acc[i][j], 0, 0, 0);
        }
        __builtin_amdgcn_s_setprio(0);
    }
    #pragma unroll
    for (int i = 0; i < MI; ++i) {
        #pragma unroll
        for (int r = 0; r < 4; ++r) {
            int row = bm + rbase + i * 16 + lg * 4 + r;
            if (row >= M) continue;
            int colb = bn + cbase + l16;
            #pragma unroll
            for (int j = 0; j < NJ; ++j) {
                float v = acc[i][j][r];
                if (bias) v += bias[colb + j * 16];
                if (ACT) v = fmaxf(v, 0.f);
                if (OUT16) ((f16*)Yv)[(size_t)row * N + colb + j * 16] = (f16)v;
                else       ((float*)Yv)[(size_t)row * N + colb + j * 16] = v;
            }
        }
    }
}

// ---------------------------------------------------------------------------
// Add + LayerNorm, one WAVE per row, 4 rows/block.
__global__ __launch_bounds__(256) void k_ln(float* __restrict__ x,
                                            const float* __restrict__ add,
                                            const float* __restrict__ g,
                                            const float* __restrict__ b,
                                            f16* __restrict__ xh, int rows) {
    int row = blockIdx.x * 4 + (threadIdx.x >> 6);
    if (row >= rows) return;
    int lane = threadIdx.x & 63;
    float* xr = x + (size_t)row * D_ + lane * 8;
    float v[8];
    {
        float4 a0 = *(const float4*)xr;
        float4 a1 = *(const float4*)(xr + 4);
        v[0] = a0.x; v[1] = a0.y; v[2] = a0.z; v[3] = a0.w;
        v[4] = a1.x; v[5] = a1.y; v[6] = a1.z; v[7] = a1.w;
    }
    if (add) {
        const float* ar = add + (size_t)row * D_ + lane * 8;
        float4 a0 = *(const float4*)ar;
        float4 a1 = *(const float4*)(ar + 4);
        v[0] += a0.x; v[1] += a0.y; v[2] += a0.z; v[3] += a0.w;
        v[4] += a1.x; v[5] += a1.y; v[6] += a1.z; v[7] += a1.w;
    }
    float s = 0.f, sq = 0.f;
    #pragma unroll
    for (int u = 0; u < 8; ++u) { s += v[u]; sq += v[u] * v[u]; }
    #pragma unroll
    for (int off = 1; off < 64; off <<= 1) {
        s  += __shfl_xor(s,  off, 64);
        sq += __shfl_xor(sq, off, 64);
    }
    float mean = s * (1.f / (float)D_);
    float var  = sq * (1.f / (float)D_) - mean * mean;
    float rs   = rsqrtf(var + 1e-5f);
    const float* gp = g + lane * 8;
    const float* bp = b + lane * 8;
    float4 g0 = *(const float4*)gp, g1 = *(const float4*)(gp + 4);
    float4 b0 = *(const float4*)bp, b1 = *(const float4*)(bp + 4);
    float gg[8] = {g0.x, g0.y, g0.z, g0.w, g1.x, g1.y, g1.z, g1.w};
    float bb[8] = {b0.x, b0.y, b0.z, b0.w, b1.x, b1.y, b1.z, b1.w};
    float o[8];
    #pragma unroll
    for (int u = 0; u < 8; ++u) o[u] = (v[u] - mean) * rs * gg[u] + bb[u];
    *(float4*)xr       = make_float4(o[0], o[1], o[2], o[3]);
    *(float4*)(xr + 4) = make_float4(o[4], o[5], o[6], o[7]);
    f16x8 hv;
    #pragma unroll
    for (int u = 0; u < 8; ++u) hv[u] = (f16)o[u];
    *(f16x8*)(xh + (size_t)row * D_ + lane * 8) = hv;
}

// ---------------------------------------------------------------------------
// Fused downsample (mean-pool + null row) + LayerNorm. Wave per output row.
__global__ __launch_bounds__(256) void k_downln(const float* __restrict__ x,
                                                const float* __restrict__ nullg,
                                                const float* __restrict__ g,
                                                const float* __restrict__ bi,
                                                float* __restrict__ xs,
                                                f16* __restrict__ xsh) {
    int row = blockIdx.x * 4 + (threadIdx.x >> 6);
    if (row >= (S_ + 1) * B_) return;
    int lane = threadIdx.x & 63;
    int s = row >> 2, b = row & 3;
    float v[8];
    if (s == 0) {
        const float* np = nullg + lane * 8;
        float4 a0 = *(const float4*)np, a1 = *(const float4*)(np + 4);
        v[0] = a0.x; v[1] = a0.y; v[2] = a0.z; v[3] = a0.w;
        v[4] = a1.x; v[5] = a1.y; v[6] = a1.z; v[7] = a1.w;
    } else {
        int t0 = (s - 1) * 4;
        #pragma unroll
        for (int u = 0; u < 8; ++u) v[u] = 0.f;
        #pragma unroll
        for (int k = 0; k < 4; ++k) {
            const float* xp = x + ((size_t)(t0 + k) * B_ + b) * D_ + lane * 8;
            float4 a0 = *(const float4*)xp, a1 = *(const float4*)(xp + 4);
            v[0] += a0.x; v[1] += a0.y; v[2] += a0.z; v[3] += a0.w;
            v[4] += a1.x; v[5] += a1.y; v[6] += a1.z; v[7] += a1.w;
        }
        #pragma unroll
        for (int u = 0; u < 8; ++u) v[u] *= 0.25f;
    }
    float sm = 0.f, sq = 0.f;
    #pragma unroll
    for (int u = 0; u < 8; ++u) { sm += v[u]; sq += v[u] * v[u]; }
    #pragma unroll
    for (int off = 1; off < 64; off <<= 1) {
        sm += __shfl_xor(sm, off, 64);
        sq += __shfl_xor(sq, off, 64);
    }
    float mean = sm * (1.f / (float)D_);
    float var  = sq * (1.f / (float)D_) - mean * mean;
    float rs   = rsqrtf(var + 1e-5f);
    float o[8];
    #pragma unroll
    for (int u = 0; u < 8; ++u)
        o[u] = (v[u] - mean) * rs * g[lane * 8 + u] + bi[lane * 8 + u];
    float* xp = xs + (size_t)row * D_ + lane * 8;
    *(float4*)xp       = make_float4(o[0], o[1], o[2], o[3]);
    *(float4*)(xp + 4) = make_float4(o[4], o[5], o[6], o[7]);
    f16x8 hv;
    #pragma unroll
    for (int u = 0; u < 8; ++u) hv[u] = (f16)o[u];
    *(f16x8*)(xsh + (size_t)row * D_ + lane * 8) = hv;
}

__global__ __launch_bounds__(256) void k_up(float* __restrict__ x,
                                            const float* __restrict__ xs,
                                            f16* __restrict__ xh) {
    int idx = blockIdx.x * 256 + threadIdx.x;
    if (idx >= T_ * B_ * D_) return;
    int d  = idx & (D_ - 1);
    int tb = idx >> 9;
    int t = tb >> 2, b = tb & 3;
    int seg = (t + 1) >> 2;
    float v = x[idx] + xs[((size_t)seg * B_ + b) * D_ + d];
    x[idx] = v; xh[idx] = (f16)v;
}

// ---------------------------------------------------------------------------
// MFMA flash attention v5 (unchanged from R7): key-split uniform tasks,
// 768 blocks = 3/CU at Q=1024, heavy-first, XCD-local, deferred softmax,
// swizzled LDS, circular RK window, 1-deep prefetch.
__global__ __launch_bounds__(256) void k_attn(f16* __restrict__ qkv,
                                              const f16* __restrict__ rkb,
                                              int ldr,
                                              const float* __restrict__ rwb,
                                              const float* __restrict__ rrb,
                                              int Q, float* __restrict__ part) {
    __shared__ f16 RKs[192 * 64];
    __shared__ f16 Ks[64 * 64];
    __shared__ f16 Vt[64 * 72];
    __shared__ f16 Pl[4][16 * 72];
    f16* Qw = RKs;
    f16* Qr = RKs + 4096;

    int it, t0, t1, b, n;
    if (Q == 1024) {
        int p = blockIdx.y * gridDim.x + blockIdx.x;
        int xcd = p & 7, qq = p >> 3;
        b = xcd >> 1;
        n = (xcd & 1) * 4 + (qq & 3);
        int slot = qq >> 2;
        it = cIT[slot]; t0 = cT0[slot]; t1 = cT1[slot];
    } else {
        it = gridDim.x - 1 - blockIdx.x;
        b = blockIdx.y >> 3; n = blockIdx.y & 7;
        t0 = 0; t1 = it + 1;
    }
    const int i0 = it * 64;
    const bool partial = (Q == 1024) && (it >= 8);
    const int tid = threadIdx.x, w = tid >> 6, lane = tid & 63;
    const int l16 = lane & 15, lg = lane >> 4;
    const int xsw = (l16 & 7) << 3;
    const int gr8 = lane >> 3;
    const int gsl = ((lane & 7) ^ gr8) * 8;
    const int vjj = tid >> 2, vdb = (tid & 3) * 16;
    const int wb = 48 - w * 16;
    const f32x4 z4 = {0.f, 0.f, 0.f, 0.f};

    {   // stage Q (+biases) into RK alias, swizzled
        int row = tid >> 2, dq = (tid & 3) * 16;
        const f16* qp = qkv + ((size_t)(i0 + row) * B_ + b) * 1536 + n * 64 + dq;
        f16x8 q0 = *(const f16x8*)qp, q1 = *(const f16x8*)(qp + 8);
        int rsw = (row & 7) << 3;
        #pragma unroll
        for (int u = 0; u < 8; ++u) {
            float qa = (float)q0[u], qb2 = (float)q1[u];
            Qw[row * 64 + ((dq + u) ^ rsw)]     = (f16)(qa + rwb[n * 64 + dq + u]);
            Qw[row * 64 + ((dq + 8 + u) ^ rsw)] = (f16)(qb2 + rwb[n * 64 + dq + 8 + u]);
            Qr[row * 64 + ((dq + u) ^ rsw)]     = (f16)(qa + rrb[n * 64 + dq + u]);
            Qr[row * 64 + ((dq + 8 + u) ^ rsw)] = (f16)(qb2 + rrb[n * 64 + dq + 8 + u]);
        }
    }
    __syncthreads();
    f16x8 aqw[2], aqr[2];
    #pragma unroll
    for (int h = 0; h < 2; ++h) {
        aqw[h] = *(const f16x8*)&Qw[(w * 16 + l16) * 64 + ((h * 32 + lg * 8) ^ xsw)];
        aqr[h] = *(const f16x8*)&Qr[(w * 16 + l16) * 64 + ((h * 32 + lg * 8) ^ xsw)];
    }
    __syncthreads();

    const long long pb = (long long)Q - 64 - i0;
    #pragma unroll
    for (int u = 0; u < 4; ++u) {
        int rb = w * 32 + u * 8;
        long long p = pb + t0 * 64 + rb + gr8;
        gload16(rkb + p * ldr + n * 64 + gsl, &RKs[rb * 64]);
    }
    #pragma unroll
    for (int u = 0; u < 2; ++u) {
        int rb = w * 16 + u * 8;
        gload16(qkv + ((size_t)(t0 * 64 + rb + gr8) * B_ + b) * 1536 + 512 + n * 64 + gsl,
                &Ks[rb * 64]);
    }
    f16x8 vr0, vr1;
    {
        const f16* vp = qkv + ((size_t)(t0 * 64 + vjj) * B_ + b) * 1536 + 1024 + n * 64 + vdb;
        vr0 = *(const f16x8*)vp; vr1 = *(const f16x8*)(vp + 8);
    }

    f32x4 acc[4]; acc[0] = z4; acc[1] = z4; acc[2] = z4; acc[3] = z4;
    float psum[4] = {0.f, 0.f, 0.f, 0.f};
    int base = 0;

    for (int t = t0; t < t1; ++t) {
        const int j0 = t * 64;
        __syncthreads();   // A
        #pragma unroll
        for (int u = 0; u < 8; ++u) {
            Vt[(vdb + u) * 72 + (vjj ^ ((u & 7) << 3))]     = vr0[u];
            Vt[(vdb + 8 + u) * 72 + (vjj ^ ((u & 7) << 3))] = vr1[u];
        }
        if (t + 1 < t1) {
            int sb = base + 128; if (sb >= 192) sb -= 192;
            #pragma unroll
            for (int u = 0; u < 2; ++u) {
                int rb = w * 16 + u * 8;
                long long p = pb + j0 + 128 + rb + gr8;
                gload16(rkb + p * ldr + n * 64 + gsl, &RKs[(sb + rb) * 64]);
            }
        }
        f32x4 s1[4]; s1[0] = z4; s1[1] = z4; s1[2] = z4; s1[3] = z4;
        __builtin_amdgcn_s_setprio(1);
        #pragma unroll
        for (int f = 0; f < 4; ++f)
            #pragma unroll
            for (int h = 0; h < 2; ++h) {
                f16x8 bv = *(const f16x8*)&Ks[(f * 16 + l16) * 64 + ((h * 32 + lg * 8) ^ xsw)];
                s1[f] = __builtin_amdgcn_mfma_f32_16x16x32_f16(aqw[h], bv, s1[f], 0, 0, 0);
            }
        __builtin_amdgcn_s_setprio(0);
        if (t + 1 < t1) {
            const f16* vp = qkv + ((size_t)(j0 + 64 + vjj) * B_ + b) * 1536 + 1024 + n * 64 + vdb;
            vr0 = *(const f16x8*)vp; vr1 = *(const f16x8*)(vp + 8);
        }
        f32x4 s2[5]; s2[0] = z4; s2[1] = z4; s2[2] = z4; s2[3] = z4; s2[4] = z4;
        __builtin_amdgcn_s_setprio(1);
        #pragma unroll
        for (int f = 0; f < 5; ++f) {
            int slot = base + wb + f * 16 + l16; if (slot >= 192) slot -= 192;
            #pragma unroll
            for (int h = 0; h < 2; ++h) {
                f16x8 bv = *(const f16x8*)&RKs[slot * 64 + ((h * 32 + lg * 8) ^ xsw)];
                s2[f] = __builtin_amdgcn_mfma_f32_16x16x32_f16(aqr[h], bv, s2[f], 0, 0, 0);
            }
        }
        __builtin_amdgcn_s_setprio(0);
        #pragma unroll
        for (int r = 0; r < 4; ++r) {
            const int q = lg * 4 + r;
            const int iq = i0 + w * 16 + q;
            const int src = (lane & 48) | ((l16 + 15 - q) & 15);
            float g0 = __shfl(s2[0][r], src, 64);
            float g1 = __shfl(s2[1][r], src, 64);
            float g2 = __shfl(s2[2][r], src, 64);
            float g3 = __shfl(s2[3][r], src, 64);
            float g4 = __shfl(s2[4][r], src, 64);
            const bool hi = l16 > q;
            float sv[4];
            sv[0] = (s1[0][r] + (hi ? g1 : g0)) * 0.125f;
            sv[1] = (s1[1][r] + (hi ? g2 : g1)) * 0.125f;
            sv[2] = (s1[2][r] + (hi ? g3 : g2)) * 0.125f;
            sv[3] = (s1[3][r] + (hi ? g4 : g3)) * 0.125f;
            #pragma unroll
            for (int h = 0; h < 4; ++h) {
                int j = j0 + h * 16 + l16;
                if (j > iq || j >= Q) sv[h] = -1e30f;
            }
            float p0 = __expf(sv[0]), p1 = __expf(sv[1]);
            float p2 = __expf(sv[2]), p3 = __expf(sv[3]);
            psum[r] += (p0 + p1) + (p2 + p3);
            Pl[w][q * 72 + l16]      = (f16)p0;
            Pl[w][q * 72 + 16 + l16] = (f16)p1;
            Pl[w][q * 72 + 32 + l16] = (f16)p2;
            Pl[w][q * 72 + 48 + l16] = (f16)p3;
        }
        __syncthreads();   // B
        f16x8 pa0 = *(const f16x8*)&Pl[w][l16 * 72 + lg * 8];
        f16x8 pa1 = *(const f16x8*)&Pl[w][l16 * 72 + 32 + lg * 8];
        __builtin_amdgcn_s_setprio(1);
        #pragma unroll
        for (int f = 0; f < 4; ++f) {
            f16x8 bv0 = *(const f16x8*)&Vt[(f * 16 + l16) * 72 + ((lg * 8) ^ xsw)];
            acc[f] = __builtin_amdgcn_mfma_f32_16x16x32_f16(pa0, bv0, acc[f], 0, 0, 0);
            f16x8 bv1 = *(const f16x8*)&Vt[(f * 16 + l16) * 72 + ((32 + lg * 8) ^ xsw)];
            acc[f] = __builtin_amdgcn_mfma_f32_16x16x32_f16(pa1, bv1, acc[f], 0, 0, 0);
        }
        __builtin_amdgcn_s_setprio(0);
        if (t + 1 < t1) {
            #pragma unroll
            for (int u = 0; u < 2; ++u) {
                int rb = w * 16 + u * 8;
                gload16(qkv + ((size_t)(j0 + 64 + rb + gr8) * B_ + b) * 1536 + 512 + n * 64 + gsl,
                        &Ks[rb * 64]);
            }
        }
        base += 64; if (base >= 192) base -= 192;
    }
    if (partial) {
        int idxp = (b * 8 + n) * 8 + (it - 8);
        float* Pp = part + (size_t)idxp * 8320 + (t0 ? 4160 : 0);
        #pragma unroll
        for (int r = 0; r < 4; ++r) {
            float ps = psum[r];
            ps += __shfl_xor(ps, 1, 64);
            ps += __shfl_xor(ps, 2, 64);
            ps += __shfl_xor(ps, 4, 64);
            ps += __shfl_xor(ps, 8, 64);
            int row = w * 16 + lg * 4 + r;
            #pragma unroll
            for (int f = 0; f < 4; ++f)
                Pp[row * 64 + f * 16 + l16] = acc[f][r];
            if (l16 == 0) Pp[4096 + row] = ps;
        }
    } else {
        #pragma unroll
        for (int r = 0; r < 4; ++r) {
            float ps = psum[r];
            ps += __shfl_xor(ps, 1, 64);
            ps += __shfl_xor(ps, 2, 64);
            ps += __shfl_xor(ps, 4, 64);
            ps += __shfl_xor(ps, 8, 64);
            int i = i0 + w * 16 + lg * 4 + r;
            if (i < Q) {
                float inv = 1.f / ps;
                f16* op = qkv + ((size_t)i * B_ + b) * 1536 + n * 64;
                #pragma unroll
                for (int f = 0; f < 4; ++f)
                    op[f * 16 + l16] = (f16)(acc[f][r] * inv);
            }
        }
    }
}

// ---------------------------------------------------------------------------
__global__ __launch_bounds__(256) void k_comb(const float* __restrict__ part,
                                              f16* __restrict__ qkv) {
    int idxp = blockIdx.x;
    int itm = idxp & 7;
    int bn = idxp >> 3;
    int b = bn >> 3, n = bn & 7;
    int i0 = (itm + 8) * 64;
    int row = threadIdx.x >> 2, dp = (threadIdx.x & 3) * 16;
    const float* A  = part + (size_t)idxp * 8320;
    const float* Bp = A + 4160;
    float inv = 1.f / (A[4096 + row] + Bp[4096 + row]);
    f16* op = qkv + ((size_t)(i0 + row) * B_ + b) * 1536 + n * 64 + dp;
    #pragma unroll
    for (int k = 0; k < 16; k += 4) {
        float4 a  = *(const float4*)(A  + row * 64 + dp + k);
        float4 bb = *(const float4*)(Bp + row * 64 + dp + k);
        op[k + 0] = (f16)((a.x + bb.x) * inv);
        op[k + 1] = (f16)((a.y + bb.y) * inv);
        op[k + 2] = (f16)((a.z + bb.z) * inv);
        op[k + 3] = (f16)((a.w + bb.w) * inv);
    }
}

// ---------------------------------------------------------------------------
extern "C" void kernel_launch(void* const* d_in, const int* in_sizes, int n_in,
                              void* d_out, int out_size, void* d_ws, size_t ws_size,
                              hipStream_t stream) {
    const int*   data     = (const int*)  d_in[0];
    const float* word_emb = (const float*)d_in[2];
    const float* rwb      = (const float*)d_in[3];
    const float* rrb      = (const float*)d_in[4];
    const float* nullg    = (const float*)d_in[5];
    const float* dg       = (const float*)d_in[6];
    const float* db       = (const float*)d_in[7];
    const float* qkv_w    = (const float*)d_in[8];
    const float* rk_w     = (const float*)d_in[9];
    const float* o_w      = (const float*)d_in[10];
    const float* ln1g     = (const float*)d_in[11];
    const float* ln1b     = (const float*)d_in[12];
    const float* w1       = (const float*)d_in[13];
    const float* b1       = (const float*)d_in[14];
    const float* w2       = (const float*)d_in[15];
    const float* b2       = (const float*)d_in[16];
    const float* ln2g     = (const float*)d_in[17];
    const float* ln2b     = (const float*)d_in[18];
    const float* fw       = (const float*)d_in[19];
    const float* fb       = (const float*)d_in[20];
    float* out = (float*)d_out;
    float* ws  = (float*)d_ws;

    float* x    = ws;                          // 2097152 f
    float* tmp  = x + 2097152;                 // 2097152 f
    float* xs   = tmp + 2097152;               // 589824 f
    f16* xh     = (f16*)(xs + 589824);         // 2097152 h
    f16* xsh    = xh + 2097152;                // 589824 h
    f16* r1h    = xsh + 589824;                // 524288 h
    f16* r2h    = r1h + 524288;                // 163840 h
    f16* rkall  = r2h + 163840;                // 2623488 h
    f16* bigh   = rkall + 2623488;             // 8388608 h
    f16* qkv_wh = bigh + 8388608;              // 6291456 h
    f16* rk_wh  = qkv_wh + 6291456;            // 2097152 h
    f16* o_wh   = rk_wh + 2097152;             // 2097152 h
    f16* w1h    = o_wh + 2097152;              // 8388608 h
    f16* w2h    = w1h + 8388608;               // 8388608 h
    f16* fwh    = w2h + 8388608;               // 131072 h

    auto conv = [&](const float* s, f16* d, int n) {
        int blocks = min(2048, (n + 1023) / 1024);
        k_f2h<<<blocks, 256, 0, stream>>>(s, d, n);
    };
    conv(qkv_w, qkv_wh, L_ * 1536 * 512);
    conv(rk_w,  rk_wh,  L_ * 512 * 512);
    conv(o_w,   o_wh,   L_ * 512 * 512);
    conv(w1,    w1h,    L_ * 2048 * 512);
    conv(w2,    w2h,    L_ * 512 * 2048);
    conv(fw,    fwh,    256 * 512);

    // tile chosen so block count >= 768 (3/CU) where possible: latency-bound
    // skinny GEMMs need co-resident blocks for overlap (R6/R7 lesson).
    auto gemm = [&](const f16* Xp, int lda, const f16* Wp, const float* bp,
                    void* Yp, int M, int N, int K, int out16, int act) {
        int b64_128 = (N % 128 == 0) ? ((M + 63) / 64) * (N / 128) : 0;
        if (b64_128 >= 768) {
            dim3 g((M + 63) / 64, N / 128);
            if (out16) {
                if (act) k_gemm<64, 128, 1, 1><<<g, 256, 0, stream>>>(Xp, lda, Wp, bp, Yp, M, N, K);
                else     k_gemm<64, 128, 1, 0><<<g, 256, 0, stream>>>(Xp, lda, Wp, bp, Yp, M, N, K);
            } else      k_gemm<64, 128, 0, 0><<<g, 256, 0, stream>>>(Xp, lda, Wp, bp, Yp, M, N, K);
            return;
        }
        int b64_64 = ((M + 63) / 64) * (N / 64);
        if (b64_64 >= 768) {
            dim3 g((M + 63) / 64, N / 64);
            if (out16) {
                if (act) k_gemm<64, 64, 1, 1><<<g, 256, 0, stream>>>(Xp, lda, Wp, bp, Yp, M, N, K);
                else     k_gemm<64, 64, 1, 0><<<g, 256, 0, stream>>>(Xp, lda, Wp, bp, Yp, M, N, K);
            } else      k_gemm<64, 64, 0, 0><<<g, 256, 0, stream>>>(Xp, lda, Wp, bp, Yp, M, N, K);
            return;
        }
        dim3 g((M + 31) / 32, N / 64);
        if (out16) {
            if (act) k_gemm<32, 64, 1, 1><<<g, 256, 0, stream>>>(Xp, lda, Wp, bp, Yp, M, N, K);
            else     k_gemm<32, 64, 1, 0><<<g, 256, 0, stream>>>(Xp, lda, Wp, bp, Yp, M, N, K);
        } else      k_gemm<32, 64, 0, 0><<<g, 256, 0, stream>>>(Xp, lda, Wp, bp, Yp, M, N, K);
    };

    k_embed<<<8192, 256, 0, stream>>>(data, word_emb, x, xh);
    k_posemb<<<1024, 256, 0, stream>>>(r1h, 1024);
    k_posemb<<<257, 256, 0, stream>>>(r2h, 257);

    // batched RK precompute (r is layer-invariant)
    gemm(r1h, 512, rk_wh,                nullptr, rkall,           1024, 1024, 512, 1, 0);
    gemm(r1h, 512, rk_wh + 6 * 262144,   nullptr, rkall + 1048576, 1024, 1024, 512, 1, 0);
    gemm(r2h, 512, rk_wh + 2 * 262144,   nullptr, rkall + 2097152,  257, 2048, 512, 1, 0);

    auto stage = [&](float* xb, f16* xbh, int Q, int lo, int hi) {
        const int M = Q * B_;
        dim3 gA = (Q == 1024) ? dim3(24, 32) : dim3((Q + 63) / 64, 32);
        dim3 gL((M + 3) / 4);
        for (int i = lo; i < hi; ++i) {
            const f16* rkp; int ldr;
            if (i < 2)       { rkp = rkall + i * 512;                 ldr = 1024; }
            else if (i >= 6) { rkp = rkall + 1048576 + (i - 6) * 512; ldr = 1024; }
            else             { rkp = rkall + 2097152 + (i - 2) * 512; ldr = 2048; }
            gemm(xbh, 512, qkv_wh + (size_t)i * 786432, nullptr, bigh, M, 1536, 512, 1, 0);
            k_attn<<<gA, 256, 0, stream>>>(bigh, rkp, ldr, rwb, rrb, Q, tmp);
            if (Q == 1024) k_comb<<<256, 256, 0, stream>>>(tmp, bigh);
            gemm(bigh, 1536, o_wh + (size_t)i * 262144, nullptr, tmp, M, 512, 512, 0, 0);
            k_ln<<<gL, 256, 0, stream>>>(xb, tmp, ln1g + (size_t)i * 512, ln1b + (size_t)i * 512, xbh, M);
            gemm(xbh, 512, w1h + (size_t)i * 1048576, b1 + (size_t)i * 2048, bigh, M, 2048, 512, 1, 1);
            gemm(bigh, 2048, w2h + (size_t)i * 1048576, b2 + (size_t)i * 512, tmp, M, 512, 2048, 0, 0);
            k_ln<<<gL, 256, 0, stream>>>(xb, tmp, ln2g + (size_t)i * 512, ln2b + (size_t)i * 512, xbh, M);
        }
    };

    stage(x, xh, 1024, 0, 2);                                    // pre
    k_downln<<<257, 256, 0, stream>>>(x, nullg, dg, db, xs, xsh);
    stage(xs, xsh, S_ + 1, 2, 6);                                // shortened
    k_up<<<8192, 256, 0, stream>>>(x, xs, xh);                   // upsample + residual
    stage(x, xh, 1024, 6, 8);                                    // post
    gemm(xh, 512, fwh, fb, out, T_ * B_, V_, 512, 0, 0);         // logits
}

// Round 9
// 851.944 us; speedup vs baseline: 6.5170x; 1.0250x over previous
//
#include <hip/hip_runtime.h>
#include <math.h>

#define T_  1024
#define B_  4
#define D_  512
#define H_  8
#define DH_ 64
#define DI_ 2048
#define V_  256
#define L_  8
#define S_  256   // segments

typedef _Float16 f16;
typedef f16   f16x8 __attribute__((ext_vector_type(8)));
typedef float f32x4 __attribute__((ext_vector_type(4)));

__device__ __forceinline__ void gload16(const void* g, void* l) {
    __builtin_amdgcn_global_load_lds(
        (const __attribute__((address_space(1))) void*)g,
        (__attribute__((address_space(3))) void*)l, 16, 0, 0);
}

// Q=1024 task table: 24 tasks/(b,n). Permuted so breadth-first CU triples
// {s, s+8, s+16} each sum to exactly 17 units (768 blocks = full residency;
// makespan = per-CU sum). Split points unchanged vs R8 (bit-identical).
__constant__ int cIT[24] = {15,15,14,13,12,11,10, 9,  8, 7,14, 6,13, 5,12, 4,  8, 0, 9, 1,10, 2,11, 3};
__constant__ int cT0[24] = { 0, 8, 0, 0, 0, 0, 0, 0,  0, 0, 8, 0, 8, 0, 8, 0,  8, 0, 8, 0, 8, 0, 8, 0};
__constant__ int cT1[24] = { 8,16, 8, 8, 8, 8, 8, 8,  8, 8,15, 7,14, 6,13, 5,  9, 1,10, 2,11, 3,12, 4};
// Q=257 task table: 8 tasks/(b,n) (tiles 2,3,4 split) = 256 blocks = 1/CU.
__constant__ int cIT2[8] = {4,4,3,3,2,2,1,0};
__constant__ int cT02[8] = {0,3,0,2,0,2,0,0};
__constant__ int cT12[8] = {3,5,2,4,2,3,2,1};

// ---------------------------------------------------------------------------
__global__ __launch_bounds__(256) void k_f2h(const float* __restrict__ s,
                                             f16* __restrict__ d, int n) {
    int i = (blockIdx.x * 256 + threadIdx.x) * 4;
    int stride = gridDim.x * 1024;
    for (; i < n; i += stride) {
        float4 v = *(const float4*)(s + i);
        d[i + 0] = (f16)v.x; d[i + 1] = (f16)v.y;
        d[i + 2] = (f16)v.z; d[i + 3] = (f16)v.w;
    }
}

// ---------------------------------------------------------------------------
__global__ __launch_bounds__(256) void k_embed(const int* __restrict__ data,
                                               const float* __restrict__ emb,
                                               float* __restrict__ x,
                                               f16* __restrict__ xh) {
    int idx = blockIdx.x * 256 + threadIdx.x;
    if (idx >= T_ * B_ * D_) return;
    int d  = idx & (D_ - 1);
    int tb = idx >> 9;
    float v = emb[(size_t)data[tb] * D_ + d];
    x[idx] = v; xh[idx] = (f16)v;
}

// ---------------------------------------------------------------------------
__global__ __launch_bounds__(256) void k_posemb(f16* __restrict__ r, int qlen) {
    int p = blockIdx.x;
    int k = threadIdx.x;
    float pos = (float)(qlen - 1 - p);
    float inv = powf(10000.f, -((float)k) / 256.f);
    float ang = pos * inv;
    r[(size_t)p * D_ + k]       = (f16)sinf(ang);
    r[(size_t)p * D_ + 256 + k] = (f16)cosf(ang);
}

// ---------------------------------------------------------------------------
// MFMA fp16 GEMM, m97 structure + XCD-chunked swizzle, parameterized tile.
template<int BM, int BN, int OUT16, int ACT>
__global__ __launch_bounds__(256) void k_gemm(const f16* __restrict__ X, int lda,
                                              const f16* __restrict__ W,
                                              const float* __restrict__ bias,
                                              void* __restrict__ Yv,
                                              int M, int N, int K) {
    __shared__ f16 As[BM * 64];
    __shared__ f16 Bs[BN * 64];
    const int tid = threadIdx.x, w = tid >> 6, lane = tid & 63;
    const int l16 = lane & 15, lg = lane >> 4;
    int nwg = gridDim.x * gridDim.y;
    int bid = blockIdx.y * gridDim.x + blockIdx.x;
    if ((nwg & 7) == 0) bid = (bid & 7) * (nwg >> 3) + (bid >> 3);   // XCD chunked
    const int bm = (bid % gridDim.x) * BM, bn = (bid / gridDim.x) * BN;
    const int lrow = lane >> 3, lcol = (lane & 7) * 8;
    constexpr int AI = (BM >= 32) ? BM / 32 : 1;
    constexpr int BI = BN / 32;
    constexpr int MI = (BN == 128) ? 4 : BM / 32;
    constexpr int NJ = 2;
    const int rbase = (BN == 128) ? 0 : (w >> 1) * (BM / 2);
    const int cbase = (BN == 128) ? w * 32 : (w & 1) * 32;
    const f32x4 z4 = {0.f, 0.f, 0.f, 0.f};
    f32x4 acc[MI][NJ];
    #pragma unroll
    for (int i = 0; i < MI; ++i)
        #pragma unroll
        for (int j = 0; j < NJ; ++j) acc[i][j] = z4;

    for (int k0 = 0; k0 < K; k0 += 64) {
        __syncthreads();
        #pragma unroll
        for (int u = 0; u < AI; ++u) {
            int rb = w * (BM / 4) + u * 8;
            gload16(X + (size_t)(bm + rb + lrow) * lda + k0 + lcol, &As[rb * 64]);
        }
        #pragma unroll
        for (int u = 0; u < BI; ++u) {
            int rb = w * (BN / 4) + u * 8;
            gload16(W + (size_t)(bn + rb + lrow) * K + k0 + lcol, &Bs[rb * 64]);
        }
        __syncthreads();
        __builtin_amdgcn_s_setprio(1);
        #pragma unroll
        for (int h = 0; h < 2; ++h) {
            f16x8 af[MI], bf[NJ];
            #pragma unroll
            for (int i = 0; i < MI; ++i)
                af[i] = *(const f16x8*)&As[(rbase + i * 16 + l16) * 64 + h * 32 + lg * 8];
            #pragma unroll
            for (int j = 0; j < NJ; ++j)
                bf[j] = *(const f16x8*)&Bs[(cbase + j * 16 + l16) * 64 + h * 32 + lg * 8];
            #pragma unroll
            for (int i = 0; i < MI; ++i)
                #pragma unroll
                for (int j = 0; j < NJ; ++j)
                    acc[i][j] = __builtin_amdgcn_mfma_f32_16x16x32_f16(af[i], bf[j], acc[i][j], 0, 0, 0);
        }
        __builtin_amdgcn_s_setprio(0);
    }
    #pragma unroll
    for (int i = 0; i < MI; ++i) {
        #pragma unroll
        for (int r = 0; r < 4; ++r) {
            int row = bm + rbase + i * 16 + lg * 4 + r;
            if (row >= M) continue;
            int colb = bn + cbase + l16;
            #pragma unroll
            for (int j = 0; j < NJ; ++j) {
                float v = acc[i][j][r];
                if (bias) v += bias[colb + j * 16];
                if (ACT) v = fmaxf(v, 0.f);
                if (OUT16) ((f16*)Yv)[(size_t)row * N + colb + j * 16] = (f16)v;
                else       ((float*)Yv)[(size_t)row * N + colb + j * 16] = v;
            }
        }
    }
}

// ---------------------------------------------------------------------------
// Add(f16) + LayerNorm, one WAVE per row, 4 rows/block.
__global__ __launch_bounds__(256) void k_ln(float* __restrict__ x,
                                            const f16* __restrict__ add,
                                            const float* __restrict__ g,
                                            const float* __restrict__ b,
                                            f16* __restrict__ xh, int rows) {
    int row = blockIdx.x * 4 + (threadIdx.x >> 6);
    if (row >= rows) return;
    int lane = threadIdx.x & 63;
    float* xr = x + (size_t)row * D_ + lane * 8;
    float v[8];
    {
        float4 a0 = *(const float4*)xr;
        float4 a1 = *(const float4*)(xr + 4);
        v[0] = a0.x; v[1] = a0.y; v[2] = a0.z; v[3] = a0.w;
        v[4] = a1.x; v[5] = a1.y; v[6] = a1.z; v[7] = a1.w;
    }
    if (add) {
        f16x8 a = *(const f16x8*)(add + (size_t)row * D_ + lane * 8);
        #pragma unroll
        for (int u = 0; u < 8; ++u) v[u] += (float)a[u];
    }
    float s = 0.f, sq = 0.f;
    #pragma unroll
    for (int u = 0; u < 8; ++u) { s += v[u]; sq += v[u] * v[u]; }
    #pragma unroll
    for (int off = 1; off < 64; off <<= 1) {
        s  += __shfl_xor(s,  off, 64);
        sq += __shfl_xor(sq, off, 64);
    }
    float mean = s * (1.f / (float)D_);
    float var  = sq * (1.f / (float)D_) - mean * mean;
    float rs   = rsqrtf(var + 1e-5f);
    const float* gp = g + lane * 8;
    const float* bp = b + lane * 8;
    float4 g0 = *(const float4*)gp, g1 = *(const float4*)(gp + 4);
    float4 b0 = *(const float4*)bp, b1 = *(const float4*)(bp + 4);
    float gg[8] = {g0.x, g0.y, g0.z, g0.w, g1.x, g1.y, g1.z, g1.w};
    float bb[8] = {b0.x, b0.y, b0.z, b0.w, b1.x, b1.y, b1.z, b1.w};
    float o[8];
    #pragma unroll
    for (int u = 0; u < 8; ++u) o[u] = (v[u] - mean) * rs * gg[u] + bb[u];
    *(float4*)xr       = make_float4(o[0], o[1], o[2], o[3]);
    *(float4*)(xr + 4) = make_float4(o[4], o[5], o[6], o[7]);
    f16x8 hv;
    #pragma unroll
    for (int u = 0; u < 8; ++u) hv[u] = (f16)o[u];
    *(f16x8*)(xh + (size_t)row * D_ + lane * 8) = hv;
}

// ---------------------------------------------------------------------------
// Fused downsample (mean-pool + null row) + LayerNorm. Wave per output row.
__global__ __launch_bounds__(256) void k_downln(const float* __restrict__ x,
                                                const float* __restrict__ nullg,
                                                const float* __restrict__ g,
                                                const float* __restrict__ bi,
                                                float* __restrict__ xs,
                                                f16* __restrict__ xsh) {
    int row = blockIdx.x * 4 + (threadIdx.x >> 6);
    if (row >= (S_ + 1) * B_) return;
    int lane = threadIdx.x & 63;
    int s = row >> 2, b = row & 3;
    float v[8];
    if (s == 0) {
        const float* np = nullg + lane * 8;
        float4 a0 = *(const float4*)np, a1 = *(const float4*)(np + 4);
        v[0] = a0.x; v[1] = a0.y; v[2] = a0.z; v[3] = a0.w;
        v[4] = a1.x; v[5] = a1.y; v[6] = a1.z; v[7] = a1.w;
    } else {
        int t0 = (s - 1) * 4;
        #pragma unroll
        for (int u = 0; u < 8; ++u) v[u] = 0.f;
        #pragma unroll
        for (int k = 0; k < 4; ++k) {
            const float* xp = x + ((size_t)(t0 + k) * B_ + b) * D_ + lane * 8;
            float4 a0 = *(const float4*)xp, a1 = *(const float4*)(xp + 4);
            v[0] += a0.x; v[1] += a0.y; v[2] += a0.z; v[3] += a0.w;
            v[4] += a1.x; v[5] += a1.y; v[6] += a1.z; v[7] += a1.w;
        }
        #pragma unroll
        for (int u = 0; u < 8; ++u) v[u] *= 0.25f;
    }
    float sm = 0.f, sq = 0.f;
    #pragma unroll
    for (int u = 0; u < 8; ++u) { sm += v[u]; sq += v[u] * v[u]; }
    #pragma unroll
    for (int off = 1; off < 64; off <<= 1) {
        sm += __shfl_xor(sm, off, 64);
        sq += __shfl_xor(sq, off, 64);
    }
    float mean = sm * (1.f / (float)D_);
    float var  = sq * (1.f / (float)D_) - mean * mean;
    float rs   = rsqrtf(var + 1e-5f);
    float o[8];
    #pragma unroll
    for (int u = 0; u < 8; ++u)
        o[u] = (v[u] - mean) * rs * g[lane * 8 + u] + bi[lane * 8 + u];
    float* xp = xs + (size_t)row * D_ + lane * 8;
    *(float4*)xp       = make_float4(o[0], o[1], o[2], o[3]);
    *(float4*)(xp + 4) = make_float4(o[4], o[5], o[6], o[7]);
    f16x8 hv;
    #pragma unroll
    for (int u = 0; u < 8; ++u) hv[u] = (f16)o[u];
    *(f16x8*)(xsh + (size_t)row * D_ + lane * 8) = hv;
}

__global__ __launch_bounds__(256) void k_up(float* __restrict__ x,
                                            const float* __restrict__ xs,
                                            f16* __restrict__ xh) {
    int idx = blockIdx.x * 256 + threadIdx.x;
    if (idx >= T_ * B_ * D_) return;
    int d  = idx & (D_ - 1);
    int tb = idx >> 9;
    int t = tb >> 2, b = tb & 3;
    int seg = (t + 1) >> 2;
    float v = x[idx] + xs[((size_t)seg * B_ + b) * D_ + d];
    x[idx] = v; xh[idx] = (f16)v;
}

// ---------------------------------------------------------------------------
// MFMA flash attention v6: balanced task tables for BOTH Q=1024 (24 tasks,
// per-CU sum exactly 17 under breadth-first fill) and Q=257 (8 tasks = 1/CU).
// Deferred softmax (partials combine by addition), swizzled LDS, circular RK
// window, 1-deep prefetch, XCD-local (b, head-group) mapping.
__global__ __launch_bounds__(256) void k_attn(f16* __restrict__ qkv,
                                              const f16* __restrict__ rkb,
                                              int ldr,
                                              const float* __restrict__ rwb,
                                              const float* __restrict__ rrb,
                                              int Q, float* __restrict__ part) {
    __shared__ f16 RKs[192 * 64];
    __shared__ f16 Ks[64 * 64];
    __shared__ f16 Vt[64 * 72];
    __shared__ f16 Pl[4][16 * 72];
    f16* Qw = RKs;
    f16* Qr = RKs + 4096;

    int it, t0, t1, b, n;
    bool partial;
    int idxp;
    {
        int p = blockIdx.y * gridDim.x + blockIdx.x;
        int xcd = p & 7, qq = p >> 3;
        b = xcd >> 1;
        n = (xcd & 1) * 4 + (qq & 3);
        int slot = qq >> 2;
        if (Q == 1024) {
            it = cIT[slot]; t0 = cT0[slot]; t1 = cT1[slot];
            partial = (it >= 8);
            idxp = (b * 8 + n) * 8 + (it - 8);
        } else {           // Q == 257, grid (8,32)
            it = cIT2[slot]; t0 = cT02[slot]; t1 = cT12[slot];
            partial = (it >= 2);
            idxp = (b * 8 + n) * 3 + (it - 2);
        }
    }
    const int i0 = it * 64;
    const int tid = threadIdx.x, w = tid >> 6, lane = tid & 63;
    const int l16 = lane & 15, lg = lane >> 4;
    const int xsw = (l16 & 7) << 3;
    const int gr8 = lane >> 3;
    const int gsl = ((lane & 7) ^ gr8) * 8;
    const int vjj = tid >> 2, vdb = (tid & 3) * 16;
    const int wb = 48 - w * 16;
    const f32x4 z4 = {0.f, 0.f, 0.f, 0.f};

    {   // stage Q (+biases) into RK alias, swizzled
        int row = tid >> 2, dq = (tid & 3) * 16;
        const f16* qp = qkv + ((size_t)(i0 + row) * B_ + b) * 1536 + n * 64 + dq;
        f16x8 q0 = *(const f16x8*)qp, q1 = *(const f16x8*)(qp + 8);
        int rsw = (row & 7) << 3;
        #pragma unroll
        for (int u = 0; u < 8; ++u) {
            float qa = (float)q0[u], qb2 = (float)q1[u];
            Qw[row * 64 + ((dq + u) ^ rsw)]     = (f16)(qa + rwb[n * 64 + dq + u]);
            Qw[row * 64 + ((dq + 8 + u) ^ rsw)] = (f16)(qb2 + rwb[n * 64 + dq + 8 + u]);
            Qr[row * 64 + ((dq + u) ^ rsw)]     = (f16)(qa + rrb[n * 64 + dq + u]);
            Qr[row * 64 + ((dq + 8 + u) ^ rsw)] = (f16)(qb2 + rrb[n * 64 + dq + 8 + u]);
        }
    }
    __syncthreads();
    f16x8 aqw[2], aqr[2];
    #pragma unroll
    for (int h = 0; h < 2; ++h) {
        aqw[h] = *(const f16x8*)&Qw[(w * 16 + l16) * 64 + ((h * 32 + lg * 8) ^ xsw)];
        aqr[h] = *(const f16x8*)&Qr[(w * 16 + l16) * 64 + ((h * 32 + lg * 8) ^ xsw)];
    }
    __syncthreads();

    const long long pb = (long long)Q - 64 - i0;
    #pragma unroll
    for (int u = 0; u < 4; ++u) {
        int rb = w * 32 + u * 8;
        long long p = pb + t0 * 64 + rb + gr8;
        gload16(rkb + p * ldr + n * 64 + gsl, &RKs[rb * 64]);
    }
    #pragma unroll
    for (int u = 0; u < 2; ++u) {
        int rb = w * 16 + u * 8;
        gload16(qkv + ((size_t)(t0 * 64 + rb + gr8) * B_ + b) * 1536 + 512 + n * 64 + gsl,
                &Ks[rb * 64]);
    }
    f16x8 vr0, vr1;
    {
        const f16* vp = qkv + ((size_t)(t0 * 64 + vjj) * B_ + b) * 1536 + 1024 + n * 64 + vdb;
        vr0 = *(const f16x8*)vp; vr1 = *(const f16x8*)(vp + 8);
    }

    f32x4 acc[4]; acc[0] = z4; acc[1] = z4; acc[2] = z4; acc[3] = z4;
    float psum[4] = {0.f, 0.f, 0.f, 0.f};
    int base = 0;

    for (int t = t0; t < t1; ++t) {
        const int j0 = t * 64;
        __syncthreads();   // A
        #pragma unroll
        for (int u = 0; u < 8; ++u) {
            Vt[(vdb + u) * 72 + (vjj ^ ((u & 7) << 3))]     = vr0[u];
            Vt[(vdb + 8 + u) * 72 + (vjj ^ ((u & 7) << 3))] = vr1[u];
        }
        if (t + 1 < t1) {
            int sb = base + 128; if (sb >= 192) sb -= 192;
            #pragma unroll
            for (int u = 0; u < 2; ++u) {
                int rb = w * 16 + u * 8;
                long long p = pb + j0 + 128 + rb + gr8;
                gload16(rkb + p * ldr + n * 64 + gsl, &RKs[(sb + rb) * 64]);
            }
        }
        f32x4 s1[4]; s1[0] = z4; s1[1] = z4; s1[2] = z4; s1[3] = z4;
        __builtin_amdgcn_s_setprio(1);
        #pragma unroll
        for (int f = 0; f < 4; ++f)
            #pragma unroll
            for (int h = 0; h < 2; ++h) {
                f16x8 bv = *(const f16x8*)&Ks[(f * 16 + l16) * 64 + ((h * 32 + lg * 8) ^ xsw)];
                s1[f] = __builtin_amdgcn_mfma_f32_16x16x32_f16(aqw[h], bv, s1[f], 0, 0, 0);
            }
        __builtin_amdgcn_s_setprio(0);
        if (t + 1 < t1) {
            const f16* vp = qkv + ((size_t)(j0 + 64 + vjj) * B_ + b) * 1536 + 1024 + n * 64 + vdb;
            vr0 = *(const f16x8*)vp; vr1 = *(const f16x8*)(vp + 8);
        }
        f32x4 s2[5]; s2[0] = z4; s2[1] = z4; s2[2] = z4; s2[3] = z4; s2[4] = z4;
        __builtin_amdgcn_s_setprio(1);
        #pragma unroll
        for (int f = 0; f < 5; ++f) {
            int slot = base + wb + f * 16 + l16; if (slot >= 192) slot -= 192;
            #pragma unroll
            for (int h = 0; h < 2; ++h) {
                f16x8 bv = *(const f16x8*)&RKs[slot * 64 + ((h * 32 + lg * 8) ^ xsw)];
                s2[f] = __builtin_amdgcn_mfma_f32_16x16x32_f16(aqr[h], bv, s2[f], 0, 0, 0);
            }
        }
        __builtin_amdgcn_s_setprio(0);
        #pragma unroll
        for (int r = 0; r < 4; ++r) {
            const int q = lg * 4 + r;
            const int iq = i0 + w * 16 + q;
            const int src = (lane & 48) | ((l16 + 15 - q) & 15);
            float g0 = __shfl(s2[0][r], src, 64);
            float g1 = __shfl(s2[1][r], src, 64);
            float g2 = __shfl(s2[2][r], src, 64);
            float g3 = __shfl(s2[3][r], src, 64);
            float g4 = __shfl(s2[4][r], src, 64);
            const bool hi = l16 > q;
            float sv[4];
            sv[0] = (s1[0][r] + (hi ? g1 : g0)) * 0.125f;
            sv[1] = (s1[1][r] + (hi ? g2 : g1)) * 0.125f;
            sv[2] = (s1[2][r] + (hi ? g3 : g2)) * 0.125f;
            sv[3] = (s1[3][r] + (hi ? g4 : g3)) * 0.125f;
            #pragma unroll
            for (int h = 0; h < 4; ++h) {
                int j = j0 + h * 16 + l16;
                if (j > iq || j >= Q) sv[h] = -1e30f;
            }
            float p0 = __expf(sv[0]), p1 = __expf(sv[1]);
            float p2 = __expf(sv[2]), p3 = __expf(sv[3]);
            psum[r] += (p0 + p1) + (p2 + p3);
            Pl[w][q * 72 + l16]      = (f16)p0;
            Pl[w][q * 72 + 16 + l16] = (f16)p1;
            Pl[w][q * 72 + 32 + l16] = (f16)p2;
            Pl[w][q * 72 + 48 + l16] = (f16)p3;
        }
        __syncthreads();   // B
        f16x8 pa0 = *(const f16x8*)&Pl[w][l16 * 72 + lg * 8];
        f16x8 pa1 = *(const f16x8*)&Pl[w][l16 * 72 + 32 + lg * 8];
        __builtin_amdgcn_s_setprio(1);
        #pragma unroll
        for (int f = 0; f < 4; ++f) {
            f16x8 bv0 = *(const f16x8*)&Vt[(f * 16 + l16) * 72 + ((lg * 8) ^ xsw)];
            acc[f] = __builtin_amdgcn_mfma_f32_16x16x32_f16(pa0, bv0, acc[f], 0, 0, 0);
            f16x8 bv1 = *(const f16x8*)&Vt[(f * 16 + l16) * 72 + ((32 + lg * 8) ^ xsw)];
            acc[f] = __builtin_amdgcn_mfma_f32_16x16x32_f16(pa1, bv1, acc[f], 0, 0, 0);
        }
        __builtin_amdgcn_s_setprio(0);
        if (t + 1 < t1) {
            #pragma unroll
            for (int u = 0; u < 2; ++u) {
                int rb = w * 16 + u * 8;
                gload16(qkv + ((size_t)(j0 + 64 + rb + gr8) * B_ + b) * 1536 + 512 + n * 64 + gsl,
                        &Ks[rb * 64]);
            }
        }
        base += 64; if (base >= 192) base -= 192;
    }
    if (partial) {
        float* Pp = part + (size_t)idxp * 8320 + (t0 ? 4160 : 0);
        #pragma unroll
        for (int r = 0; r < 4; ++r) {
            float ps = psum[r];
            ps += __shfl_xor(ps, 1, 64);
            ps += __shfl_xor(ps, 2, 64);
            ps += __shfl_xor(ps, 4, 64);
            ps += __shfl_xor(ps, 8, 64);
            int row = w * 16 + lg * 4 + r;
            #pragma unroll
            for (int f = 0; f < 4; ++f)
                Pp[row * 64 + f * 16 + l16] = acc[f][r];
            if (l16 == 0) Pp[4096 + row] = ps;
        }
    } else {
        #pragma unroll
        for (int r = 0; r < 4; ++r) {
            float ps = psum[r];
            ps += __shfl_xor(ps, 1, 64);
            ps += __shfl_xor(ps, 2, 64);
            ps += __shfl_xor(ps, 4, 64);
            ps += __shfl_xor(ps, 8, 64);
            int i = i0 + w * 16 + lg * 4 + r;
            if (i < Q) {
                float inv = 1.f / ps;
                f16* op = qkv + ((size_t)i * B_ + b) * 1536 + n * 64;
                #pragma unroll
                for (int f = 0; f < 4; ++f)
                    op[f * 16 + l16] = (f16)(acc[f][r] * inv);
            }
        }
    }
}

// ---------------------------------------------------------------------------
// Combine split-attention partials: out = (accA+accB)/(psA+psB).
__global__ __launch_bounds__(256) void k_comb(const float* __restrict__ part,
                                              f16* __restrict__ qkv,
                                              int nm, int itbase, int Q) {
    int idxp = blockIdx.x;
    int m = idxp % nm;
    int bn = idxp / nm;
    int b = bn >> 3, n = bn & 7;
    int i0 = (m + itbase) * 64;
    int row = threadIdx.x >> 2, dp = (threadIdx.x & 3) * 16;
    if (i0 + row >= Q) return;
    const float* A  = part + (size_t)idxp * 8320;
    const float* Bp = A + 4160;
    float inv = 1.f / (A[4096 + row] + Bp[4096 + row]);
    f16* op = qkv + ((size_t)(i0 + row) * B_ + b) * 1536 + n * 64 + dp;
    #pragma unroll
    for (int k = 0; k < 16; k += 4) {
        float4 a  = *(const float4*)(A  + row * 64 + dp + k);
        float4 bb = *(const float4*)(Bp + row * 64 + dp + k);
        op[k + 0] = (f16)((a.x + bb.x) * inv);
        op[k + 1] = (f16)((a.y + bb.y) * inv);
        op[k + 2] = (f16)((a.z + bb.z) * inv);
        op[k + 3] = (f16)((a.w + bb.w) * inv);
    }
}

// ---------------------------------------------------------------------------
extern "C" void kernel_launch(void* const* d_in, const int* in_sizes, int n_in,
                              void* d_out, int out_size, void* d_ws, size_t ws_size,
                              hipStream_t stream) {
    const int*   data     = (const int*)  d_in[0];
    const float* word_emb = (const float*)d_in[2];
    const float* rwb      = (const float*)d_in[3];
    const float* rrb      = (const float*)d_in[4];
    const float* nullg    = (const float*)d_in[5];
    const float* dg       = (const float*)d_in[6];
    const float* db       = (const float*)d_in[7];
    const float* qkv_w    = (const float*)d_in[8];
    const float* rk_w     = (const float*)d_in[9];
    const float* o_w      = (const float*)d_in[10];
    const float* ln1g     = (const float*)d_in[11];
    const float* ln1b     = (const float*)d_in[12];
    const float* w1       = (const float*)d_in[13];
    const float* b1       = (const float*)d_in[14];
    const float* w2       = (const float*)d_in[15];
    const float* b2       = (const float*)d_in[16];
    const float* ln2g     = (const float*)d_in[17];
    const float* ln2b     = (const float*)d_in[18];
    const float* fw       = (const float*)d_in[19];
    const float* fb       = (const float*)d_in[20];
    float* out = (float*)d_out;
    float* ws  = (float*)d_ws;

    float* x    = ws;                          // 2097152 f
    float* tmp  = x + 2097152;                 // 2097152 f (attn partials / f16 tmp)
    float* xs   = tmp + 2097152;               // 589824 f
    f16* xh     = (f16*)(xs + 589824);         // 2097152 h
    f16* xsh    = xh + 2097152;                // 589824 h
    f16* r1h    = xsh + 589824;                // 524288 h
    f16* r2h    = r1h + 524288;                // 163840 h
    f16* rkall  = r2h + 163840;                // 2623488 h
    f16* bigh   = rkall + 2623488;             // 8388608 h
    f16* qkv_wh = bigh + 8388608;              // 6291456 h
    f16* rk_wh  = qkv_wh + 6291456;            // 2097152 h
    f16* o_wh   = rk_wh + 2097152;             // 2097152 h
    f16* w1h    = o_wh + 2097152;              // 8388608 h
    f16* w2h    = w1h + 8388608;               // 8388608 h
    f16* fwh    = w2h + 8388608;               // 131072 h
    f16* tmph   = (f16*)tmp;                   // alias: o/w2 f16 output

    auto conv = [&](const float* s, f16* d, int n) {
        int blocks = min(2048, (n + 1023) / 1024);
        k_f2h<<<blocks, 256, 0, stream>>>(s, d, n);
    };
    conv(qkv_w, qkv_wh, L_ * 1536 * 512);
    conv(rk_w,  rk_wh,  L_ * 512 * 512);
    conv(o_w,   o_wh,   L_ * 512 * 512);
    conv(w1,    w1h,    L_ * 2048 * 512);
    conv(w2,    w2h,    L_ * 512 * 2048);
    conv(fw,    fwh,    256 * 512);

    auto gemm = [&](const f16* Xp, int lda, const f16* Wp, const float* bp,
                    void* Yp, int M, int N, int K, int out16, int act) {
        int b64_128 = (N % 128 == 0) ? ((M + 63) / 64) * (N / 128) : 0;
        if (b64_128 >= 768) {
            dim3 g((M + 63) / 64, N / 128);
            if (out16) {
                if (act) k_gemm<64, 128, 1, 1><<<g, 256, 0, stream>>>(Xp, lda, Wp, bp, Yp, M, N, K);
                else     k_gemm<64, 128, 1, 0><<<g, 256, 0, stream>>>(Xp, lda, Wp, bp, Yp, M, N, K);
            } else      k_gemm<64, 128, 0, 0><<<g, 256, 0, stream>>>(Xp, lda, Wp, bp, Yp, M, N, K);
            return;
        }
        int b64_64 = ((M + 63) / 64) * (N / 64);
        if (b64_64 >= 768) {
            dim3 g((M + 63) / 64, N / 64);
            if (out16) {
                if (act) k_gemm<64, 64, 1, 1><<<g, 256, 0, stream>>>(Xp, lda, Wp, bp, Yp, M, N, K);
                else     k_gemm<64, 64, 1, 0><<<g, 256, 0, stream>>>(Xp, lda, Wp, bp, Yp, M, N, K);
            } else      k_gemm<64, 64, 0, 0><<<g, 256, 0, stream>>>(Xp, lda, Wp, bp, Yp, M, N, K);
            return;
        }
        dim3 g((M + 31) / 32, N / 64);
        if (out16) {
            if (act) k_gemm<32, 64, 1, 1><<<g, 256, 0, stream>>>(Xp, lda, Wp, bp, Yp, M, N, K);
            else     k_gemm<32, 64, 1, 0><<<g, 256, 0, stream>>>(Xp, lda, Wp, bp, Yp, M, N, K);
        } else      k_gemm<32, 64, 0, 0><<<g, 256, 0, stream>>>(Xp, lda, Wp, bp, Yp, M, N, K);
    };

    k_embed<<<8192, 256, 0, stream>>>(data, word_emb, x, xh);
    k_posemb<<<1024, 256, 0, stream>>>(r1h, 1024);
    k_posemb<<<257, 256, 0, stream>>>(r2h, 257);

    // batched RK precompute (r is layer-invariant)
    gemm(r1h, 512, rk_wh,                nullptr, rkall,           1024, 1024, 512, 1, 0);
    gemm(r1h, 512, rk_wh + 6 * 262144,   nullptr, rkall + 1048576, 1024, 1024, 512, 1, 0);
    gemm(r2h, 512, rk_wh + 2 * 262144,   nullptr, rkall + 2097152,  257, 2048, 512, 1, 0);

    auto stage = [&](float* xb, f16* xbh, int Q, int lo, int hi) {
        const int M = Q * B_;
        dim3 gA = (Q == 1024) ? dim3(24, 32) : dim3(8, 32);
        dim3 gL((M + 3) / 4);
        for (int i = lo; i < hi; ++i) {
            const f16* rkp; int ldr;
            if (i < 2)       { rkp = rkall + i * 512;                 ldr = 1024; }
            else if (i >= 6) { rkp = rkall + 1048576 + (i - 6) * 512; ldr = 1024; }
            else             { rkp = rkall + 2097152 + (i - 2) * 512; ldr = 2048; }
            gemm(xbh, 512, qkv_wh + (size_t)i * 786432, nullptr, bigh, M, 1536, 512, 1, 0);
            k_attn<<<gA, 256, 0, stream>>>(bigh, rkp, ldr, rwb, rrb, Q, tmp);
            if (Q == 1024) k_comb<<<256, 256, 0, stream>>>(tmp, bigh, 8, 8, 1024);
            else           k_comb<<<96, 256, 0, stream>>>(tmp, bigh, 3, 2, 257);
            gemm(bigh, 1536, o_wh + (size_t)i * 262144, nullptr, tmph, M, 512, 512, 1, 0);
            k_ln<<<gL, 256, 0, stream>>>(xb, tmph, ln1g + (size_t)i * 512, ln1b + (size_t)i * 512, xbh, M);
            gemm(xbh, 512, w1h + (size_t)i * 1048576, b1 + (size_t)i * 2048, bigh, M, 2048, 512, 1, 1);
            gemm(bigh, 2048, w2h + (size_t)i * 1048576, b2 + (size_t)i * 512, tmph, M, 512, 2048, 1, 0);
            k_ln<<<gL, 256, 0, stream>>>(xb, tmph, ln2g + (size_t)i * 512, ln2b + (size_t)i * 512, xbh, M);
        }
    };

    stage(x, xh, 1024, 0, 2);                                    // pre
    k_downln<<<257, 256, 0, stream>>>(x, nullg, dg, db, xs, xsh);
    stage(xs, xsh, S_ + 1, 2, 6);                                // shortened
    k_up<<<8192, 256, 0, stream>>>(x, xs, xh);                   // upsample + residual
    stage(x, xh, 1024, 6, 8);                                    // post
    gemm(xh, 512, fwh, fb, out, T_ * B_, V_, 512, 0, 0);         // logits
}